// Round 10
// baseline (7829.871 us; speedup 1.0000x reference)
//
#include <hip/hip_runtime.h>
#include <hip/hip_bf16.h>

#define N_NODES 50000
#define N_EDGES 800000
#define N_GRAPH 500
#define ND 64
#define ED 32
#define HD 128
#define WPB 4   // waves per block (256 threads)

typedef __attribute__((ext_vector_type(8))) short bf16x8;
typedef __attribute__((ext_vector_type(4))) float f32x4;

__device__ __forceinline__ float sp(float x) {
    return fmaxf(x, 0.f) + log1pf(expf(-fabsf(x)));
}

// fast softplus for the bf16 edge path
__device__ __forceinline__ float spf(float x) {
    return fmaxf(x, 0.f) + __logf(1.f + __expf(-fabsf(x)));
}

__device__ __forceinline__ unsigned short f2bf(float v) {
    __hip_bfloat16 b = __float2bfloat16(v);
    return *(unsigned short*)&b;
}

__device__ __forceinline__ unsigned int pkbf(float a, float b) {
    return (unsigned int)f2bf(a) | ((unsigned int)f2bf(b) << 16);
}

// ---------------- node projection + BN (fp32) ---------------------------
__global__ __launch_bounds__(256) void k_node_proj(
    const float* __restrict__ x, const float* __restrict__ Wnp,
    const float* __restrict__ bnp, float* __restrict__ t,
    float* __restrict__ stats) {
    int lane = threadIdx.x & 63;
    int wave = (blockIdx.x * blockDim.x + threadIdx.x) >> 6;
    int nw = (gridDim.x * blockDim.x) >> 6;
    float w[13];
#pragma unroll
    for (int k = 0; k < 13; ++k) w[k] = Wnp[k * ND + lane];
    float bb = bnp[lane];
    float s0 = 0.f, s1 = 0.f;
    for (int i = wave; i < N_NODES; i += nw) {
        float acc = bb;
#pragma unroll
        for (int k = 0; k < 13; ++k) acc += x[i * 13 + k] * w[k];
        float v = sp(acc);
        t[i * ND + lane] = v;
        s0 += v; s1 += v * v;
    }
    atomicAdd(&stats[lane], s0);
    atomicAdd(&stats[ND + lane], s1);
}

__global__ void k_bn_finalize(const float* __restrict__ stats,
                              const float* __restrict__ g,
                              const float* __restrict__ b,
                              float* __restrict__ ss) {
    int j = threadIdx.x;
    if (j >= ND) return;
    float inv_n = 1.f / (float)N_NODES;
    float mu = stats[j] * inv_n;
    float var = stats[ND + j] * inv_n - mu * mu;
    float rs = rsqrtf(var + 1e-5f);
    float sc = rs * g[j];
    ss[j] = sc;
    ss[ND + j] = b[j] - mu * sc;
}

__global__ __launch_bounds__(256) void k_bn_apply(
    const float* __restrict__ t, const float* __restrict__ ss,
    float* __restrict__ h, unsigned short* __restrict__ hb) {
    int idx = blockIdx.x * blockDim.x + threadIdx.x;
    int tot = N_NODES * ND;
    int stride = gridDim.x * blockDim.x;
    for (; idx < tot; idx += stride) {
        int c = idx & (ND - 1);
        float v = t[idx] * ss[c] + ss[ND + c];
        h[idx] = v;
        hb[idx] = f2bf(v);
    }
}

// ---------------- counting sort of edges by dst -------------------------
__global__ __launch_bounds__(256) void k_hist(const int* __restrict__ ei,
                                              int* __restrict__ hist) {
    int e = blockIdx.x * 256 + threadIdx.x;
    if (e < N_EDGES) atomicAdd(&hist[ei[N_EDGES + e]], 1);
}

__global__ __launch_bounds__(1024) void k_scan1(const int* __restrict__ hist,
                                                int* __restrict__ chunksum) {
    __shared__ int s[1024];
    int t = threadIdx.x;
    int i = blockIdx.x * 1024 + t;
    s[t] = (i < N_NODES) ? hist[i] : 0;
    __syncthreads();
    for (int off = 512; off; off >>= 1) {
        if (t < off) s[t] += s[t + off];
        __syncthreads();
    }
    if (t == 0) chunksum[blockIdx.x] = s[0];
}

__global__ void k_scan2(int* __restrict__ chunksum, int n) {
    if (threadIdx.x == 0) {
        int acc = 0;
        for (int i = 0; i < n; ++i) { int v = chunksum[i]; chunksum[i] = acc; acc += v; }
    }
}

__global__ __launch_bounds__(1024) void k_scan3(const int* __restrict__ hist,
                                                const int* __restrict__ chunksum,
                                                int* __restrict__ cursor,
                                                int* __restrict__ rowptr) {
    __shared__ int s[1024];
    int t = threadIdx.x;
    int i = blockIdx.x * 1024 + t;
    int v = (i < N_NODES) ? hist[i] : 0;
    s[t] = v;
    __syncthreads();
    for (int off = 1; off < 1024; off <<= 1) {
        int u = (t >= off) ? s[t - off] : 0;
        __syncthreads();
        s[t] += u;
        __syncthreads();
    }
    if (i < N_NODES) {
        int ex = chunksum[blockIdx.x] + s[t] - v;  // exclusive scan
        cursor[i] = ex;
        rowptr[i] = ex;
    }
}

__global__ __launch_bounds__(256) void k_scatter(const int* __restrict__ ei,
                                                 int* __restrict__ cursor,
                                                 int* __restrict__ sS,
                                                 int* __restrict__ sE) {
    int e = blockIdx.x * 256 + threadIdx.x;
    if (e >= N_EDGES) return;
    int d = ei[N_EDGES + e];
    int pos = atomicAdd(&cursor[d], 1);
    sS[pos] = ei[e];
    sE[pos] = e;
}

// edge projection into sorted order (layer-invariant, once per call)
__global__ __launch_bounds__(256) void k_eproj_sorted(
    const float* __restrict__ ea, const int* __restrict__ sE,
    const float* __restrict__ Wep, const float* __restrict__ bep,
    unsigned short* __restrict__ e_bf) {
    long idx = (long)blockIdx.x * blockDim.x + threadIdx.x;
    long tot = (long)N_EDGES * 32;
    if (idx >= tot) return;
    int p = (int)(idx >> 5), col = (int)(idx & 31);
    int e = sE[p];
    float v = spf(ea[2 * e] * Wep[col] + ea[2 * e + 1] * Wep[32 + col] + bep[col]);
    e_bf[idx] = f2bf(v);
}

// ---- weight pack: W[K][128] (+bias as extra kstep) -> A-frag layout ----
// data ksteps: out[((ks*8+nf)*64+l)*8+r] = bf16(W[32ks+8*(l>>4)+r][16nf+(l&15)])
// bias kstep (ks==nk): A[k=0][n] = bias[n], else 0  (pairs with ones-B at k=0)
__global__ __launch_bounds__(256) void k_pack_w(
    const float* __restrict__ W, const float* __restrict__ bias,
    unsigned short* __restrict__ out, int nk_data) {
    int tid = blockIdx.x * blockDim.x + threadIdx.x;
    int total = (nk_data + 1) * 8 * 64;
    if (tid >= total) return;
    int l = tid & 63; int fr = tid >> 6; int nf = fr & 7; int ks = fr >> 3;
    int n = 16 * nf + (l & 15);
    if (ks < nk_data) {
        int k0 = 32 * ks + 8 * (l >> 4);
#pragma unroll
        for (int r = 0; r < 8; ++r)
            out[tid * 8 + r] = f2bf(W[(k0 + r) * 128 + n]);
    } else {
#pragma unroll
        for (int r = 0; r < 8; ++r)
            out[tid * 8 + r] = ((l >> 4) == 0 && r == 0) ? f2bf(bias[n]) : (unsigned short)0;
    }
}

// ---------------- node-centric MFMA edge conv (CSR, no atomics) ---------
// Register-minimal: carried state = 2 floats (rs0/rs1) via per-tile
// cndmask-butterfly m-reduction; biases folded into packed A (no per-tile
// bias loads); GEMMs split into quarters (2 nf) to bound transients.
template <bool EPRE>
__global__ __launch_bounds__(256, 2) void k_edge_node(
    const unsigned short* __restrict__ h_bf, const unsigned short* __restrict__ e_bf,
    const float* __restrict__ ea, const int* __restrict__ sE,
    const float* __restrict__ Wep, const float* __restrict__ bep,
    const int* __restrict__ rowptr, const int* __restrict__ hist,
    const int* __restrict__ sS,
    const unsigned short* __restrict__ pA1,
    const unsigned short* __restrict__ pA2,
    float* __restrict__ aggr) {
    __shared__ unsigned short P[WPB][16][136];

    int lane = threadIdx.x & 63;
    int w = threadIdx.x >> 6;
    int m = lane & 15, g = lane >> 4;
    int node = blockIdx.x * WPB + w;
    if (node >= N_NODES) return;
    int start = rowptr[node];
    int deg = hist[node];

    // loop-invariant: dst-node fragments + ones-vector for the bias kstep
    bf16x8 bn0 = *(const bf16x8*)(h_bf + (size_t)node * 64 + 8 * g);
    bf16x8 bn1 = *(const bf16x8*)(h_bf + (size_t)node * 64 + 32 + 8 * g);
    bf16x8 bias_b = (bf16x8){0, 0, 0, 0, 0, 0, 0, 0};
    if (g == 0) bias_b[0] = (short)0x3F80;  // bf16(1.0) at k-row 0

    float rs0 = 0.f, rs1 = 0.f;

    int nt = (deg + 15) >> 4;
    for (int t = 0; t < nt; ++t) {
        int rem = deg - (t << 4);           // > 0
        int me = min(m, rem - 1);           // clamped edge slot
        int p = start + (t << 4) + me;      // sorted edge position
        int src = sS[p];
        bool valid = (m < rem);

        bf16x8 B1[6];
        B1[0] = bn0; B1[1] = bn1;
        B1[2] = *(const bf16x8*)(h_bf + (size_t)src * 64 + 8 * g);
        B1[3] = *(const bf16x8*)(h_bf + (size_t)src * 64 + 32 + 8 * g);
        if constexpr (EPRE) {
            B1[4] = *(const bf16x8*)(e_bf + (size_t)p * 32 + 8 * g);
        } else {
            int eo = sE[p];
            float a0 = ea[2 * eo], a1 = ea[2 * eo + 1];
            bf16x8 bt;
#pragma unroll
            for (int r = 0; r < 8; ++r) {
                int col = 8 * g + r;
                bt[r] = (short)f2bf(spf(a0 * Wep[col] + a1 * Wep[32 + col] + bep[col]));
            }
            B1[4] = bt;
        }
        B1[5] = bias_b;

        // ---- GEMM1 (K=160 + bias kstep) in 4 quarters of 2 nf ----
#pragma unroll
        for (int qt = 0; qt < 4; ++qt) {
            f32x4 a0 = (f32x4){0.f, 0.f, 0.f, 0.f};
            f32x4 a1 = (f32x4){0.f, 0.f, 0.f, 0.f};
#pragma unroll
            for (int ks = 0; ks < 6; ++ks) {
                bf16x8 A0 = *(const bf16x8*)(pA1 + ((ks * 8 + 2 * qt) * 64 + lane) * 8);
                bf16x8 A1 = *(const bf16x8*)(pA1 + ((ks * 8 + 2 * qt + 1) * 64 + lane) * 8);
                a0 = __builtin_amdgcn_mfma_f32_16x16x32_bf16(A0, B1[ks], a0, 0, 0, 0);
                a1 = __builtin_amdgcn_mfma_f32_16x16x32_bf16(A1, B1[ks], a1, 0, 0, 0);
            }
            // epilogue: softplus -> P (bias already in accumulator)
            unsigned int* d0 = (unsigned int*)&P[w][m][16 * (2 * qt) + 4 * g];
            d0[0] = pkbf(spf(a0[0]), spf(a0[1]));
            d0[1] = pkbf(spf(a0[2]), spf(a0[3]));
            unsigned int* d1 = (unsigned int*)&P[w][m][16 * (2 * qt + 1) + 4 * g];
            d1[0] = pkbf(spf(a1[0]), spf(a1[1]));
            d1[1] = pkbf(spf(a1[2]), spf(a1[3]));
        }

        // ---- GEMM2 (K=128 + bias kstep) ----
        bf16x8 B2[5];
#pragma unroll
        for (int ks = 0; ks < 4; ++ks)
            B2[ks] = *(const bf16x8*)&P[w][m][32 * ks + 8 * g];
        B2[4] = bias_b;

        float v[32];
#pragma unroll
        for (int qt = 0; qt < 4; ++qt) {
            f32x4 a0 = (f32x4){0.f, 0.f, 0.f, 0.f};
            f32x4 a1 = (f32x4){0.f, 0.f, 0.f, 0.f};
#pragma unroll
            for (int ks = 0; ks < 5; ++ks) {
                bf16x8 A0 = *(const bf16x8*)(pA2 + ((ks * 8 + 2 * qt) * 64 + lane) * 8);
                bf16x8 A1 = *(const bf16x8*)(pA2 + ((ks * 8 + 2 * qt + 1) * 64 + lane) * 8);
                a0 = __builtin_amdgcn_mfma_f32_16x16x32_bf16(A0, B2[ks], a0, 0, 0, 0);
                a1 = __builtin_amdgcn_mfma_f32_16x16x32_bf16(A1, B2[ks], a1, 0, 0, 0);
            }
#pragma unroll
            for (int j = 0; j < 4; ++j) {
                v[(2 * qt) * 4 + j]     = valid ? spf(a0[j]) : 0.f;
                v[(2 * qt + 1) * 4 + j] = valid ? spf(a1[j]) : 0.f;
            }
        }

        // ---- butterfly m-reduction: 32 values -> 2 per lane ----
#pragma unroll
        for (int k = 0; k < 4; ++k) {
            int half = 16 >> k;
            bool bs = (m >> k) & 1;
#pragma unroll
            for (int i = 0; i < 16; ++i) {   // only i < half active
                if (i < half) {
                    float keep = bs ? v[i + half] : v[i];
                    float send = bs ? v[i] : v[i + half];
                    v[i] = keep + __shfl_xor(send, 1 << k);
                }
            }
        }
        rs0 += v[0];
        rs1 += v[1];
    }

    // lane (m,g) owns channels idx = bitrev4(m)*2 + {0,1}
    int rev = ((m & 1) << 3) | ((m & 2) << 1) | ((m & 4) >> 1) | ((m & 8) >> 3);
    int i0 = rev * 2;
    int ch0 = ((i0 >> 2) << 4) + 4 * g + (i0 & 3);   // 16*nf + 4g + j
    float* base = aggr + (size_t)node * HD;
    base[ch0] = rs0;
    base[ch0 + 1] = rs1;   // i1 = i0+1: same nf, j+1
}

// ---------------- node update (fp32, unchanged) -------------------------
__global__ __launch_bounds__(256) void k_node_update(
    const float* __restrict__ h, const float* __restrict__ aggr,
    const float* __restrict__ Wn1, const float* __restrict__ bn1,
    const float* __restrict__ Wn2, const float* __restrict__ bn2,
    float* __restrict__ t, float* __restrict__ stats) {
    __shared__ float zb[WPB][ND + HD];
    __shared__ float pb[WPB][HD];
    int lane = threadIdx.x & 63;
    int wid = threadIdx.x >> 6;
    int wave = (blockIdx.x * blockDim.x + threadIdx.x) >> 6;
    int nw = (gridDim.x * blockDim.x) >> 6;
    int iters = (N_NODES + nw - 1) / nw;
    float s0 = 0.f, s1 = 0.f;
    for (int it = 0; it < iters; ++it) {
        int i = wave + it * nw;
        bool valid = i < N_NODES;
        int ic = valid ? i : N_NODES - 1;
        float hv = h[ic * ND + lane];
        zb[wid][lane] = hv;
        zb[wid][ND + lane] = aggr[ic * HD + lane];
        zb[wid][ND + 64 + lane] = aggr[ic * HD + 64 + lane];
        __syncthreads();
        float h0 = bn1[lane], h1 = bn1[64 + lane];
#pragma unroll 8
        for (int k = 0; k < ND + HD; ++k) {
            float zk = zb[wid][k];
            h0 += zk * Wn1[k * HD + lane];
            h1 += zk * Wn1[k * HD + 64 + lane];
        }
        pb[wid][lane] = sp(h0);
        pb[wid][64 + lane] = sp(h1);
        __syncthreads();
        float o = bn2[lane];
#pragma unroll 8
        for (int k = 0; k < HD; ++k) o += pb[wid][k] * Wn2[k * ND + lane];
        if (valid) {
            float tn = o + hv;
            t[ic * ND + lane] = tn;
            s0 += tn; s1 += tn * tn;
        }
        __syncthreads();
    }
    atomicAdd(&stats[lane], s0);
    atomicAdd(&stats[ND + lane], s1);
}

// ---------------- pooling + readout (unchanged) -------------------------
__global__ __launch_bounds__(256) void k_pool(
    const float* __restrict__ h, const int* __restrict__ batch,
    float* __restrict__ pooled, float* __restrict__ cnt) {
    int lane = threadIdx.x & 63;
    int wave = (blockIdx.x * blockDim.x + threadIdx.x) >> 6;
    int nw = (gridDim.x * blockDim.x) >> 6;
    int chunk = (N_NODES + nw - 1) / nw;
    int s = wave * chunk;
    int epos = min(N_NODES, s + chunk);
    if (s >= N_NODES) return;
    int curg = batch[s];
    float acc = 0.f, c = 0.f;
    for (int i = s; i < epos; ++i) {
        int g = batch[i];
        if (g != curg) {
            atomicAdd(&pooled[curg * ND + lane], acc);
            if (lane == 0) atomicAdd(&cnt[curg], c);
            acc = 0.f; c = 0.f; curg = g;
        }
        acc += h[i * ND + lane];
        c += 1.f;
    }
    atomicAdd(&pooled[curg * ND + lane], acc);
    if (lane == 0) atomicAdd(&cnt[curg], c);
}

__global__ __launch_bounds__(256) void k_readout(
    const float* __restrict__ pooled, const float* __restrict__ cnt,
    const float* __restrict__ Wo1, const float* __restrict__ bo1,
    const float* __restrict__ Wo2, const float* __restrict__ bo2,
    float* __restrict__ out) {
    __shared__ float pbuf[WPB][ND];
    int lane = threadIdx.x & 63;
    int wid = threadIdx.x >> 6;
    int g = blockIdx.x * WPB + wid;
    bool valid = g < N_GRAPH;
    int gc = valid ? g : N_GRAPH - 1;
    float c = fmaxf(cnt[gc], 1.f);
    pbuf[wid][lane] = pooled[gc * ND + lane] / c;
    __syncthreads();
    float h0 = bo1[lane], h1 = bo1[64 + lane];
#pragma unroll 8
    for (int k = 0; k < ND; ++k) {
        float pk = pbuf[wid][k];
        h0 += pk * Wo1[k * HD + lane];
        h1 += pk * Wo1[k * HD + 64 + lane];
    }
    float s = sp(h0) * Wo2[lane] + sp(h1) * Wo2[64 + lane];
#pragma unroll
    for (int off = 32; off; off >>= 1) s += __shfl_down(s, off);
    if (valid && lane == 0) out[g] = s + bo2[0];
}

extern "C" void kernel_launch(void* const* d_in, const int* in_sizes, int n_in,
                              void* d_out, int out_size, void* d_ws, size_t ws_size,
                              hipStream_t stream) {
    const float* x       = (const float*)d_in[0];
    const float* ea      = (const float*)d_in[1];
    const int*   ei      = (const int*)d_in[2];
    const int*   batch   = (const int*)d_in[3];
    const float* Wnp     = (const float*)d_in[4];
    const float* bnp     = (const float*)d_in[5];
    const float* g_np    = (const float*)d_in[6];
    const float* be_np   = (const float*)d_in[7];
    const float* Wep     = (const float*)d_in[8];
    const float* bep     = (const float*)d_in[9];
    const float* We1     = (const float*)d_in[10];
    const float* be1     = (const float*)d_in[11];
    const float* We2     = (const float*)d_in[12];
    const float* be2     = (const float*)d_in[13];
    const float* Wn1     = (const float*)d_in[14];
    const float* bn1     = (const float*)d_in[15];
    const float* Wn2     = (const float*)d_in[16];
    const float* bn2     = (const float*)d_in[17];
    const float* g_bn    = (const float*)d_in[18];
    const float* b_bn    = (const float*)d_in[19];
    const float* Wo1     = (const float*)d_in[20];
    const float* bo1     = (const float*)d_in[21];
    const float* Wo2     = (const float*)d_in[22];
    const float* bo2     = (const float*)d_in[23];

    float* ws = (float*)d_ws;
    size_t off = 0;
    float* h      = ws + off; off += (size_t)N_NODES * ND;
    float* t      = ws + off; off += (size_t)N_NODES * ND;
    float* aggr   = ws + off; off += (size_t)N_NODES * HD;
    float* stats  = ws + off; off += 2 * ND;
    float* ss     = ws + off; off += 2 * ND;
    float* pooled = ws + off; off += N_GRAPH * ND;
    float* cnt    = ws + off; off += 512;
    unsigned short* h_bf = (unsigned short*)(ws + off); off += (size_t)N_NODES * ND / 2;
    unsigned short* pA1  = (unsigned short*)(ws + off); off += 6 * 8 * 64 * 8 / 2;
    unsigned short* pA2  = (unsigned short*)(ws + off); off += 5 * 8 * 64 * 8 / 2;
    int* sS       = (int*)(ws + off); off += N_EDGES;
    int* sE       = (int*)(ws + off); off += N_EDGES;
    int* hist     = (int*)(ws + off); off += N_NODES;
    int* cursor   = (int*)(ws + off); off += N_NODES;
    int* rowptr   = (int*)(ws + off); off += N_NODES;
    int* chunksum = (int*)(ws + off); off += 64;
    size_t base_bytes = off * sizeof(float);
    unsigned short* e_bf = (unsigned short*)(ws + off);
    bool epre = (ws_size >= base_bytes + (size_t)N_EDGES * 32 * 2);

    float* outp = (float*)d_out;

    const int NCH = (N_NODES + 1023) / 1024;  // 49

    // ---- counting sort of edges by dst -> CSR (once per call) ----
    hipMemsetAsync(hist, 0, N_NODES * sizeof(int), stream);
    k_hist<<<(N_EDGES + 255) / 256, 256, 0, stream>>>(ei, hist);
    k_scan1<<<NCH, 1024, 0, stream>>>(hist, chunksum);
    k_scan2<<<1, 64, 0, stream>>>(chunksum, NCH);
    k_scan3<<<NCH, 1024, 0, stream>>>(hist, chunksum, cursor, rowptr);
    k_scatter<<<(N_EDGES + 255) / 256, 256, 0, stream>>>(ei, cursor, sS, sE);
    if (epre)
        k_eproj_sorted<<<(int)(((long)N_EDGES * 32 + 255) / 256), 256, 0, stream>>>(
            ea, sE, Wep, bep, e_bf);

    // ---- node projection + BN ----
    hipMemsetAsync(stats, 0, 2 * ND * sizeof(float), stream);
    k_node_proj<<<512, 256, 0, stream>>>(x, Wnp, bnp, t, stats);
    k_bn_finalize<<<1, 64, 0, stream>>>(stats, g_np, be_np, ss);
    k_bn_apply<<<2048, 256, 0, stream>>>(t, ss, h, h_bf);

    for (int l = 0; l < 3; ++l) {
        k_pack_w<<<(6 * 8 * 64 + 255) / 256, 256, 0, stream>>>(
            We1 + (size_t)l * 160 * HD, be1 + l * HD, pA1, 5);
        k_pack_w<<<(5 * 8 * 64 + 255) / 256, 256, 0, stream>>>(
            We2 + (size_t)l * HD * HD, be2 + l * HD, pA2, 4);

        if (epre)
            k_edge_node<true><<<(N_NODES + WPB - 1) / WPB, 256, 0, stream>>>(
                h_bf, e_bf, ea, sE, Wep, bep, rowptr, hist, sS, pA1, pA2, aggr);
        else
            k_edge_node<false><<<(N_NODES + WPB - 1) / WPB, 256, 0, stream>>>(
                h_bf, e_bf, ea, sE, Wep, bep, rowptr, hist, sS, pA1, pA2, aggr);

        hipMemsetAsync(stats, 0, 2 * ND * sizeof(float), stream);
        k_node_update<<<512, 256, 0, stream>>>(
            h, aggr,
            Wn1 + (size_t)l * (ND + HD) * HD, bn1 + l * HD,
            Wn2 + (size_t)l * HD * ND, bn2 + l * ND, t, stats);
        k_bn_finalize<<<1, 64, 0, stream>>>(stats, g_bn + l * ND, b_bn + l * ND, ss);
        k_bn_apply<<<2048, 256, 0, stream>>>(t, ss, h, h_bf);
    }

    hipMemsetAsync(pooled, 0, (size_t)(N_GRAPH * ND + 512) * sizeof(float), stream);
    k_pool<<<512, 256, 0, stream>>>(h, batch, pooled, cnt);
    k_readout<<<(N_GRAPH + WPB - 1) / WPB, 256, 0, stream>>>(
        pooled, cnt, Wo1, bo1, Wo2, bo2, outp);
}

// Round 11
// 1998.310 us; speedup vs baseline: 3.9182x; 3.9182x over previous
//
#include <hip/hip_runtime.h>
#include <hip/hip_bf16.h>

#define N_NODES 50000
#define N_EDGES 800000
#define N_GRAPH 500
#define ND 64
#define ED 32
#define HD 128
#define WPB 4   // waves per block (256 threads)

typedef __attribute__((ext_vector_type(8))) short bf16x8;
typedef __attribute__((ext_vector_type(4))) float f32x4;

__device__ __forceinline__ float sp(float x) {
    return fmaxf(x, 0.f) + log1pf(expf(-fabsf(x)));
}

// fast softplus for the bf16 edge path (v_exp_f32/v_log_f32 based)
__device__ __forceinline__ float spf(float x) {
    return fmaxf(x, 0.f) + __logf(1.f + __expf(-fabsf(x)));
}

__device__ __forceinline__ unsigned short f2bf(float v) {
    __hip_bfloat16 b = __float2bfloat16(v);
    return *(unsigned short*)&b;
}

__device__ __forceinline__ unsigned int pkbf(float a, float b) {
    return (unsigned int)f2bf(a) | ((unsigned int)f2bf(b) << 16);
}

// ---------------- node projection + BN (fp32) ---------------------------
__global__ __launch_bounds__(256) void k_node_proj(
    const float* __restrict__ x, const float* __restrict__ Wnp,
    const float* __restrict__ bnp, float* __restrict__ t,
    float* __restrict__ stats) {
    int lane = threadIdx.x & 63;
    int wave = (blockIdx.x * blockDim.x + threadIdx.x) >> 6;
    int nw = (gridDim.x * blockDim.x) >> 6;
    float w[13];
#pragma unroll
    for (int k = 0; k < 13; ++k) w[k] = Wnp[k * ND + lane];
    float bb = bnp[lane];
    float s0 = 0.f, s1 = 0.f;
    for (int i = wave; i < N_NODES; i += nw) {
        float acc = bb;
#pragma unroll
        for (int k = 0; k < 13; ++k) acc += x[i * 13 + k] * w[k];
        float v = sp(acc);
        t[i * ND + lane] = v;
        s0 += v; s1 += v * v;
    }
    atomicAdd(&stats[lane], s0);
    atomicAdd(&stats[ND + lane], s1);
}

__global__ void k_bn_finalize(const float* __restrict__ stats,
                              const float* __restrict__ g,
                              const float* __restrict__ b,
                              float* __restrict__ ss) {
    int j = threadIdx.x;
    if (j >= ND) return;
    float inv_n = 1.f / (float)N_NODES;
    float mu = stats[j] * inv_n;
    float var = stats[ND + j] * inv_n - mu * mu;
    float rs = rsqrtf(var + 1e-5f);
    float sc = rs * g[j];
    ss[j] = sc;
    ss[ND + j] = b[j] - mu * sc;
}

__global__ __launch_bounds__(256) void k_bn_apply(
    const float* __restrict__ t, const float* __restrict__ ss,
    float* __restrict__ h, unsigned short* __restrict__ hb) {
    int idx = blockIdx.x * blockDim.x + threadIdx.x;
    int tot = N_NODES * ND;
    int stride = gridDim.x * blockDim.x;
    for (; idx < tot; idx += stride) {
        int c = idx & (ND - 1);
        float v = t[idx] * ss[c] + ss[ND + c];
        h[idx] = v;
        hb[idx] = f2bf(v);
    }
}

// ---------------- counting sort of edges by dst -------------------------
__global__ __launch_bounds__(256) void k_hist(const int* __restrict__ ei,
                                              int* __restrict__ hist) {
    int e = blockIdx.x * 256 + threadIdx.x;
    if (e < N_EDGES) atomicAdd(&hist[ei[N_EDGES + e]], 1);
}

__global__ __launch_bounds__(1024) void k_scan1(const int* __restrict__ hist,
                                                int* __restrict__ chunksum) {
    __shared__ int s[1024];
    int t = threadIdx.x;
    int i = blockIdx.x * 1024 + t;
    s[t] = (i < N_NODES) ? hist[i] : 0;
    __syncthreads();
    for (int off = 512; off; off >>= 1) {
        if (t < off) s[t] += s[t + off];
        __syncthreads();
    }
    if (t == 0) chunksum[blockIdx.x] = s[0];
}

__global__ void k_scan2(int* __restrict__ chunksum, int n) {
    if (threadIdx.x == 0) {
        int acc = 0;
        for (int i = 0; i < n; ++i) { int v = chunksum[i]; chunksum[i] = acc; acc += v; }
    }
}

__global__ __launch_bounds__(1024) void k_scan3(const int* __restrict__ hist,
                                                const int* __restrict__ chunksum,
                                                int* __restrict__ cursor) {
    __shared__ int s[1024];
    int t = threadIdx.x;
    int i = blockIdx.x * 1024 + t;
    int v = (i < N_NODES) ? hist[i] : 0;
    s[t] = v;
    __syncthreads();
    for (int off = 1; off < 1024; off <<= 1) {
        int u = (t >= off) ? s[t - off] : 0;
        __syncthreads();
        s[t] += u;
        __syncthreads();
    }
    if (i < N_NODES) cursor[i] = chunksum[blockIdx.x] + s[t] - v;  // exclusive
}

__global__ __launch_bounds__(256) void k_scatter(const int* __restrict__ ei,
                                                 int* __restrict__ cursor,
                                                 int* __restrict__ sD,
                                                 int* __restrict__ sS,
                                                 int* __restrict__ sE) {
    int e = blockIdx.x * 256 + threadIdx.x;
    if (e >= N_EDGES) return;
    int d = ei[N_EDGES + e];
    int pos = atomicAdd(&cursor[d], 1);
    sD[pos] = d;
    sS[pos] = ei[e];
    sE[pos] = e;
}

// edge projection into sorted order (layer-invariant, once per call)
__global__ __launch_bounds__(256) void k_eproj_sorted(
    const float* __restrict__ ea, const int* __restrict__ sE,
    const float* __restrict__ Wep, const float* __restrict__ bep,
    unsigned short* __restrict__ e_bf) {
    long idx = (long)blockIdx.x * blockDim.x + threadIdx.x;
    long tot = (long)N_EDGES * 32;
    if (idx >= tot) return;
    int p = (int)(idx >> 5), col = (int)(idx & 31);
    int e = sE[p];
    float v = spf(ea[2 * e] * Wep[col] + ea[2 * e + 1] * Wep[32 + col] + bep[col]);
    e_bf[idx] = f2bf(v);
}

// ---------------- weight pack: W[K][128] -> A-frag layout ---------------
__global__ __launch_bounds__(256) void k_pack_w(
    const float* __restrict__ W, unsigned short* __restrict__ out, int ksteps) {
    int tid = blockIdx.x * blockDim.x + threadIdx.x;
    int total = ksteps * 8 * 64;
    if (tid >= total) return;
    int l = tid & 63; int fr = tid >> 6; int nf = fr & 7; int ks = fr >> 3;
    int n = 16 * nf + (l & 15);
    int k0 = 32 * ks + 8 * (l >> 4);
#pragma unroll
    for (int r = 0; r < 8; ++r)
        out[tid * 8 + r] = f2bf(W[(k0 + r) * 128 + n]);
}

// ---------------- MFMA edge conv on dst-sorted edges --------------------
// Per block: 128 sorted edges. Per wave: 32 edges. Epilogue stages results
// fp32 in LDS (reusing P) and does run-length segmented reduction: one
// atomicAdd per (run, channel) instead of per (edge, channel).
// (256,2): 256-reg budget -> acc[2][8] AGPRs + hoisted A-frags fit without
// scratch spill (round-6's (256,4) 128-reg cap caused ~500 MB spill traffic).
template <bool EPRE>
__global__ __launch_bounds__(256, 2) void k_edge_mfma_s(
    const unsigned short* __restrict__ h_bf, const unsigned short* __restrict__ e_bf,
    const float* __restrict__ ea, const int* __restrict__ sE,
    const float* __restrict__ Wep, const float* __restrict__ bep,
    const int* __restrict__ sD, const int* __restrict__ sS,
    const unsigned short* __restrict__ pA1, const float* __restrict__ be1,
    const unsigned short* __restrict__ pA2, const float* __restrict__ be2,
    float* __restrict__ aggr) {
    __shared__ unsigned short P[WPB][32][136];   // bf16 P; reused as fp32 stage
    __shared__ int dstS[WPB][16];
    __shared__ unsigned short eL[EPRE ? 64 : 128 * 32];

    int lane = threadIdx.x & 63;
    int w = threadIdx.x >> 6;
    int m = lane & 15, g = lane >> 4;
    int tile0 = blockIdx.x * 128;
    int wbase = tile0 + 32 * w;

    int eD0 = sD[wbase + m];
    int eD1 = sD[wbase + 16 + m];
    int eS0 = sS[wbase + m];
    int eS1 = sS[wbase + 16 + m];

    if constexpr (!EPRE) {
        int col = threadIdx.x & 31;
        int r0 = threadIdx.x >> 5;
        float w0 = Wep[col], w1 = Wep[32 + col], bb = bep[col];
#pragma unroll
        for (int i = 0; i < 16; ++i) {
            int em = r0 + 8 * i;
            int e = sE[tile0 + em];
            eL[em * 32 + col] = f2bf(spf(ea[2 * e] * w0 + ea[2 * e + 1] * w1 + bb));
        }
        __syncthreads();
    }

    f32x4 acc[2][8];
#pragma unroll
    for (int mf = 0; mf < 2; ++mf)
#pragma unroll
        for (int nf = 0; nf < 8; ++nf) acc[mf][nf] = (f32x4){0.f, 0.f, 0.f, 0.f};

    // ---- GEMM1: K = 160 (dst 64 | src 64 | e 32) ----
#pragma unroll
    for (int ks = 0; ks < 5; ++ks) {
        bf16x8 b0, b1;
        if (ks < 2) {
            b0 = *(const bf16x8*)(h_bf + (size_t)eD0 * 64 + ks * 32 + 8 * g);
            b1 = *(const bf16x8*)(h_bf + (size_t)eD1 * 64 + ks * 32 + 8 * g);
        } else if (ks < 4) {
            b0 = *(const bf16x8*)(h_bf + (size_t)eS0 * 64 + (ks - 2) * 32 + 8 * g);
            b1 = *(const bf16x8*)(h_bf + (size_t)eS1 * 64 + (ks - 2) * 32 + 8 * g);
        } else {
            if constexpr (EPRE) {
                b0 = *(const bf16x8*)(e_bf + (size_t)(wbase + m) * 32 + 8 * g);
                b1 = *(const bf16x8*)(e_bf + (size_t)(wbase + 16 + m) * 32 + 8 * g);
            } else {
                b0 = *(const bf16x8*)&eL[(32 * w + m) * 32 + 8 * g];
                b1 = *(const bf16x8*)&eL[(32 * w + 16 + m) * 32 + 8 * g];
            }
        }
#pragma unroll
        for (int nf = 0; nf < 8; ++nf) {
            bf16x8 a = *(const bf16x8*)(pA1 + ((ks * 8 + nf) * 64 + lane) * 8);
            acc[0][nf] = __builtin_amdgcn_mfma_f32_16x16x32_bf16(a, b0, acc[0][nf], 0, 0, 0);
            acc[1][nf] = __builtin_amdgcn_mfma_f32_16x16x32_bf16(a, b1, acc[1][nf], 0, 0, 0);
        }
    }

    // ---- epilogue 1: bias + fast softplus -> P (bf16) in LDS ----
#pragma unroll
    for (int nf = 0; nf < 8; ++nf) {
        f32x4 bb = *(const f32x4*)(be1 + 16 * nf + 4 * g);
#pragma unroll
        for (int mf = 0; mf < 2; ++mf) {
            f32x4 c = acc[mf][nf];
            unsigned int u01 = pkbf(spf(c[0] + bb[0]), spf(c[1] + bb[1]));
            unsigned int u23 = pkbf(spf(c[2] + bb[2]), spf(c[3] + bb[3]));
            unsigned int* dst = (unsigned int*)&P[w][m + 16 * mf][16 * nf + 4 * g];
            dst[0] = u01; dst[1] = u23;
        }
    }

    f32x4 acc2[2][8];
#pragma unroll
    for (int mf = 0; mf < 2; ++mf)
#pragma unroll
        for (int nf = 0; nf < 8; ++nf) acc2[mf][nf] = (f32x4){0.f, 0.f, 0.f, 0.f};

    // ---- GEMM2: K = 128, B = P^T from LDS (wave-private rows) ----
#pragma unroll
    for (int ks = 0; ks < 4; ++ks) {
        bf16x8 b0 = *(const bf16x8*)&P[w][m][32 * ks + 8 * g];
        bf16x8 b1 = *(const bf16x8*)&P[w][m + 16][32 * ks + 8 * g];
#pragma unroll
        for (int nf = 0; nf < 8; ++nf) {
            bf16x8 a = *(const bf16x8*)(pA2 + ((ks * 8 + nf) * 64 + lane) * 8);
            acc2[0][nf] = __builtin_amdgcn_mfma_f32_16x16x32_bf16(a, b0, acc2[0][nf], 0, 0, 0);
            acc2[1][nf] = __builtin_amdgcn_mfma_f32_16x16x32_bf16(a, b1, acc2[1][nf], 0, 0, 0);
        }
    }

    __syncthreads();  // fence: P (bf16) reads done before fp32 reuse

    // ---- epilogue 2: stage fp32 rows, run-length segmented reduce ------
    float* st = (float*)&P[w][0][0];  // 16 rows x 132 floats = 8448B <= 8704B
#pragma unroll 1
    for (int mf = 0; mf < 2; ++mf) {
        int d = mf ? eD1 : eD0;
        dstS[w][m] = d;  // all g write same value
#pragma unroll
        for (int nf = 0; nf < 8; ++nf) {
            f32x4 bb = *(const f32x4*)(be2 + 16 * nf + 4 * g);
            f32x4 c = acc2[mf][nf];
            f32x4 v = { spf(c[0] + bb[0]), spf(c[1] + bb[1]),
                        spf(c[2] + bb[2]), spf(c[3] + bb[3]) };
            *(f32x4*)&st[m * 132 + 16 * nf + 4 * g] = v;
        }
        asm volatile("" ::: "memory");
        float a0 = 0.f, a1 = 0.f;
        int cur = dstS[w][0];
#pragma unroll 1
        for (int r = 0; r < 16; ++r) {
            int dr = dstS[w][r];               // wave-uniform
            if (dr != cur) {                   // uniform branch
                atomicAdd(&aggr[(size_t)cur * HD + lane], a0);
                atomicAdd(&aggr[(size_t)cur * HD + 64 + lane], a1);
                a0 = 0.f; a1 = 0.f; cur = dr;
            }
            a0 += st[r * 132 + lane];
            a1 += st[r * 132 + 64 + lane];
        }
        atomicAdd(&aggr[(size_t)cur * HD + lane], a0);
        atomicAdd(&aggr[(size_t)cur * HD + 64 + lane], a1);
        asm volatile("" ::: "memory");
    }
}

// ---------------- node update (fp32, unchanged) -------------------------
__global__ __launch_bounds__(256) void k_node_update(
    const float* __restrict__ h, const float* __restrict__ aggr,
    const float* __restrict__ Wn1, const float* __restrict__ bn1,
    const float* __restrict__ Wn2, const float* __restrict__ bn2,
    float* __restrict__ t, float* __restrict__ stats) {
    __shared__ float zb[WPB][ND + HD];
    __shared__ float pb[WPB][HD];
    int lane = threadIdx.x & 63;
    int wid = threadIdx.x >> 6;
    int wave = (blockIdx.x * blockDim.x + threadIdx.x) >> 6;
    int nw = (gridDim.x * blockDim.x) >> 6;
    int iters = (N_NODES + nw - 1) / nw;
    float s0 = 0.f, s1 = 0.f;
    for (int it = 0; it < iters; ++it) {
        int i = wave + it * nw;
        bool valid = i < N_NODES;
        int ic = valid ? i : N_NODES - 1;
        float hv = h[ic * ND + lane];
        zb[wid][lane] = hv;
        zb[wid][ND + lane] = aggr[ic * HD + lane];
        zb[wid][ND + 64 + lane] = aggr[ic * HD + 64 + lane];
        __syncthreads();
        float h0 = bn1[lane], h1 = bn1[64 + lane];
#pragma unroll 8
        for (int k = 0; k < ND + HD; ++k) {
            float zk = zb[wid][k];
            h0 += zk * Wn1[k * HD + lane];
            h1 += zk * Wn1[k * HD + 64 + lane];
        }
        pb[wid][lane] = sp(h0);
        pb[wid][64 + lane] = sp(h1);
        __syncthreads();
        float o = bn2[lane];
#pragma unroll 8
        for (int k = 0; k < HD; ++k) o += pb[wid][k] * Wn2[k * ND + lane];
        if (valid) {
            float tn = o + hv;
            t[ic * ND + lane] = tn;
            s0 += tn; s1 += tn * tn;
        }
        __syncthreads();
    }
    atomicAdd(&stats[lane], s0);
    atomicAdd(&stats[ND + lane], s1);
}

// ---------------- pooling + readout (unchanged) -------------------------
__global__ __launch_bounds__(256) void k_pool(
    const float* __restrict__ h, const int* __restrict__ batch,
    float* __restrict__ pooled, float* __restrict__ cnt) {
    int lane = threadIdx.x & 63;
    int wave = (blockIdx.x * blockDim.x + threadIdx.x) >> 6;
    int nw = (gridDim.x * blockDim.x) >> 6;
    int chunk = (N_NODES + nw - 1) / nw;
    int s = wave * chunk;
    int epos = min(N_NODES, s + chunk);
    if (s >= N_NODES) return;
    int curg = batch[s];
    float acc = 0.f, c = 0.f;
    for (int i = s; i < epos; ++i) {
        int g = batch[i];
        if (g != curg) {
            atomicAdd(&pooled[curg * ND + lane], acc);
            if (lane == 0) atomicAdd(&cnt[curg], c);
            acc = 0.f; c = 0.f; curg = g;
        }
        acc += h[i * ND + lane];
        c += 1.f;
    }
    atomicAdd(&pooled[curg * ND + lane], acc);
    if (lane == 0) atomicAdd(&cnt[curg], c);
}

__global__ __launch_bounds__(256) void k_readout(
    const float* __restrict__ pooled, const float* __restrict__ cnt,
    const float* __restrict__ Wo1, const float* __restrict__ bo1,
    const float* __restrict__ Wo2, const float* __restrict__ bo2,
    float* __restrict__ out) {
    __shared__ float pbuf[WPB][ND];
    int lane = threadIdx.x & 63;
    int wid = threadIdx.x >> 6;
    int g = blockIdx.x * WPB + wid;
    bool valid = g < N_GRAPH;
    int gc = valid ? g : N_GRAPH - 1;
    float c = fmaxf(cnt[gc], 1.f);
    pbuf[wid][lane] = pooled[gc * ND + lane] / c;
    __syncthreads();
    float h0 = bo1[lane], h1 = bo1[64 + lane];
#pragma unroll 8
    for (int k = 0; k < ND; ++k) {
        float pk = pbuf[wid][k];
        h0 += pk * Wo1[k * HD + lane];
        h1 += pk * Wo1[k * HD + 64 + lane];
    }
    float s = sp(h0) * Wo2[lane] + sp(h1) * Wo2[64 + lane];
#pragma unroll
    for (int off = 32; off; off >>= 1) s += __shfl_down(s, off);
    if (valid && lane == 0) out[g] = s + bo2[0];
}

extern "C" void kernel_launch(void* const* d_in, const int* in_sizes, int n_in,
                              void* d_out, int out_size, void* d_ws, size_t ws_size,
                              hipStream_t stream) {
    const float* x       = (const float*)d_in[0];
    const float* ea      = (const float*)d_in[1];
    const int*   ei      = (const int*)d_in[2];
    const int*   batch   = (const int*)d_in[3];
    const float* Wnp     = (const float*)d_in[4];
    const float* bnp     = (const float*)d_in[5];
    const float* g_np    = (const float*)d_in[6];
    const float* be_np   = (const float*)d_in[7];
    const float* Wep     = (const float*)d_in[8];
    const float* bep     = (const float*)d_in[9];
    const float* We1     = (const float*)d_in[10];
    const float* be1     = (const float*)d_in[11];
    const float* We2     = (const float*)d_in[12];
    const float* be2     = (const float*)d_in[13];
    const float* Wn1     = (const float*)d_in[14];
    const float* bn1     = (const float*)d_in[15];
    const float* Wn2     = (const float*)d_in[16];
    const float* bn2     = (const float*)d_in[17];
    const float* g_bn    = (const float*)d_in[18];
    const float* b_bn    = (const float*)d_in[19];
    const float* Wo1     = (const float*)d_in[20];
    const float* bo1     = (const float*)d_in[21];
    const float* Wo2     = (const float*)d_in[22];
    const float* bo2     = (const float*)d_in[23];

    float* ws = (float*)d_ws;
    size_t off = 0;
    float* h      = ws + off; off += (size_t)N_NODES * ND;
    float* t      = ws + off; off += (size_t)N_NODES * ND;
    float* aggr   = ws + off; off += (size_t)N_NODES * HD;
    float* stats  = ws + off; off += 2 * ND;
    float* ss     = ws + off; off += 2 * ND;
    float* pooled = ws + off; off += N_GRAPH * ND;
    float* cnt    = ws + off; off += 512;
    unsigned short* h_bf = (unsigned short*)(ws + off); off += (size_t)N_NODES * ND / 2;
    unsigned short* pA1  = (unsigned short*)(ws + off); off += 5 * 8 * 64 * 8 / 2;
    unsigned short* pA2  = (unsigned short*)(ws + off); off += 4 * 8 * 64 * 8 / 2;
    int* sD       = (int*)(ws + off); off += N_EDGES;
    int* sS       = (int*)(ws + off); off += N_EDGES;
    int* sE       = (int*)(ws + off); off += N_EDGES;
    int* hist     = (int*)(ws + off); off += N_NODES;
    int* cursor   = (int*)(ws + off); off += N_NODES;
    int* chunksum = (int*)(ws + off); off += 64;
    size_t base_bytes = off * sizeof(float);
    unsigned short* e_bf = (unsigned short*)(ws + off);
    bool epre = (ws_size >= base_bytes + (size_t)N_EDGES * 32 * 2);

    float* outp = (float*)d_out;

    const int NCH = (N_NODES + 1023) / 1024;  // 49

    // ---- counting sort of edges by dst (once per call) ----
    hipMemsetAsync(hist, 0, N_NODES * sizeof(int), stream);
    k_hist<<<(N_EDGES + 255) / 256, 256, 0, stream>>>(ei, hist);
    k_scan1<<<NCH, 1024, 0, stream>>>(hist, chunksum);
    k_scan2<<<1, 64, 0, stream>>>(chunksum, NCH);
    k_scan3<<<NCH, 1024, 0, stream>>>(hist, chunksum, cursor);
    k_scatter<<<(N_EDGES + 255) / 256, 256, 0, stream>>>(ei, cursor, sD, sS, sE);
    if (epre)
        k_eproj_sorted<<<(int)(((long)N_EDGES * 32 + 255) / 256), 256, 0, stream>>>(
            ea, sE, Wep, bep, e_bf);

    // ---- node projection + BN ----
    hipMemsetAsync(stats, 0, 2 * ND * sizeof(float), stream);
    k_node_proj<<<512, 256, 0, stream>>>(x, Wnp, bnp, t, stats);
    k_bn_finalize<<<1, 64, 0, stream>>>(stats, g_np, be_np, ss);
    k_bn_apply<<<2048, 256, 0, stream>>>(t, ss, h, h_bf);

    for (int l = 0; l < 3; ++l) {
        k_pack_w<<<(5 * 8 * 64 + 255) / 256, 256, 0, stream>>>(
            We1 + (size_t)l * 160 * HD, pA1, 5);
        k_pack_w<<<(4 * 8 * 64 + 255) / 256, 256, 0, stream>>>(
            We2 + (size_t)l * HD * HD, pA2, 4);

        hipMemsetAsync(aggr, 0, (size_t)N_NODES * HD * sizeof(float), stream);
        if (epre)
            k_edge_mfma_s<true><<<N_EDGES / 128, 256, 0, stream>>>(
                h_bf, e_bf, ea, sE, Wep, bep, sD, sS,
                pA1, be1 + l * HD, pA2, be2 + l * HD, aggr);
        else
            k_edge_mfma_s<false><<<N_EDGES / 128, 256, 0, stream>>>(
                h_bf, e_bf, ea, sE, Wep, bep, sD, sS,
                pA1, be1 + l * HD, pA2, be2 + l * HD, aggr);

        hipMemsetAsync(stats, 0, 2 * ND * sizeof(float), stream);
        k_node_update<<<512, 256, 0, stream>>>(
            h, aggr,
            Wn1 + (size_t)l * (ND + HD) * HD, bn1 + l * HD,
            Wn2 + (size_t)l * HD * ND, bn2 + l * ND, t, stats);
        k_bn_finalize<<<1, 64, 0, stream>>>(stats, g_bn + l * ND, b_bn + l * ND, ss);
        k_bn_apply<<<2048, 256, 0, stream>>>(t, ss, h, h_bf);
    }

    hipMemsetAsync(pooled, 0, (size_t)(N_GRAPH * ND + 512) * sizeof(float), stream);
    k_pool<<<512, 256, 0, stream>>>(h, batch, pooled, cnt);
    k_readout<<<(N_GRAPH + WPB - 1) / WPB, 256, 0, stream>>>(
        pooled, cnt, Wo1, bo1, Wo2, bo2, outp);
}

// Round 12
// 1825.352 us; speedup vs baseline: 4.2895x; 1.0948x over previous
//
#include <hip/hip_runtime.h>
#include <hip/hip_bf16.h>

#define N_NODES 50000
#define N_EDGES 800000
#define N_GRAPH 500
#define ND 64
#define ED 32
#define HD 128
#define WPB 4   // waves per block (256 threads)

typedef __attribute__((ext_vector_type(8))) short bf16x8;
typedef __attribute__((ext_vector_type(4))) float f32x4;

__device__ __forceinline__ float sp(float x) {
    return fmaxf(x, 0.f) + log1pf(expf(-fabsf(x)));
}

// fast softplus for the bf16 path (v_exp_f32/v_log_f32 based)
__device__ __forceinline__ float spf(float x) {
    return fmaxf(x, 0.f) + __logf(1.f + __expf(-fabsf(x)));
}

__device__ __forceinline__ unsigned short f2bf(float v) {
    __hip_bfloat16 b = __float2bfloat16(v);
    return *(unsigned short*)&b;
}

__device__ __forceinline__ unsigned int pkbf(float a, float b) {
    return (unsigned int)f2bf(a) | ((unsigned int)f2bf(b) << 16);
}

// ---------------- node projection + BN (fp32) ---------------------------
__global__ __launch_bounds__(256) void k_node_proj(
    const float* __restrict__ x, const float* __restrict__ Wnp,
    const float* __restrict__ bnp, float* __restrict__ t,
    float* __restrict__ stats) {
    int lane = threadIdx.x & 63;
    int wave = (blockIdx.x * blockDim.x + threadIdx.x) >> 6;
    int nw = (gridDim.x * blockDim.x) >> 6;
    float w[13];
#pragma unroll
    for (int k = 0; k < 13; ++k) w[k] = Wnp[k * ND + lane];
    float bb = bnp[lane];
    float s0 = 0.f, s1 = 0.f;
    for (int i = wave; i < N_NODES; i += nw) {
        float acc = bb;
#pragma unroll
        for (int k = 0; k < 13; ++k) acc += x[i * 13 + k] * w[k];
        float v = sp(acc);
        t[i * ND + lane] = v;
        s0 += v; s1 += v * v;
    }
    atomicAdd(&stats[lane], s0);
    atomicAdd(&stats[ND + lane], s1);
}

__global__ void k_bn_finalize(const float* __restrict__ stats,
                              const float* __restrict__ g,
                              const float* __restrict__ b,
                              float* __restrict__ ss) {
    int j = threadIdx.x;
    if (j >= ND) return;
    float inv_n = 1.f / (float)N_NODES;
    float mu = stats[j] * inv_n;
    float var = stats[ND + j] * inv_n - mu * mu;
    float rs = rsqrtf(var + 1e-5f);
    float sc = rs * g[j];
    ss[j] = sc;
    ss[ND + j] = b[j] - mu * sc;
}

__global__ __launch_bounds__(256) void k_bn_apply(
    const float* __restrict__ t, const float* __restrict__ ss,
    float* __restrict__ h, unsigned short* __restrict__ hb) {
    int idx = blockIdx.x * blockDim.x + threadIdx.x;
    int tot = N_NODES * ND;
    int stride = gridDim.x * blockDim.x;
    for (; idx < tot; idx += stride) {
        int c = idx & (ND - 1);
        float v = t[idx] * ss[c] + ss[ND + c];
        h[idx] = v;
        hb[idx] = f2bf(v);
    }
}

// ---------------- counting sort of edges by dst -------------------------
__global__ __launch_bounds__(256) void k_hist(const int* __restrict__ ei,
                                              int* __restrict__ hist) {
    int e = blockIdx.x * 256 + threadIdx.x;
    if (e < N_EDGES) atomicAdd(&hist[ei[N_EDGES + e]], 1);
}

__global__ __launch_bounds__(1024) void k_scan1(const int* __restrict__ hist,
                                                int* __restrict__ chunksum) {
    __shared__ int s[1024];
    int t = threadIdx.x;
    int i = blockIdx.x * 1024 + t;
    s[t] = (i < N_NODES) ? hist[i] : 0;
    __syncthreads();
    for (int off = 512; off; off >>= 1) {
        if (t < off) s[t] += s[t + off];
        __syncthreads();
    }
    if (t == 0) chunksum[blockIdx.x] = s[0];
}

__global__ void k_scan2(int* __restrict__ chunksum, int n) {
    if (threadIdx.x == 0) {
        int acc = 0;
        for (int i = 0; i < n; ++i) { int v = chunksum[i]; chunksum[i] = acc; acc += v; }
    }
}

__global__ __launch_bounds__(1024) void k_scan3(const int* __restrict__ hist,
                                                const int* __restrict__ chunksum,
                                                int* __restrict__ cursor) {
    __shared__ int s[1024];
    int t = threadIdx.x;
    int i = blockIdx.x * 1024 + t;
    int v = (i < N_NODES) ? hist[i] : 0;
    s[t] = v;
    __syncthreads();
    for (int off = 1; off < 1024; off <<= 1) {
        int u = (t >= off) ? s[t - off] : 0;
        __syncthreads();
        s[t] += u;
        __syncthreads();
    }
    if (i < N_NODES) cursor[i] = chunksum[blockIdx.x] + s[t] - v;  // exclusive
}

__global__ __launch_bounds__(256) void k_scatter(const int* __restrict__ ei,
                                                 int* __restrict__ cursor,
                                                 int* __restrict__ sD,
                                                 int* __restrict__ sS,
                                                 int* __restrict__ sE) {
    int e = blockIdx.x * 256 + threadIdx.x;
    if (e >= N_EDGES) return;
    int d = ei[N_EDGES + e];
    int pos = atomicAdd(&cursor[d], 1);
    sD[pos] = d;
    sS[pos] = ei[e];
    sE[pos] = e;
}

// edge projection into sorted order (layer-invariant, once per call)
__global__ __launch_bounds__(256) void k_eproj_sorted(
    const float* __restrict__ ea, const int* __restrict__ sE,
    const float* __restrict__ Wep, const float* __restrict__ bep,
    unsigned short* __restrict__ e_bf) {
    long idx = (long)blockIdx.x * blockDim.x + threadIdx.x;
    long tot = (long)N_EDGES * 32;
    if (idx >= tot) return;
    int p = (int)(idx >> 5), col = (int)(idx & 31);
    int e = sE[p];
    float v = spf(ea[2 * e] * Wep[col] + ea[2 * e + 1] * Wep[32 + col] + bep[col]);
    e_bf[idx] = f2bf(v);
}

// ---- generalized weight pack: W[K][ncols] -> A-frag layout -------------
// out[((ks*nfrag+nf)*64+l)*8+r] = bf16(W[(32ks+8*(l>>4)+r)*ncols + 16nf+(l&15)])
__global__ __launch_bounds__(256) void k_pack_wg(
    const float* __restrict__ W, unsigned short* __restrict__ out,
    int ksteps, int ncols) {
    int nfrag = ncols >> 4;
    int tid = blockIdx.x * blockDim.x + threadIdx.x;
    int total = ksteps * nfrag * 64;
    if (tid >= total) return;
    int l = tid & 63; int fr = tid >> 6; int nf = fr % nfrag; int ks = fr / nfrag;
    int n = 16 * nf + (l & 15);
    int k0 = 32 * ks + 8 * (l >> 4);
#pragma unroll
    for (int r = 0; r < 8; ++r)
        out[tid * 8 + r] = f2bf(W[(k0 + r) * ncols + n]);
}

// aggr fp32 -> bf16 mirror for MFMA B-operands
__global__ __launch_bounds__(256) void k_cvt_aggr(
    const float* __restrict__ a, unsigned short* __restrict__ o) {
    int i = (blockIdx.x * 256 + threadIdx.x) * 8;
    if (i >= N_NODES * HD) return;
    f32x4 v0 = *(const f32x4*)(a + i);
    f32x4 v1 = *(const f32x4*)(a + i + 4);
    bf16x8 r;
    r[0] = (short)f2bf(v0[0]); r[1] = (short)f2bf(v0[1]);
    r[2] = (short)f2bf(v0[2]); r[3] = (short)f2bf(v0[3]);
    r[4] = (short)f2bf(v1[0]); r[5] = (short)f2bf(v1[1]);
    r[6] = (short)f2bf(v1[2]); r[7] = (short)f2bf(v1[3]);
    *(bf16x8*)(o + i) = r;
}

// ---------------- MFMA edge conv on dst-sorted edges (unchanged) --------
template <bool EPRE>
__global__ __launch_bounds__(256, 2) void k_edge_mfma_s(
    const unsigned short* __restrict__ h_bf, const unsigned short* __restrict__ e_bf,
    const float* __restrict__ ea, const int* __restrict__ sE,
    const float* __restrict__ Wep, const float* __restrict__ bep,
    const int* __restrict__ sD, const int* __restrict__ sS,
    const unsigned short* __restrict__ pA1, const float* __restrict__ be1,
    const unsigned short* __restrict__ pA2, const float* __restrict__ be2,
    float* __restrict__ aggr) {
    __shared__ unsigned short P[WPB][32][136];   // bf16 P; reused as fp32 stage
    __shared__ int dstS[WPB][16];
    __shared__ unsigned short eL[EPRE ? 64 : 128 * 32];

    int lane = threadIdx.x & 63;
    int w = threadIdx.x >> 6;
    int m = lane & 15, g = lane >> 4;
    int tile0 = blockIdx.x * 128;
    int wbase = tile0 + 32 * w;

    int eD0 = sD[wbase + m];
    int eD1 = sD[wbase + 16 + m];
    int eS0 = sS[wbase + m];
    int eS1 = sS[wbase + 16 + m];

    if constexpr (!EPRE) {
        int col = threadIdx.x & 31;
        int r0 = threadIdx.x >> 5;
        float w0 = Wep[col], w1 = Wep[32 + col], bb = bep[col];
#pragma unroll
        for (int i = 0; i < 16; ++i) {
            int em = r0 + 8 * i;
            int e = sE[tile0 + em];
            eL[em * 32 + col] = f2bf(spf(ea[2 * e] * w0 + ea[2 * e + 1] * w1 + bb));
        }
        __syncthreads();
    }

    f32x4 acc[2][8];
#pragma unroll
    for (int mf = 0; mf < 2; ++mf)
#pragma unroll
        for (int nf = 0; nf < 8; ++nf) acc[mf][nf] = (f32x4){0.f, 0.f, 0.f, 0.f};

    // ---- GEMM1: K = 160 (dst 64 | src 64 | e 32) ----
#pragma unroll
    for (int ks = 0; ks < 5; ++ks) {
        bf16x8 b0, b1;
        if (ks < 2) {
            b0 = *(const bf16x8*)(h_bf + (size_t)eD0 * 64 + ks * 32 + 8 * g);
            b1 = *(const bf16x8*)(h_bf + (size_t)eD1 * 64 + ks * 32 + 8 * g);
        } else if (ks < 4) {
            b0 = *(const bf16x8*)(h_bf + (size_t)eS0 * 64 + (ks - 2) * 32 + 8 * g);
            b1 = *(const bf16x8*)(h_bf + (size_t)eS1 * 64 + (ks - 2) * 32 + 8 * g);
        } else {
            if constexpr (EPRE) {
                b0 = *(const bf16x8*)(e_bf + (size_t)(wbase + m) * 32 + 8 * g);
                b1 = *(const bf16x8*)(e_bf + (size_t)(wbase + 16 + m) * 32 + 8 * g);
            } else {
                b0 = *(const bf16x8*)&eL[(32 * w + m) * 32 + 8 * g];
                b1 = *(const bf16x8*)&eL[(32 * w + 16 + m) * 32 + 8 * g];
            }
        }
#pragma unroll
        for (int nf = 0; nf < 8; ++nf) {
            bf16x8 a = *(const bf16x8*)(pA1 + ((ks * 8 + nf) * 64 + lane) * 8);
            acc[0][nf] = __builtin_amdgcn_mfma_f32_16x16x32_bf16(a, b0, acc[0][nf], 0, 0, 0);
            acc[1][nf] = __builtin_amdgcn_mfma_f32_16x16x32_bf16(a, b1, acc[1][nf], 0, 0, 0);
        }
    }

    // ---- epilogue 1: bias + fast softplus -> P (bf16) in LDS ----
#pragma unroll
    for (int nf = 0; nf < 8; ++nf) {
        f32x4 bb = *(const f32x4*)(be1 + 16 * nf + 4 * g);
#pragma unroll
        for (int mf = 0; mf < 2; ++mf) {
            f32x4 c = acc[mf][nf];
            unsigned int u01 = pkbf(spf(c[0] + bb[0]), spf(c[1] + bb[1]));
            unsigned int u23 = pkbf(spf(c[2] + bb[2]), spf(c[3] + bb[3]));
            unsigned int* dst = (unsigned int*)&P[w][m + 16 * mf][16 * nf + 4 * g];
            dst[0] = u01; dst[1] = u23;
        }
    }

    f32x4 acc2[2][8];
#pragma unroll
    for (int mf = 0; mf < 2; ++mf)
#pragma unroll
        for (int nf = 0; nf < 8; ++nf) acc2[mf][nf] = (f32x4){0.f, 0.f, 0.f, 0.f};

    // ---- GEMM2: K = 128, B = P^T from LDS (wave-private rows) ----
#pragma unroll
    for (int ks = 0; ks < 4; ++ks) {
        bf16x8 b0 = *(const bf16x8*)&P[w][m][32 * ks + 8 * g];
        bf16x8 b1 = *(const bf16x8*)&P[w][m + 16][32 * ks + 8 * g];
#pragma unroll
        for (int nf = 0; nf < 8; ++nf) {
            bf16x8 a = *(const bf16x8*)(pA2 + ((ks * 8 + nf) * 64 + lane) * 8);
            acc2[0][nf] = __builtin_amdgcn_mfma_f32_16x16x32_bf16(a, b0, acc2[0][nf], 0, 0, 0);
            acc2[1][nf] = __builtin_amdgcn_mfma_f32_16x16x32_bf16(a, b1, acc2[1][nf], 0, 0, 0);
        }
    }

    __syncthreads();  // fence: P (bf16) reads done before fp32 reuse

    // ---- epilogue 2: stage fp32 rows, run-length segmented reduce ------
    float* st = (float*)&P[w][0][0];  // 16 rows x 132 floats = 8448B <= 8704B
#pragma unroll 1
    for (int mf = 0; mf < 2; ++mf) {
        int d = mf ? eD1 : eD0;
        dstS[w][m] = d;  // all g write same value
#pragma unroll
        for (int nf = 0; nf < 8; ++nf) {
            f32x4 bb = *(const f32x4*)(be2 + 16 * nf + 4 * g);
            f32x4 c = acc2[mf][nf];
            f32x4 v = { spf(c[0] + bb[0]), spf(c[1] + bb[1]),
                        spf(c[2] + bb[2]), spf(c[3] + bb[3]) };
            *(f32x4*)&st[m * 132 + 16 * nf + 4 * g] = v;
        }
        asm volatile("" ::: "memory");
        float a0 = 0.f, a1 = 0.f;
        int cur = dstS[w][0];
#pragma unroll 1
        for (int r = 0; r < 16; ++r) {
            int dr = dstS[w][r];               // wave-uniform
            if (dr != cur) {                   // uniform branch
                atomicAdd(&aggr[(size_t)cur * HD + lane], a0);
                atomicAdd(&aggr[(size_t)cur * HD + 64 + lane], a1);
                a0 = 0.f; a1 = 0.f; cur = dr;
            }
            a0 += st[r * 132 + lane];
            a1 += st[r * 132 + 64 + lane];
        }
        atomicAdd(&aggr[(size_t)cur * HD + lane], a0);
        atomicAdd(&aggr[(size_t)cur * HD + 64 + lane], a1);
        asm volatile("" ::: "memory");
    }
}

// ---------------- MFMA node update ---------------------------------------
// Per block: 128 nodes; per wave 32 (2 m-frags). Same structure as the edge
// kernel. GEMM1: z2=[h(64)|aggr(128)], K=192, A=packed Wn1. P=sp(.) in LDS.
// GEMM2: K=128, N=64, A=packed Wn2. Epilogue: +bn2 +h residual -> t, BN stats
// via shfl-reduce + atomics.
__global__ __launch_bounds__(256, 2) void k_node_mfma(
    const unsigned short* __restrict__ h_bf, const unsigned short* __restrict__ aggr_bf,
    const float* __restrict__ h,
    const unsigned short* __restrict__ pWn1, const float* __restrict__ bn1,
    const unsigned short* __restrict__ pWn2, const float* __restrict__ bn2,
    float* __restrict__ t, float* __restrict__ stats) {
    __shared__ unsigned short P[WPB][32][136];

    int lane = threadIdx.x & 63;
    int w = threadIdx.x >> 6;
    int m = lane & 15, g = lane >> 4;
    int tile0 = blockIdx.x * 128;
    int wbase = tile0 + 32 * w;
    int n0 = wbase + m, n1 = wbase + 16 + m;
    bool v0 = n0 < N_NODES, v1 = n1 < N_NODES;
    int c0 = v0 ? n0 : N_NODES - 1;
    int c1 = v1 ? n1 : N_NODES - 1;

    f32x4 acc[2][8];
#pragma unroll
    for (int mf = 0; mf < 2; ++mf)
#pragma unroll
        for (int nf = 0; nf < 8; ++nf) acc[mf][nf] = (f32x4){0.f, 0.f, 0.f, 0.f};

    // ---- GEMM1: K = 192 (h 64 | aggr 128) ----
#pragma unroll
    for (int ks = 0; ks < 6; ++ks) {
        bf16x8 b0, b1;
        if (ks < 2) {
            b0 = *(const bf16x8*)(h_bf + (size_t)c0 * 64 + ks * 32 + 8 * g);
            b1 = *(const bf16x8*)(h_bf + (size_t)c1 * 64 + ks * 32 + 8 * g);
        } else {
            b0 = *(const bf16x8*)(aggr_bf + (size_t)c0 * 128 + (ks - 2) * 32 + 8 * g);
            b1 = *(const bf16x8*)(aggr_bf + (size_t)c1 * 128 + (ks - 2) * 32 + 8 * g);
        }
#pragma unroll
        for (int nf = 0; nf < 8; ++nf) {
            bf16x8 a = *(const bf16x8*)(pWn1 + ((ks * 8 + nf) * 64 + lane) * 8);
            acc[0][nf] = __builtin_amdgcn_mfma_f32_16x16x32_bf16(a, b0, acc[0][nf], 0, 0, 0);
            acc[1][nf] = __builtin_amdgcn_mfma_f32_16x16x32_bf16(a, b1, acc[1][nf], 0, 0, 0);
        }
    }

    // ---- epilogue 1: bias + fast softplus -> P (bf16) in LDS ----
#pragma unroll
    for (int nf = 0; nf < 8; ++nf) {
        f32x4 bb = *(const f32x4*)(bn1 + 16 * nf + 4 * g);
#pragma unroll
        for (int mf = 0; mf < 2; ++mf) {
            f32x4 c = acc[mf][nf];
            unsigned int u01 = pkbf(spf(c[0] + bb[0]), spf(c[1] + bb[1]));
            unsigned int u23 = pkbf(spf(c[2] + bb[2]), spf(c[3] + bb[3]));
            unsigned int* dst = (unsigned int*)&P[w][m + 16 * mf][16 * nf + 4 * g];
            dst[0] = u01; dst[1] = u23;
        }
    }

    f32x4 acc2[2][4];
#pragma unroll
    for (int mf = 0; mf < 2; ++mf)
#pragma unroll
        for (int nf = 0; nf < 4; ++nf) acc2[mf][nf] = (f32x4){0.f, 0.f, 0.f, 0.f};

    // ---- GEMM2: K = 128, N = 64, B = P^T from LDS ----
#pragma unroll
    for (int ks = 0; ks < 4; ++ks) {
        bf16x8 b0 = *(const bf16x8*)&P[w][m][32 * ks + 8 * g];
        bf16x8 b1 = *(const bf16x8*)&P[w][m + 16][32 * ks + 8 * g];
#pragma unroll
        for (int nf = 0; nf < 4; ++nf) {
            bf16x8 a = *(const bf16x8*)(pWn2 + ((ks * 4 + nf) * 64 + lane) * 8);
            acc2[0][nf] = __builtin_amdgcn_mfma_f32_16x16x32_bf16(a, b0, acc2[0][nf], 0, 0, 0);
            acc2[1][nf] = __builtin_amdgcn_mfma_f32_16x16x32_bf16(a, b1, acc2[1][nf], 0, 0, 0);
        }
    }

    // ---- epilogue 2: +bn2 +h residual -> t; BN stats ----
#pragma unroll
    for (int nf = 0; nf < 4; ++nf) {
        f32x4 bb = *(const f32x4*)(bn2 + 16 * nf + 4 * g);
        f32x4 s0v = (f32x4){0.f, 0.f, 0.f, 0.f};
        f32x4 s1v = (f32x4){0.f, 0.f, 0.f, 0.f};
#pragma unroll
        for (int mf = 0; mf < 2; ++mf) {
            int cn = mf ? c1 : c0;
            bool vn = mf ? v1 : v0;
            f32x4 hv = *(const f32x4*)(h + (size_t)cn * 64 + 16 * nf + 4 * g);
            f32x4 c = acc2[mf][nf];
            f32x4 tn;
#pragma unroll
            for (int j = 0; j < 4; ++j) tn[j] = c[j] + bb[j] + hv[j];
            if (vn) *(f32x4*)(t + (size_t)cn * 64 + 16 * nf + 4 * g) = tn;
#pragma unroll
            for (int j = 0; j < 4; ++j) {
                float tv = vn ? tn[j] : 0.f;
                s0v[j] += tv;
                s1v[j] += tv * tv;
            }
        }
#pragma unroll
        for (int j = 0; j < 4; ++j) {
#pragma unroll
            for (int k = 1; k <= 8; k <<= 1) {
                s0v[j] += __shfl_xor(s0v[j], k);
                s1v[j] += __shfl_xor(s1v[j], k);
            }
        }
        if (m == 0) {
#pragma unroll
            for (int j = 0; j < 4; ++j) {
                atomicAdd(&stats[16 * nf + 4 * g + j], s0v[j]);
                atomicAdd(&stats[ND + 16 * nf + 4 * g + j], s1v[j]);
            }
        }
    }
}

// ---------------- pooling + readout (unchanged) -------------------------
__global__ __launch_bounds__(256) void k_pool(
    const float* __restrict__ h, const int* __restrict__ batch,
    float* __restrict__ pooled, float* __restrict__ cnt) {
    int lane = threadIdx.x & 63;
    int wave = (blockIdx.x * blockDim.x + threadIdx.x) >> 6;
    int nw = (gridDim.x * blockDim.x) >> 6;
    int chunk = (N_NODES + nw - 1) / nw;
    int s = wave * chunk;
    int epos = min(N_NODES, s + chunk);
    if (s >= N_NODES) return;
    int curg = batch[s];
    float acc = 0.f, c = 0.f;
    for (int i = s; i < epos; ++i) {
        int g = batch[i];
        if (g != curg) {
            atomicAdd(&pooled[curg * ND + lane], acc);
            if (lane == 0) atomicAdd(&cnt[curg], c);
            acc = 0.f; c = 0.f; curg = g;
        }
        acc += h[i * ND + lane];
        c += 1.f;
    }
    atomicAdd(&pooled[curg * ND + lane], acc);
    if (lane == 0) atomicAdd(&cnt[curg], c);
}

__global__ __launch_bounds__(256) void k_readout(
    const float* __restrict__ pooled, const float* __restrict__ cnt,
    const float* __restrict__ Wo1, const float* __restrict__ bo1,
    const float* __restrict__ Wo2, const float* __restrict__ bo2,
    float* __restrict__ out) {
    __shared__ float pbuf[WPB][ND];
    int lane = threadIdx.x & 63;
    int wid = threadIdx.x >> 6;
    int g = blockIdx.x * WPB + wid;
    bool valid = g < N_GRAPH;
    int gc = valid ? g : N_GRAPH - 1;
    float c = fmaxf(cnt[gc], 1.f);
    pbuf[wid][lane] = pooled[gc * ND + lane] / c;
    __syncthreads();
    float h0 = bo1[lane], h1 = bo1[64 + lane];
#pragma unroll 8
    for (int k = 0; k < ND; ++k) {
        float pk = pbuf[wid][k];
        h0 += pk * Wo1[k * HD + lane];
        h1 += pk * Wo1[k * HD + 64 + lane];
    }
    float s = sp(h0) * Wo2[lane] + sp(h1) * Wo2[64 + lane];
#pragma unroll
    for (int off = 32; off; off >>= 1) s += __shfl_down(s, off);
    if (valid && lane == 0) out[g] = s + bo2[0];
}

extern "C" void kernel_launch(void* const* d_in, const int* in_sizes, int n_in,
                              void* d_out, int out_size, void* d_ws, size_t ws_size,
                              hipStream_t stream) {
    const float* x       = (const float*)d_in[0];
    const float* ea      = (const float*)d_in[1];
    const int*   ei      = (const int*)d_in[2];
    const int*   batch   = (const int*)d_in[3];
    const float* Wnp     = (const float*)d_in[4];
    const float* bnp     = (const float*)d_in[5];
    const float* g_np    = (const float*)d_in[6];
    const float* be_np   = (const float*)d_in[7];
    const float* Wep     = (const float*)d_in[8];
    const float* bep     = (const float*)d_in[9];
    const float* We1     = (const float*)d_in[10];
    const float* be1     = (const float*)d_in[11];
    const float* We2     = (const float*)d_in[12];
    const float* be2     = (const float*)d_in[13];
    const float* Wn1     = (const float*)d_in[14];
    const float* bn1     = (const float*)d_in[15];
    const float* Wn2     = (const float*)d_in[16];
    const float* bn2     = (const float*)d_in[17];
    const float* g_bn    = (const float*)d_in[18];
    const float* b_bn    = (const float*)d_in[19];
    const float* Wo1     = (const float*)d_in[20];
    const float* bo1     = (const float*)d_in[21];
    const float* Wo2     = (const float*)d_in[22];
    const float* bo2     = (const float*)d_in[23];

    float* ws = (float*)d_ws;
    size_t off = 0;
    float* h      = ws + off; off += (size_t)N_NODES * ND;
    float* t      = ws + off; off += (size_t)N_NODES * ND;
    float* aggr   = ws + off; off += (size_t)N_NODES * HD;
    float* stats  = ws + off; off += 2 * ND;
    float* ss     = ws + off; off += 2 * ND;
    float* pooled = ws + off; off += N_GRAPH * ND;
    float* cnt    = ws + off; off += 512;
    unsigned short* h_bf = (unsigned short*)(ws + off); off += (size_t)N_NODES * ND / 2;
    unsigned short* aggr_bf = (unsigned short*)(ws + off); off += (size_t)N_NODES * HD / 2;
    unsigned short* pA1  = (unsigned short*)(ws + off); off += 5 * 8 * 64 * 8 / 2;
    unsigned short* pA2  = (unsigned short*)(ws + off); off += 4 * 8 * 64 * 8 / 2;
    unsigned short* pWn1 = (unsigned short*)(ws + off); off += 6 * 8 * 64 * 8 / 2;
    unsigned short* pWn2 = (unsigned short*)(ws + off); off += 4 * 4 * 64 * 8 / 2;
    int* sD       = (int*)(ws + off); off += N_EDGES;
    int* sS       = (int*)(ws + off); off += N_EDGES;
    int* sE       = (int*)(ws + off); off += N_EDGES;
    int* hist     = (int*)(ws + off); off += N_NODES;
    int* cursor   = (int*)(ws + off); off += N_NODES;
    int* chunksum = (int*)(ws + off); off += 64;
    size_t base_bytes = off * sizeof(float);
    unsigned short* e_bf = (unsigned short*)(ws + off);
    bool epre = (ws_size >= base_bytes + (size_t)N_EDGES * 32 * 2);

    float* outp = (float*)d_out;

    const int NCH = (N_NODES + 1023) / 1024;  // 49

    // ---- counting sort of edges by dst (once per call) ----
    hipMemsetAsync(hist, 0, N_NODES * sizeof(int), stream);
    k_hist<<<(N_EDGES + 255) / 256, 256, 0, stream>>>(ei, hist);
    k_scan1<<<NCH, 1024, 0, stream>>>(hist, chunksum);
    k_scan2<<<1, 64, 0, stream>>>(chunksum, NCH);
    k_scan3<<<NCH, 1024, 0, stream>>>(hist, chunksum, cursor);
    k_scatter<<<(N_EDGES + 255) / 256, 256, 0, stream>>>(ei, cursor, sD, sS, sE);
    if (epre)
        k_eproj_sorted<<<(int)(((long)N_EDGES * 32 + 255) / 256), 256, 0, stream>>>(
            ea, sE, Wep, bep, e_bf);

    // ---- node projection + BN ----
    hipMemsetAsync(stats, 0, 2 * ND * sizeof(float), stream);
    k_node_proj<<<512, 256, 0, stream>>>(x, Wnp, bnp, t, stats);
    k_bn_finalize<<<1, 64, 0, stream>>>(stats, g_np, be_np, ss);
    k_bn_apply<<<2048, 256, 0, stream>>>(t, ss, h, h_bf);

    for (int l = 0; l < 3; ++l) {
        k_pack_wg<<<(5 * 8 * 64 + 255) / 256, 256, 0, stream>>>(
            We1 + (size_t)l * 160 * HD, pA1, 5, 128);
        k_pack_wg<<<(4 * 8 * 64 + 255) / 256, 256, 0, stream>>>(
            We2 + (size_t)l * HD * HD, pA2, 4, 128);
        k_pack_wg<<<(6 * 8 * 64 + 255) / 256, 256, 0, stream>>>(
            Wn1 + (size_t)l * 192 * HD, pWn1, 6, 128);
        k_pack_wg<<<(4 * 4 * 64 + 255) / 256, 256, 0, stream>>>(
            Wn2 + (size_t)l * HD * ND, pWn2, 4, 64);

        hipMemsetAsync(aggr, 0, (size_t)N_NODES * HD * sizeof(float), stream);
        if (epre)
            k_edge_mfma_s<true><<<N_EDGES / 128, 256, 0, stream>>>(
                h_bf, e_bf, ea, sE, Wep, bep, sD, sS,
                pA1, be1 + l * HD, pA2, be2 + l * HD, aggr);
        else
            k_edge_mfma_s<false><<<N_EDGES / 128, 256, 0, stream>>>(
                h_bf, e_bf, ea, sE, Wep, bep, sD, sS,
                pA1, be1 + l * HD, pA2, be2 + l * HD, aggr);

        k_cvt_aggr<<<(N_NODES * HD / 8 + 255) / 256, 256, 0, stream>>>(aggr, aggr_bf);

        hipMemsetAsync(stats, 0, 2 * ND * sizeof(float), stream);
        k_node_mfma<<<(N_NODES + 127) / 128, 256, 0, stream>>>(
            h_bf, aggr_bf, h, pWn1, bn1 + l * HD, pWn2, bn2 + l * ND, t, stats);
        k_bn_finalize<<<1, 64, 0, stream>>>(stats, g_bn + l * ND, b_bn + l * ND, ss);
        k_bn_apply<<<2048, 256, 0, stream>>>(t, ss, h, h_bf);
    }

    hipMemsetAsync(pooled, 0, (size_t)(N_GRAPH * ND + 512) * sizeof(float), stream);
    k_pool<<<512, 256, 0, stream>>>(h, batch, pooled, cnt);
    k_readout<<<(N_GRAPH + WPB - 1) / WPB, 256, 0, stream>>>(
        pooled, cnt, Wo1, bo1, Wo2, bo2, outp);
}

// Round 14
// 1823.274 us; speedup vs baseline: 4.2944x; 1.0011x over previous
//
#include <hip/hip_runtime.h>
#include <hip/hip_bf16.h>

#define N_NODES 50000
#define N_EDGES 800000
#define N_GRAPH 500
#define ND 64
#define ED 32
#define HD 128
#define WPB 4   // waves per block (256 threads)

typedef __attribute__((ext_vector_type(8))) short bf16x8;
typedef __attribute__((ext_vector_type(4))) float f32x4;

__device__ __forceinline__ float sp(float x) {
    return fmaxf(x, 0.f) + log1pf(expf(-fabsf(x)));
}

// fast softplus for the bf16 path (v_exp_f32/v_log_f32 based)
__device__ __forceinline__ float spf(float x) {
    return fmaxf(x, 0.f) + __logf(1.f + __expf(-fabsf(x)));
}

__device__ __forceinline__ unsigned short f2bf(float v) {
    __hip_bfloat16 b = __float2bfloat16(v);
    return *(unsigned short*)&b;
}

__device__ __forceinline__ unsigned int pkbf(float a, float b) {
    return (unsigned int)f2bf(a) | ((unsigned int)f2bf(b) << 16);
}

__device__ __forceinline__ float lo_bf(unsigned int u) { return __uint_as_float(u << 16); }
__device__ __forceinline__ float hi_bf(unsigned int u) { return __uint_as_float(u & 0xffff0000u); }

// ---------------- node projection + BN (fp32) ---------------------------
__global__ __launch_bounds__(256) void k_node_proj(
    const float* __restrict__ x, const float* __restrict__ Wnp,
    const float* __restrict__ bnp, float* __restrict__ t,
    float* __restrict__ stats) {
    int lane = threadIdx.x & 63;
    int wave = (blockIdx.x * blockDim.x + threadIdx.x) >> 6;
    int nw = (gridDim.x * blockDim.x) >> 6;
    float w[13];
#pragma unroll
    for (int k = 0; k < 13; ++k) w[k] = Wnp[k * ND + lane];
    float bb = bnp[lane];
    float s0 = 0.f, s1 = 0.f;
    for (int i = wave; i < N_NODES; i += nw) {
        float acc = bb;
#pragma unroll
        for (int k = 0; k < 13; ++k) acc += x[i * 13 + k] * w[k];
        float v = sp(acc);
        t[i * ND + lane] = v;
        s0 += v; s1 += v * v;
    }
    atomicAdd(&stats[lane], s0);
    atomicAdd(&stats[ND + lane], s1);
}

__global__ void k_bn_finalize(const float* __restrict__ stats,
                              const float* __restrict__ g,
                              const float* __restrict__ b,
                              float* __restrict__ ss) {
    int j = threadIdx.x;
    if (j >= ND) return;
    float inv_n = 1.f / (float)N_NODES;
    float mu = stats[j] * inv_n;
    float var = stats[ND + j] * inv_n - mu * mu;
    float rs = rsqrtf(var + 1e-5f);
    float sc = rs * g[j];
    ss[j] = sc;
    ss[ND + j] = b[j] - mu * sc;
}

__global__ __launch_bounds__(256) void k_bn_apply(
    const float* __restrict__ t, const float* __restrict__ ss,
    float* __restrict__ h, unsigned short* __restrict__ hb) {
    int idx = blockIdx.x * blockDim.x + threadIdx.x;
    int tot = N_NODES * ND;
    int stride = gridDim.x * blockDim.x;
    for (; idx < tot; idx += stride) {
        int c = idx & (ND - 1);
        float v = t[idx] * ss[c] + ss[ND + c];
        h[idx] = v;
        hb[idx] = f2bf(v);
    }
}

// ---------------- counting sort of edges by dst -------------------------
__global__ __launch_bounds__(256) void k_hist(const int* __restrict__ ei,
                                              int* __restrict__ hist) {
    int e = blockIdx.x * 256 + threadIdx.x;
    if (e < N_EDGES) atomicAdd(&hist[ei[N_EDGES + e]], 1);
}

__global__ __launch_bounds__(1024) void k_scan1(const int* __restrict__ hist,
                                                int* __restrict__ chunksum) {
    __shared__ int s[1024];
    int t = threadIdx.x;
    int i = blockIdx.x * 1024 + t;
    s[t] = (i < N_NODES) ? hist[i] : 0;
    __syncthreads();
    for (int off = 512; off; off >>= 1) {
        if (t < off) s[t] += s[t + off];
        __syncthreads();
    }
    if (t == 0) chunksum[blockIdx.x] = s[0];
}

__global__ void k_scan2(int* __restrict__ chunksum, int n) {
    if (threadIdx.x == 0) {
        int acc = 0;
        for (int i = 0; i < n; ++i) { int v = chunksum[i]; chunksum[i] = acc; acc += v; }
    }
}

__global__ __launch_bounds__(1024) void k_scan3(const int* __restrict__ hist,
                                                const int* __restrict__ chunksum,
                                                int* __restrict__ cursor,
                                                int* __restrict__ rowptr) {
    __shared__ int s[1024];
    int t = threadIdx.x;
    int i = blockIdx.x * 1024 + t;
    int v = (i < N_NODES) ? hist[i] : 0;
    s[t] = v;
    __syncthreads();
    for (int off = 1; off < 1024; off <<= 1) {
        int u = (t >= off) ? s[t - off] : 0;
        __syncthreads();
        s[t] += u;
        __syncthreads();
    }
    if (i < N_NODES) {
        int ex = chunksum[blockIdx.x] + s[t] - v;  // exclusive
        cursor[i] = ex;
        rowptr[i] = ex;
    }
}

__global__ __launch_bounds__(256) void k_scatter(const int* __restrict__ ei,
                                                 int* __restrict__ cursor,
                                                 int* __restrict__ sD,
                                                 int* __restrict__ sS,
                                                 int* __restrict__ sE) {
    int e = blockIdx.x * 256 + threadIdx.x;
    if (e >= N_EDGES) return;
    int d = ei[N_EDGES + e];
    int pos = atomicAdd(&cursor[d], 1);
    sD[pos] = d;
    sS[pos] = ei[e];
    sE[pos] = e;
}

// edge projection into sorted order (layer-invariant, once per call)
__global__ __launch_bounds__(256) void k_eproj_sorted(
    const float* __restrict__ ea, const int* __restrict__ sE,
    const float* __restrict__ Wep, const float* __restrict__ bep,
    unsigned short* __restrict__ e_bf) {
    long idx = (long)blockIdx.x * blockDim.x + threadIdx.x;
    long tot = (long)N_EDGES * 32;
    if (idx >= tot) return;
    int p = (int)(idx >> 5), col = (int)(idx & 31);
    int e = sE[p];
    float v = spf(ea[2 * e] * Wep[col] + ea[2 * e + 1] * Wep[32 + col] + bep[col]);
    e_bf[idx] = f2bf(v);
}

// ---- generalized weight pack: W[K][ncols] -> A-frag layout -------------
__global__ __launch_bounds__(256) void k_pack_wg(
    const float* __restrict__ W, unsigned short* __restrict__ out,
    int ksteps, int ncols) {
    int nfrag = ncols >> 4;
    int tid = blockIdx.x * blockDim.x + threadIdx.x;
    int total = ksteps * nfrag * 64;
    if (tid >= total) return;
    int l = tid & 63; int fr = tid >> 6; int nf = fr % nfrag; int ks = fr / nfrag;
    int n = 16 * nf + (l & 15);
    int k0 = 32 * ks + 8 * (l >> 4);
#pragma unroll
    for (int r = 0; r < 8; ++r)
        out[tid * 8 + r] = f2bf(W[(k0 + r) * ncols + n]);
}

// aggr fp32 -> bf16 mirror (fallback path only)
__global__ __launch_bounds__(256) void k_cvt_aggr(
    const float* __restrict__ a, unsigned short* __restrict__ o) {
    int i = (blockIdx.x * 256 + threadIdx.x) * 8;
    if (i >= N_NODES * HD) return;
    f32x4 v0 = *(const f32x4*)(a + i);
    f32x4 v1 = *(const f32x4*)(a + i + 4);
    bf16x8 r;
    r[0] = (short)f2bf(v0[0]); r[1] = (short)f2bf(v0[1]);
    r[2] = (short)f2bf(v0[2]); r[3] = (short)f2bf(v0[3]);
    r[4] = (short)f2bf(v1[0]); r[5] = (short)f2bf(v1[1]);
    r[6] = (short)f2bf(v1[2]); r[7] = (short)f2bf(v1[3]);
    *(bf16x8*)(o + i) = r;
}

// dense path: aggr_bf[n][ch] = bf16( sum over CSR rows of m_bf )
__global__ __launch_bounds__(256) void k_aggr_sum(
    const unsigned short* __restrict__ m_bf, const int* __restrict__ rowptr,
    const int* __restrict__ hist, unsigned short* __restrict__ aggr_bf) {
    int lane = threadIdx.x & 63;
    int w = threadIdx.x >> 6;
    int node = blockIdx.x * WPB + w;
    if (node >= N_NODES) return;
    int start = rowptr[node];
    int deg = hist[node];
    float a0 = 0.f, a1 = 0.f;
    const unsigned short* p = m_bf + (size_t)start * HD + 2 * lane;
    for (int i = 0; i < deg; ++i, p += HD) {
        unsigned int u = *(const unsigned int*)p;
        a0 += lo_bf(u);
        a1 += hi_bf(u);
    }
    *(unsigned int*)(aggr_bf + (size_t)node * HD + 2 * lane) = pkbf(a0, a1);
}

// ---------------- MFMA edge conv on dst-sorted edges --------------------
// DENSE: epilogue 2 writes per-edge m rows (bf16) to m_bf -- no atomics,
// no LDS second pass; aggregation happens in k_aggr_sum.
// !DENSE: legacy run-length segmented atomic reduce (ws fallback).
template <bool EPRE, bool DENSE>
__global__ __launch_bounds__(256, 2) void k_edge_mfma_s(
    const unsigned short* __restrict__ h_bf, const unsigned short* __restrict__ e_bf,
    const float* __restrict__ ea, const int* __restrict__ sE,
    const float* __restrict__ Wep, const float* __restrict__ bep,
    const int* __restrict__ sD, const int* __restrict__ sS,
    const unsigned short* __restrict__ pA1, const float* __restrict__ be1,
    const unsigned short* __restrict__ pA2, const float* __restrict__ be2,
    float* __restrict__ aggr, unsigned short* __restrict__ m_bf) {
    __shared__ unsigned short P[WPB][32][136];   // bf16 P; reused as fp32 stage (!DENSE)
    __shared__ int dstS[WPB][16];
    __shared__ unsigned short eL[EPRE ? 64 : 128 * 32];

    int lane = threadIdx.x & 63;
    int w = threadIdx.x >> 6;
    int m = lane & 15, g = lane >> 4;
    int tile0 = blockIdx.x * 128;
    int wbase = tile0 + 32 * w;

    int eD0 = sD[wbase + m];
    int eD1 = sD[wbase + 16 + m];
    int eS0 = sS[wbase + m];
    int eS1 = sS[wbase + 16 + m];

    if constexpr (!EPRE) {
        int col = threadIdx.x & 31;
        int r0 = threadIdx.x >> 5;
        float w0 = Wep[col], w1 = Wep[32 + col], bb = bep[col];
#pragma unroll
        for (int i = 0; i < 16; ++i) {
            int em = r0 + 8 * i;
            int e = sE[tile0 + em];
            eL[em * 32 + col] = f2bf(spf(ea[2 * e] * w0 + ea[2 * e + 1] * w1 + bb));
        }
        __syncthreads();
    }

    f32x4 acc[2][8];
#pragma unroll
    for (int mf = 0; mf < 2; ++mf)
#pragma unroll
        for (int nf = 0; nf < 8; ++nf) acc[mf][nf] = (f32x4){0.f, 0.f, 0.f, 0.f};

    // ---- GEMM1: K = 160 (dst 64 | src 64 | e 32) ----
#pragma unroll
    for (int ks = 0; ks < 5; ++ks) {
        bf16x8 b0, b1;
        if (ks < 2) {
            b0 = *(const bf16x8*)(h_bf + (size_t)eD0 * 64 + ks * 32 + 8 * g);
            b1 = *(const bf16x8*)(h_bf + (size_t)eD1 * 64 + ks * 32 + 8 * g);
        } else if (ks < 4) {
            b0 = *(const bf16x8*)(h_bf + (size_t)eS0 * 64 + (ks - 2) * 32 + 8 * g);
            b1 = *(const bf16x8*)(h_bf + (size_t)eS1 * 64 + (ks - 2) * 32 + 8 * g);
        } else {
            if constexpr (EPRE) {
                b0 = *(const bf16x8*)(e_bf + (size_t)(wbase + m) * 32 + 8 * g);
                b1 = *(const bf16x8*)(e_bf + (size_t)(wbase + 16 + m) * 32 + 8 * g);
            } else {
                b0 = *(const bf16x8*)&eL[(32 * w + m) * 32 + 8 * g];
                b1 = *(const bf16x8*)&eL[(32 * w + 16 + m) * 32 + 8 * g];
            }
        }
#pragma unroll
        for (int nf = 0; nf < 8; ++nf) {
            bf16x8 a = *(const bf16x8*)(pA1 + ((ks * 8 + nf) * 64 + lane) * 8);
            acc[0][nf] = __builtin_amdgcn_mfma_f32_16x16x32_bf16(a, b0, acc[0][nf], 0, 0, 0);
            acc[1][nf] = __builtin_amdgcn_mfma_f32_16x16x32_bf16(a, b1, acc[1][nf], 0, 0, 0);
        }
    }

    // ---- epilogue 1: bias + fast softplus -> P (bf16) in LDS ----
#pragma unroll
    for (int nf = 0; nf < 8; ++nf) {
        f32x4 bb = *(const f32x4*)(be1 + 16 * nf + 4 * g);
#pragma unroll
        for (int mf = 0; mf < 2; ++mf) {
            f32x4 c = acc[mf][nf];
            unsigned int u01 = pkbf(spf(c[0] + bb[0]), spf(c[1] + bb[1]));
            unsigned int u23 = pkbf(spf(c[2] + bb[2]), spf(c[3] + bb[3]));
            unsigned int* dst = (unsigned int*)&P[w][m + 16 * mf][16 * nf + 4 * g];
            dst[0] = u01; dst[1] = u23;
        }
    }

    f32x4 acc2[2][8];
#pragma unroll
    for (int mf = 0; mf < 2; ++mf)
#pragma unroll
        for (int nf = 0; nf < 8; ++nf) acc2[mf][nf] = (f32x4){0.f, 0.f, 0.f, 0.f};

    // ---- GEMM2: K = 128, B = P^T from LDS (wave-private rows) ----
#pragma unroll
    for (int ks = 0; ks < 4; ++ks) {
        bf16x8 b0 = *(const bf16x8*)&P[w][m][32 * ks + 8 * g];
        bf16x8 b1 = *(const bf16x8*)&P[w][m + 16][32 * ks + 8 * g];
#pragma unroll
        for (int nf = 0; nf < 8; ++nf) {
            bf16x8 a = *(const bf16x8*)(pA2 + ((ks * 8 + nf) * 64 + lane) * 8);
            acc2[0][nf] = __builtin_amdgcn_mfma_f32_16x16x32_bf16(a, b0, acc2[0][nf], 0, 0, 0);
            acc2[1][nf] = __builtin_amdgcn_mfma_f32_16x16x32_bf16(a, b1, acc2[1][nf], 0, 0, 0);
        }
    }

    if constexpr (DENSE) {
        // ---- epilogue 2 (dense): bias + softplus -> m_bf row stores ----
#pragma unroll
        for (int nf = 0; nf < 8; ++nf) {
            f32x4 bb = *(const f32x4*)(be2 + 16 * nf + 4 * g);
#pragma unroll
            for (int mf = 0; mf < 2; ++mf) {
                f32x4 c = acc2[mf][nf];
                unsigned int u01 = pkbf(spf(c[0] + bb[0]), spf(c[1] + bb[1]));
                unsigned int u23 = pkbf(spf(c[2] + bb[2]), spf(c[3] + bb[3]));
                unsigned long long v = (unsigned long long)u01 |
                                       ((unsigned long long)u23 << 32);
                *(unsigned long long*)&m_bf[(size_t)(wbase + 16 * mf + m) * HD +
                                            16 * nf + 4 * g] = v;
            }
        }
    } else {
        __syncthreads();  // fence: P (bf16) reads done before fp32 reuse
        // ---- epilogue 2 (fallback): stage fp32, run-length atomic reduce
        float* st = (float*)&P[w][0][0];
#pragma unroll 1
        for (int mf = 0; mf < 2; ++mf) {
            int d = mf ? eD1 : eD0;
            dstS[w][m] = d;
#pragma unroll
            for (int nf = 0; nf < 8; ++nf) {
                f32x4 bb = *(const f32x4*)(be2 + 16 * nf + 4 * g);
                f32x4 c = acc2[mf][nf];
                f32x4 v = { spf(c[0] + bb[0]), spf(c[1] + bb[1]),
                            spf(c[2] + bb[2]), spf(c[3] + bb[3]) };
                *(f32x4*)&st[m * 132 + 16 * nf + 4 * g] = v;
            }
            asm volatile("" ::: "memory");
            float a0 = 0.f, a1 = 0.f;
            int cur = dstS[w][0];
#pragma unroll 1
            for (int r = 0; r < 16; ++r) {
                int dr = dstS[w][r];
                if (dr != cur) {
                    atomicAdd(&aggr[(size_t)cur * HD + lane], a0);
                    atomicAdd(&aggr[(size_t)cur * HD + 64 + lane], a1);
                    a0 = 0.f; a1 = 0.f; cur = dr;
                }
                a0 += st[r * 132 + lane];
                a1 += st[r * 132 + 64 + lane];
            }
            atomicAdd(&aggr[(size_t)cur * HD + lane], a0);
            atomicAdd(&aggr[(size_t)cur * HD + 64 + lane], a1);
            asm volatile("" ::: "memory");
        }
    }
}

// ---------------- MFMA node update (unchanged) ---------------------------
__global__ __launch_bounds__(256, 2) void k_node_mfma(
    const unsigned short* __restrict__ h_bf, const unsigned short* __restrict__ aggr_bf,
    const float* __restrict__ h,
    const unsigned short* __restrict__ pWn1, const float* __restrict__ bn1,
    const unsigned short* __restrict__ pWn2, const float* __restrict__ bn2,
    float* __restrict__ t, float* __restrict__ stats) {
    __shared__ unsigned short P[WPB][32][136];

    int lane = threadIdx.x & 63;
    int w = threadIdx.x >> 6;
    int m = lane & 15, g = lane >> 4;
    int tile0 = blockIdx.x * 128;
    int wbase = tile0 + 32 * w;
    int n0 = wbase + m, n1 = wbase + 16 + m;
    bool v0 = n0 < N_NODES, v1 = n1 < N_NODES;
    int c0 = v0 ? n0 : N_NODES - 1;
    int c1 = v1 ? n1 : N_NODES - 1;

    f32x4 acc[2][8];
#pragma unroll
    for (int mf = 0; mf < 2; ++mf)
#pragma unroll
        for (int nf = 0; nf < 8; ++nf) acc[mf][nf] = (f32x4){0.f, 0.f, 0.f, 0.f};

    // ---- GEMM1: K = 192 (h 64 | aggr 128) ----
#pragma unroll
    for (int ks = 0; ks < 6; ++ks) {
        bf16x8 b0, b1;
        if (ks < 2) {
            b0 = *(const bf16x8*)(h_bf + (size_t)c0 * 64 + ks * 32 + 8 * g);
            b1 = *(const bf16x8*)(h_bf + (size_t)c1 * 64 + ks * 32 + 8 * g);
        } else {
            b0 = *(const bf16x8*)(aggr_bf + (size_t)c0 * 128 + (ks - 2) * 32 + 8 * g);
            b1 = *(const bf16x8*)(aggr_bf + (size_t)c1 * 128 + (ks - 2) * 32 + 8 * g);
        }
#pragma unroll
        for (int nf = 0; nf < 8; ++nf) {
            bf16x8 a = *(const bf16x8*)(pWn1 + ((ks * 8 + nf) * 64 + lane) * 8);
            acc[0][nf] = __builtin_amdgcn_mfma_f32_16x16x32_bf16(a, b0, acc[0][nf], 0, 0, 0);
            acc[1][nf] = __builtin_amdgcn_mfma_f32_16x16x32_bf16(a, b1, acc[1][nf], 0, 0, 0);
        }
    }

    // ---- epilogue 1: bias + fast softplus -> P (bf16) in LDS ----
#pragma unroll
    for (int nf = 0; nf < 8; ++nf) {
        f32x4 bb = *(const f32x4*)(bn1 + 16 * nf + 4 * g);
#pragma unroll
        for (int mf = 0; mf < 2; ++mf) {
            f32x4 c = acc[mf][nf];
            unsigned int u01 = pkbf(spf(c[0] + bb[0]), spf(c[1] + bb[1]));
            unsigned int u23 = pkbf(spf(c[2] + bb[2]), spf(c[3] + bb[3]));
            unsigned int* dst = (unsigned int*)&P[w][m + 16 * mf][16 * nf + 4 * g];
            dst[0] = u01; dst[1] = u23;
        }
    }

    f32x4 acc2[2][4];
#pragma unroll
    for (int mf = 0; mf < 2; ++mf)
#pragma unroll
        for (int nf = 0; nf < 4; ++nf) acc2[mf][nf] = (f32x4){0.f, 0.f, 0.f, 0.f};

    // ---- GEMM2: K = 128, N = 64 ----
#pragma unroll
    for (int ks = 0; ks < 4; ++ks) {
        bf16x8 b0 = *(const bf16x8*)&P[w][m][32 * ks + 8 * g];
        bf16x8 b1 = *(const bf16x8*)&P[w][m + 16][32 * ks + 8 * g];
#pragma unroll
        for (int nf = 0; nf < 4; ++nf) {
            bf16x8 a = *(const bf16x8*)(pWn2 + ((ks * 4 + nf) * 64 + lane) * 8);
            acc2[0][nf] = __builtin_amdgcn_mfma_f32_16x16x32_bf16(a, b0, acc2[0][nf], 0, 0, 0);
            acc2[1][nf] = __builtin_amdgcn_mfma_f32_16x16x32_bf16(a, b1, acc2[1][nf], 0, 0, 0);
        }
    }

    // ---- epilogue 2: +bn2 +h residual -> t; BN stats ----
#pragma unroll
    for (int nf = 0; nf < 4; ++nf) {
        f32x4 bb = *(const f32x4*)(bn2 + 16 * nf + 4 * g);
        f32x4 s0v = (f32x4){0.f, 0.f, 0.f, 0.f};
        f32x4 s1v = (f32x4){0.f, 0.f, 0.f, 0.f};
#pragma unroll
        for (int mf = 0; mf < 2; ++mf) {
            int cn = mf ? c1 : c0;
            bool vn = mf ? v1 : v0;
            f32x4 hv = *(const f32x4*)(h + (size_t)cn * 64 + 16 * nf + 4 * g);
            f32x4 c = acc2[mf][nf];
            f32x4 tn;
#pragma unroll
            for (int j = 0; j < 4; ++j) tn[j] = c[j] + bb[j] + hv[j];
            if (vn) *(f32x4*)(t + (size_t)cn * 64 + 16 * nf + 4 * g) = tn;
#pragma unroll
            for (int j = 0; j < 4; ++j) {
                float tv = vn ? tn[j] : 0.f;
                s0v[j] += tv;
                s1v[j] += tv * tv;
            }
        }
#pragma unroll
        for (int j = 0; j < 4; ++j) {
#pragma unroll
            for (int k = 1; k <= 8; k <<= 1) {
                s0v[j] += __shfl_xor(s0v[j], k);
                s1v[j] += __shfl_xor(s1v[j], k);
            }
        }
        if (m == 0) {
#pragma unroll
            for (int j = 0; j < 4; ++j) {
                atomicAdd(&stats[16 * nf + 4 * g + j], s0v[j]);
                atomicAdd(&stats[ND + 16 * nf + 4 * g + j], s1v[j]);
            }
        }
    }
}

// ---------------- pooling + readout (unchanged) -------------------------
__global__ __launch_bounds__(256) void k_pool(
    const float* __restrict__ h, const int* __restrict__ batch,
    float* __restrict__ pooled, float* __restrict__ cnt) {
    int lane = threadIdx.x & 63;
    int wave = (blockIdx.x * blockDim.x + threadIdx.x) >> 6;
    int nw = (gridDim.x * blockDim.x) >> 6;
    int chunk = (N_NODES + nw - 1) / nw;
    int s = wave * chunk;
    int epos = min(N_NODES, s + chunk);
    if (s >= N_NODES) return;
    int curg = batch[s];
    float acc = 0.f, c = 0.f;
    for (int i = s; i < epos; ++i) {
        int g = batch[i];
        if (g != curg) {
            atomicAdd(&pooled[curg * ND + lane], acc);
            if (lane == 0) atomicAdd(&cnt[curg], c);
            acc = 0.f; c = 0.f; curg = g;
        }
        acc += h[i * ND + lane];
        c += 1.f;
    }
    atomicAdd(&pooled[curg * ND + lane], acc);
    if (lane == 0) atomicAdd(&cnt[curg], c);
}

__global__ __launch_bounds__(256) void k_readout(
    const float* __restrict__ pooled, const float* __restrict__ cnt,
    const float* __restrict__ Wo1, const float* __restrict__ bo1,
    const float* __restrict__ Wo2, const float* __restrict__ bo2,
    float* __restrict__ out) {
    __shared__ float pbuf[WPB][ND];
    int lane = threadIdx.x & 63;
    int wid = threadIdx.x >> 6;
    int g = blockIdx.x * WPB + wid;
    bool valid = g < N_GRAPH;
    int gc = valid ? g : N_GRAPH - 1;
    float c = fmaxf(cnt[gc], 1.f);
    pbuf[wid][lane] = pooled[gc * ND + lane] / c;
    __syncthreads();
    float h0 = bo1[lane], h1 = bo1[64 + lane];
#pragma unroll 8
    for (int k = 0; k < ND; ++k) {
        float pk = pbuf[wid][k];
        h0 += pk * Wo1[k * HD + lane];
        h1 += pk * Wo1[k * HD + 64 + lane];
    }
    float s = sp(h0) * Wo2[lane] + sp(h1) * Wo2[64 + lane];
#pragma unroll
    for (int off = 32; off; off >>= 1) s += __shfl_down(s, off);
    if (valid && lane == 0) out[g] = s + bo2[0];
}

extern "C" void kernel_launch(void* const* d_in, const int* in_sizes, int n_in,
                              void* d_out, int out_size, void* d_ws, size_t ws_size,
                              hipStream_t stream) {
    const float* x       = (const float*)d_in[0];
    const float* ea      = (const float*)d_in[1];
    const int*   ei      = (const int*)d_in[2];
    const int*   batch   = (const int*)d_in[3];
    const float* Wnp     = (const float*)d_in[4];
    const float* bnp     = (const float*)d_in[5];
    const float* g_np    = (const float*)d_in[6];
    const float* be_np   = (const float*)d_in[7];
    const float* Wep     = (const float*)d_in[8];
    const float* bep     = (const float*)d_in[9];
    const float* We1     = (const float*)d_in[10];
    const float* be1     = (const float*)d_in[11];
    const float* We2     = (const float*)d_in[12];
    const float* be2     = (const float*)d_in[13];
    const float* Wn1     = (const float*)d_in[14];
    const float* bn1     = (const float*)d_in[15];
    const float* Wn2     = (const float*)d_in[16];
    const float* bn2     = (const float*)d_in[17];
    const float* g_bn    = (const float*)d_in[18];
    const float* b_bn    = (const float*)d_in[19];
    const float* Wo1     = (const float*)d_in[20];
    const float* bo1     = (const float*)d_in[21];
    const float* Wo2     = (const float*)d_in[22];
    const float* bo2     = (const float*)d_in[23];

    float* ws = (float*)d_ws;
    size_t off = 0;
    float* h      = ws + off; off += (size_t)N_NODES * ND;
    float* t      = ws + off; off += (size_t)N_NODES * ND;
    float* aggr   = ws + off; off += (size_t)N_NODES * HD;   // fallback only
    float* stats  = ws + off; off += 2 * ND;
    float* ss     = ws + off; off += 2 * ND;
    float* pooled = ws + off; off += N_GRAPH * ND;
    float* cnt    = ws + off; off += 512;
    unsigned short* h_bf = (unsigned short*)(ws + off); off += (size_t)N_NODES * ND / 2;
    unsigned short* aggr_bf = (unsigned short*)(ws + off); off += (size_t)N_NODES * HD / 2;
    unsigned short* pA1  = (unsigned short*)(ws + off); off += 5 * 8 * 64 * 8 / 2;
    unsigned short* pA2  = (unsigned short*)(ws + off); off += 4 * 8 * 64 * 8 / 2;
    unsigned short* pWn1 = (unsigned short*)(ws + off); off += 6 * 8 * 64 * 8 / 2;
    unsigned short* pWn2 = (unsigned short*)(ws + off); off += 4 * 4 * 64 * 8 / 2;
    int* sD       = (int*)(ws + off); off += N_EDGES;
    int* sS       = (int*)(ws + off); off += N_EDGES;
    int* sE       = (int*)(ws + off); off += N_EDGES;
    int* hist     = (int*)(ws + off); off += N_NODES;
    int* cursor   = (int*)(ws + off); off += N_NODES;
    int* rowptr   = (int*)(ws + off); off += N_NODES;
    int* chunksum = (int*)(ws + off); off += 64;
    unsigned short* e_bf = (unsigned short*)(ws + off);
    size_t off_ebf_end = off + (size_t)N_EDGES * 32 / 2;
    unsigned short* m_bf = (unsigned short*)(ws + off_ebf_end);
    size_t off_mbf_end = off_ebf_end + (size_t)N_EDGES * HD / 2;
    bool epre  = (ws_size >= off_ebf_end * sizeof(float));
    bool dense = (ws_size >= off_mbf_end * sizeof(float));

    float* outp = (float*)d_out;

    const int NCH = (N_NODES + 1023) / 1024;  // 49

    // ---- counting sort of edges by dst -> CSR (once per call) ----
    hipMemsetAsync(hist, 0, N_NODES * sizeof(int), stream);
    k_hist<<<(N_EDGES + 255) / 256, 256, 0, stream>>>(ei, hist);
    k_scan1<<<NCH, 1024, 0, stream>>>(hist, chunksum);
    k_scan2<<<1, 64, 0, stream>>>(chunksum, NCH);
    k_scan3<<<NCH, 1024, 0, stream>>>(hist, chunksum, cursor, rowptr);
    k_scatter<<<(N_EDGES + 255) / 256, 256, 0, stream>>>(ei, cursor, sD, sS, sE);
    if (epre)
        k_eproj_sorted<<<(int)(((long)N_EDGES * 32 + 255) / 256), 256, 0, stream>>>(
            ea, sE, Wep, bep, e_bf);

    // ---- node projection + BN ----
    hipMemsetAsync(stats, 0, 2 * ND * sizeof(float), stream);
    k_node_proj<<<512, 256, 0, stream>>>(x, Wnp, bnp, t, stats);
    k_bn_finalize<<<1, 64, 0, stream>>>(stats, g_np, be_np, ss);
    k_bn_apply<<<2048, 256, 0, stream>>>(t, ss, h, h_bf);

    for (int l = 0; l < 3; ++l) {
        k_pack_wg<<<(5 * 8 * 64 + 255) / 256, 256, 0, stream>>>(
            We1 + (size_t)l * 160 * HD, pA1, 5, 128);
        k_pack_wg<<<(4 * 8 * 64 + 255) / 256, 256, 0, stream>>>(
            We2 + (size_t)l * HD * HD, pA2, 4, 128);
        k_pack_wg<<<(6 * 8 * 64 + 255) / 256, 256, 0, stream>>>(
            Wn1 + (size_t)l * 192 * HD, pWn1, 6, 128);
        k_pack_wg<<<(4 * 4 * 64 + 255) / 256, 256, 0, stream>>>(
            Wn2 + (size_t)l * HD * ND, pWn2, 4, 64);

        if (dense) {
            k_edge_mfma_s<true, true><<<N_EDGES / 128, 256, 0, stream>>>(
                h_bf, e_bf, ea, sE, Wep, bep, sD, sS,
                pA1, be1 + l * HD, pA2, be2 + l * HD, aggr, m_bf);
            k_aggr_sum<<<(N_NODES + WPB - 1) / WPB, 256, 0, stream>>>(
                m_bf, rowptr, hist, aggr_bf);
        } else {
            hipMemsetAsync(aggr, 0, (size_t)N_NODES * HD * sizeof(float), stream);
            if (epre)
                k_edge_mfma_s<true, false><<<N_EDGES / 128, 256, 0, stream>>>(
                    h_bf, e_bf, ea, sE, Wep, bep, sD, sS,
                    pA1, be1 + l * HD, pA2, be2 + l * HD, aggr, m_bf);
            else
                k_edge_mfma_s<false, false><<<N_EDGES / 128, 256, 0, stream>>>(
                    h_bf, e_bf, ea, sE, Wep, bep, sD, sS,
                    pA1, be1 + l * HD, pA2, be2 + l * HD, aggr, m_bf);
            k_cvt_aggr<<<(N_NODES * HD / 8 + 255) / 256, 256, 0, stream>>>(aggr, aggr_bf);
        }

        hipMemsetAsync(stats, 0, 2 * ND * sizeof(float), stream);
        k_node_mfma<<<(N_NODES + 127) / 128, 256, 0, stream>>>(
            h_bf, aggr_bf, h, pWn1, bn1 + l * HD, pWn2, bn2 + l * ND, t, stats);
        k_bn_finalize<<<1, 64, 0, stream>>>(stats, g_bn + l * ND, b_bn + l * ND, ss);
        k_bn_apply<<<2048, 256, 0, stream>>>(t, ss, h, h_bf);
    }

    hipMemsetAsync(pooled, 0, (size_t)(N_GRAPH * ND + 512) * sizeof(float), stream);
    k_pool<<<512, 256, 0, stream>>>(h, batch, pooled, cnt);
    k_readout<<<(N_GRAPH + WPB - 1) / WPB, 256, 0, stream>>>(
        pooled, cnt, Wo1, bo1, Wo2, bo2, outp);
}

// Round 15
// 1605.095 us; speedup vs baseline: 4.8781x; 1.1359x over previous
//
#include <hip/hip_runtime.h>
#include <hip/hip_bf16.h>

#define N_NODES 50000
#define N_EDGES 800000
#define N_GRAPH 500
#define ND 64
#define ED 32
#define HD 128
#define WPB 4   // waves per block (256 threads)

typedef __attribute__((ext_vector_type(8))) short bf16x8;
typedef __attribute__((ext_vector_type(4))) float f32x4;

__device__ __forceinline__ float sp(float x) {
    return fmaxf(x, 0.f) + log1pf(expf(-fabsf(x)));
}

// fast softplus for the bf16 path (v_exp_f32/v_log_f32 based)
__device__ __forceinline__ float spf(float x) {
    return fmaxf(x, 0.f) + __logf(1.f + __expf(-fabsf(x)));
}

__device__ __forceinline__ unsigned short f2bf(float v) {
    __hip_bfloat16 b = __float2bfloat16(v);
    return *(unsigned short*)&b;
}

__device__ __forceinline__ unsigned int pkbf(float a, float b) {
    return (unsigned int)f2bf(a) | ((unsigned int)f2bf(b) << 16);
}

__device__ __forceinline__ float lo_bf(unsigned int u) { return __uint_as_float(u << 16); }
__device__ __forceinline__ float hi_bf(unsigned int u) { return __uint_as_float(u & 0xffff0000u); }

// ---------------- node projection + BN (fp32) ---------------------------
__global__ __launch_bounds__(256) void k_node_proj(
    const float* __restrict__ x, const float* __restrict__ Wnp,
    const float* __restrict__ bnp, float* __restrict__ t,
    float* __restrict__ stats) {
    int lane = threadIdx.x & 63;
    int wave = (blockIdx.x * blockDim.x + threadIdx.x) >> 6;
    int nw = (gridDim.x * blockDim.x) >> 6;
    float w[13];
#pragma unroll
    for (int k = 0; k < 13; ++k) w[k] = Wnp[k * ND + lane];
    float bb = bnp[lane];
    float s0 = 0.f, s1 = 0.f;
    for (int i = wave; i < N_NODES; i += nw) {
        float acc = bb;
#pragma unroll
        for (int k = 0; k < 13; ++k) acc += x[i * 13 + k] * w[k];
        float v = sp(acc);
        t[i * ND + lane] = v;
        s0 += v; s1 += v * v;
    }
    atomicAdd(&stats[lane], s0);
    atomicAdd(&stats[ND + lane], s1);
}

__global__ void k_bn_finalize(const float* __restrict__ stats,
                              const float* __restrict__ g,
                              const float* __restrict__ b,
                              float* __restrict__ ss) {
    int j = threadIdx.x;
    if (j >= ND) return;
    float inv_n = 1.f / (float)N_NODES;
    float mu = stats[j] * inv_n;
    float var = stats[ND + j] * inv_n - mu * mu;
    float rs = rsqrtf(var + 1e-5f);
    float sc = rs * g[j];
    ss[j] = sc;
    ss[ND + j] = b[j] - mu * sc;
}

__global__ __launch_bounds__(256) void k_bn_apply(
    const float* __restrict__ t, const float* __restrict__ ss,
    float* __restrict__ h, unsigned short* __restrict__ hb) {
    int idx = blockIdx.x * blockDim.x + threadIdx.x;
    int tot = N_NODES * ND;
    int stride = gridDim.x * blockDim.x;
    for (; idx < tot; idx += stride) {
        int c = idx & (ND - 1);
        float v = t[idx] * ss[c] + ss[ND + c];
        h[idx] = v;
        hb[idx] = f2bf(v);
    }
}

// ---------------- counting sort of edges by dst -------------------------
__global__ __launch_bounds__(256) void k_hist(const int* __restrict__ ei,
                                              int* __restrict__ hist) {
    int e = blockIdx.x * 256 + threadIdx.x;
    if (e < N_EDGES) atomicAdd(&hist[ei[N_EDGES + e]], 1);
}

__global__ __launch_bounds__(1024) void k_scan1(const int* __restrict__ hist,
                                                int* __restrict__ chunksum) {
    __shared__ int s[1024];
    int t = threadIdx.x;
    int i = blockIdx.x * 1024 + t;
    s[t] = (i < N_NODES) ? hist[i] : 0;
    __syncthreads();
    for (int off = 512; off; off >>= 1) {
        if (t < off) s[t] += s[t + off];
        __syncthreads();
    }
    if (t == 0) chunksum[blockIdx.x] = s[0];
}

__global__ void k_scan2(int* __restrict__ chunksum, int n) {
    if (threadIdx.x == 0) {
        int acc = 0;
        for (int i = 0; i < n; ++i) { int v = chunksum[i]; chunksum[i] = acc; acc += v; }
    }
}

__global__ __launch_bounds__(1024) void k_scan3(const int* __restrict__ hist,
                                                const int* __restrict__ chunksum,
                                                int* __restrict__ cursor,
                                                int* __restrict__ rowptr) {
    __shared__ int s[1024];
    int t = threadIdx.x;
    int i = blockIdx.x * 1024 + t;
    int v = (i < N_NODES) ? hist[i] : 0;
    s[t] = v;
    __syncthreads();
    for (int off = 1; off < 1024; off <<= 1) {
        int u = (t >= off) ? s[t - off] : 0;
        __syncthreads();
        s[t] += u;
        __syncthreads();
    }
    if (i < N_NODES) {
        int ex = chunksum[blockIdx.x] + s[t] - v;  // exclusive
        cursor[i] = ex;
        rowptr[i] = ex;
    }
}

__global__ __launch_bounds__(256) void k_scatter(const int* __restrict__ ei,
                                                 int* __restrict__ cursor,
                                                 int* __restrict__ sD,
                                                 int* __restrict__ sS,
                                                 int* __restrict__ sE) {
    int e = blockIdx.x * 256 + threadIdx.x;
    if (e >= N_EDGES) return;
    int d = ei[N_EDGES + e];
    int pos = atomicAdd(&cursor[d], 1);
    sD[pos] = d;
    sS[pos] = ei[e];
    sE[pos] = e;
}

// edge projection into sorted order (layer-invariant, once per call)
__global__ __launch_bounds__(256) void k_eproj_sorted(
    const float* __restrict__ ea, const int* __restrict__ sE,
    const float* __restrict__ Wep, const float* __restrict__ bep,
    unsigned short* __restrict__ e_bf) {
    long idx = (long)blockIdx.x * blockDim.x + threadIdx.x;
    long tot = (long)N_EDGES * 32;
    if (idx >= tot) return;
    int p = (int)(idx >> 5), col = (int)(idx & 31);
    int e = sE[p];
    float v = spf(ea[2 * e] * Wep[col] + ea[2 * e + 1] * Wep[32 + col] + bep[col]);
    e_bf[idx] = f2bf(v);
}

// ---- generalized weight pack: W[K][ncols] -> A-frag layout -------------
__global__ __launch_bounds__(256) void k_pack_wg(
    const float* __restrict__ W, unsigned short* __restrict__ out,
    int ksteps, int ncols) {
    int nfrag = ncols >> 4;
    int tid = blockIdx.x * blockDim.x + threadIdx.x;
    int total = ksteps * nfrag * 64;
    if (tid >= total) return;
    int l = tid & 63; int fr = tid >> 6; int nf = fr % nfrag; int ks = fr / nfrag;
    int n = 16 * nf + (l & 15);
    int k0 = 32 * ks + 8 * (l >> 4);
#pragma unroll
    for (int r = 0; r < 8; ++r)
        out[tid * 8 + r] = f2bf(W[(k0 + r) * ncols + n]);
}

// aggr fp32 -> bf16 mirror
__global__ __launch_bounds__(256) void k_cvt_aggr(
    const float* __restrict__ a, unsigned short* __restrict__ o) {
    int i = (blockIdx.x * 256 + threadIdx.x) * 8;
    if (i >= N_NODES * HD) return;
    f32x4 v0 = *(const f32x4*)(a + i);
    f32x4 v1 = *(const f32x4*)(a + i + 4);
    bf16x8 r;
    r[0] = (short)f2bf(v0[0]); r[1] = (short)f2bf(v0[1]);
    r[2] = (short)f2bf(v0[2]); r[3] = (short)f2bf(v0[3]);
    r[4] = (short)f2bf(v1[0]); r[5] = (short)f2bf(v1[1]);
    r[6] = (short)f2bf(v1[2]); r[7] = (short)f2bf(v1[3]);
    *(bf16x8*)(o + i) = r;
}

// ---------------- MFMA edge conv on dst-sorted edges --------------------
// Epilogue: stage all 128 edge-result rows (bf16) in LDS, then block-wide
// run-length segmented reduction. Interior nodes (all edges in this block)
// get PLAIN coalesced stores; only block-boundary nodes use atomics
// (~1.6M atomic dwords vs 12.8M before). Zero extra workspace.
template <bool EPRE>
__global__ __launch_bounds__(256, 2) void k_edge_mfma_s(
    const unsigned short* __restrict__ h_bf, const unsigned short* __restrict__ e_bf,
    const float* __restrict__ ea, const int* __restrict__ sE,
    const float* __restrict__ Wep, const float* __restrict__ bep,
    const int* __restrict__ sD, const int* __restrict__ sS,
    const int* __restrict__ rowptr, const int* __restrict__ hist,
    const unsigned short* __restrict__ pA1, const float* __restrict__ be1,
    const unsigned short* __restrict__ pA2, const float* __restrict__ be2,
    float* __restrict__ aggr) {
    __shared__ unsigned short P[WPB][32][136];   // per-wave P; reused as 128-row stage
    __shared__ int dstB[128];
    __shared__ unsigned short eL[EPRE ? 64 : 128 * 32];

    int lane = threadIdx.x & 63;
    int w = threadIdx.x >> 6;
    int m = lane & 15, g = lane >> 4;
    int tile0 = blockIdx.x * 128;
    int wbase = tile0 + 32 * w;

    int eD0 = sD[wbase + m];
    int eD1 = sD[wbase + 16 + m];
    int eS0 = sS[wbase + m];
    int eS1 = sS[wbase + 16 + m];

    if constexpr (!EPRE) {
        int col = threadIdx.x & 31;
        int r0 = threadIdx.x >> 5;
        float w0 = Wep[col], w1 = Wep[32 + col], bb = bep[col];
#pragma unroll
        for (int i = 0; i < 16; ++i) {
            int em = r0 + 8 * i;
            int e = sE[tile0 + em];
            eL[em * 32 + col] = f2bf(spf(ea[2 * e] * w0 + ea[2 * e + 1] * w1 + bb));
        }
        __syncthreads();
    }

    f32x4 acc[2][8];
#pragma unroll
    for (int mf = 0; mf < 2; ++mf)
#pragma unroll
        for (int nf = 0; nf < 8; ++nf) acc[mf][nf] = (f32x4){0.f, 0.f, 0.f, 0.f};

    // ---- GEMM1: K = 160 (dst 64 | src 64 | e 32) ----
#pragma unroll
    for (int ks = 0; ks < 5; ++ks) {
        bf16x8 b0, b1;
        if (ks < 2) {
            b0 = *(const bf16x8*)(h_bf + (size_t)eD0 * 64 + ks * 32 + 8 * g);
            b1 = *(const bf16x8*)(h_bf + (size_t)eD1 * 64 + ks * 32 + 8 * g);
        } else if (ks < 4) {
            b0 = *(const bf16x8*)(h_bf + (size_t)eS0 * 64 + (ks - 2) * 32 + 8 * g);
            b1 = *(const bf16x8*)(h_bf + (size_t)eS1 * 64 + (ks - 2) * 32 + 8 * g);
        } else {
            if constexpr (EPRE) {
                b0 = *(const bf16x8*)(e_bf + (size_t)(wbase + m) * 32 + 8 * g);
                b1 = *(const bf16x8*)(e_bf + (size_t)(wbase + 16 + m) * 32 + 8 * g);
            } else {
                b0 = *(const bf16x8*)&eL[(32 * w + m) * 32 + 8 * g];
                b1 = *(const bf16x8*)&eL[(32 * w + 16 + m) * 32 + 8 * g];
            }
        }
#pragma unroll
        for (int nf = 0; nf < 8; ++nf) {
            bf16x8 a = *(const bf16x8*)(pA1 + ((ks * 8 + nf) * 64 + lane) * 8);
            acc[0][nf] = __builtin_amdgcn_mfma_f32_16x16x32_bf16(a, b0, acc[0][nf], 0, 0, 0);
            acc[1][nf] = __builtin_amdgcn_mfma_f32_16x16x32_bf16(a, b1, acc[1][nf], 0, 0, 0);
        }
    }

    // ---- epilogue 1: bias + fast softplus -> P (bf16) in LDS ----
#pragma unroll
    for (int nf = 0; nf < 8; ++nf) {
        f32x4 bb = *(const f32x4*)(be1 + 16 * nf + 4 * g);
#pragma unroll
        for (int mf = 0; mf < 2; ++mf) {
            f32x4 c = acc[mf][nf];
            unsigned int u01 = pkbf(spf(c[0] + bb[0]), spf(c[1] + bb[1]));
            unsigned int u23 = pkbf(spf(c[2] + bb[2]), spf(c[3] + bb[3]));
            unsigned int* dst = (unsigned int*)&P[w][m + 16 * mf][16 * nf + 4 * g];
            dst[0] = u01; dst[1] = u23;
        }
    }

    f32x4 acc2[2][8];
#pragma unroll
    for (int mf = 0; mf < 2; ++mf)
#pragma unroll
        for (int nf = 0; nf < 8; ++nf) acc2[mf][nf] = (f32x4){0.f, 0.f, 0.f, 0.f};

    // ---- GEMM2: K = 128, B = P^T from LDS (wave-private rows) ----
#pragma unroll
    for (int ks = 0; ks < 4; ++ks) {
        bf16x8 b0 = *(const bf16x8*)&P[w][m][32 * ks + 8 * g];
        bf16x8 b1 = *(const bf16x8*)&P[w][m + 16][32 * ks + 8 * g];
#pragma unroll
        for (int nf = 0; nf < 8; ++nf) {
            bf16x8 a = *(const bf16x8*)(pA2 + ((ks * 8 + nf) * 64 + lane) * 8);
            acc2[0][nf] = __builtin_amdgcn_mfma_f32_16x16x32_bf16(a, b0, acc2[0][nf], 0, 0, 0);
            acc2[1][nf] = __builtin_amdgcn_mfma_f32_16x16x32_bf16(a, b1, acc2[1][nf], 0, 0, 0);
        }
    }

    // ---- epilogue 2: stage bf16 m rows (full block) + dst table ----
    unsigned short (*Pf)[136] = (unsigned short(*)[136]) & P[0][0][0];
#pragma unroll
    for (int nf = 0; nf < 8; ++nf) {
        f32x4 bb = *(const f32x4*)(be2 + 16 * nf + 4 * g);
#pragma unroll
        for (int mf = 0; mf < 2; ++mf) {
            f32x4 c = acc2[mf][nf];
            unsigned int* dst = (unsigned int*)&Pf[32 * w + 16 * mf + m][16 * nf + 4 * g];
            dst[0] = pkbf(spf(c[0] + bb[0]), spf(c[1] + bb[1]));
            dst[1] = pkbf(spf(c[2] + bb[2]), spf(c[3] + bb[3]));
        }
    }
    if (g == 0) {
        dstB[32 * w + m] = eD0;
        dstB[32 * w + 16 + m] = eD1;
    }
    __syncthreads();

    // ---- block-wide run-length segmented reduction ----
    int rbeg = 32 * w, rend = rbeg + 32;
    int r = rbeg;
    if (w) {  // skip rows continuing a run that started in a lower wave
        while (r < rend && dstB[r] == dstB[r - 1]) ++r;
    }
    while (r < rend) {
        int d = dstB[r];
        float a0 = 0.f, a1 = 0.f;
        int rr = r;
        do {
            unsigned int u = *(const unsigned int*)&Pf[rr][2 * lane];
            a0 += lo_bf(u);
            a1 += hi_bf(u);
            ++rr;
        } while (rr < 128 && dstB[rr] == d);
        int s0 = rowptr[d];
        bool interior = (s0 >= tile0) && (s0 + hist[d] <= tile0 + 128);
        float* base = aggr + (size_t)d * HD + 2 * lane;
        if (interior) {
            base[0] = a0;
            base[1] = a1;
        } else {
            atomicAdd(base, a0);
            atomicAdd(base + 1, a1);
        }
        r = rr;
    }
}

// ---------------- MFMA node update (unchanged) ---------------------------
__global__ __launch_bounds__(256, 2) void k_node_mfma(
    const unsigned short* __restrict__ h_bf, const unsigned short* __restrict__ aggr_bf,
    const float* __restrict__ h,
    const unsigned short* __restrict__ pWn1, const float* __restrict__ bn1,
    const unsigned short* __restrict__ pWn2, const float* __restrict__ bn2,
    float* __restrict__ t, float* __restrict__ stats) {
    __shared__ unsigned short P[WPB][32][136];

    int lane = threadIdx.x & 63;
    int w = threadIdx.x >> 6;
    int m = lane & 15, g = lane >> 4;
    int tile0 = blockIdx.x * 128;
    int wbase = tile0 + 32 * w;
    int n0 = wbase + m, n1 = wbase + 16 + m;
    bool v0 = n0 < N_NODES, v1 = n1 < N_NODES;
    int c0 = v0 ? n0 : N_NODES - 1;
    int c1 = v1 ? n1 : N_NODES - 1;

    f32x4 acc[2][8];
#pragma unroll
    for (int mf = 0; mf < 2; ++mf)
#pragma unroll
        for (int nf = 0; nf < 8; ++nf) acc[mf][nf] = (f32x4){0.f, 0.f, 0.f, 0.f};

    // ---- GEMM1: K = 192 (h 64 | aggr 128) ----
#pragma unroll
    for (int ks = 0; ks < 6; ++ks) {
        bf16x8 b0, b1;
        if (ks < 2) {
            b0 = *(const bf16x8*)(h_bf + (size_t)c0 * 64 + ks * 32 + 8 * g);
            b1 = *(const bf16x8*)(h_bf + (size_t)c1 * 64 + ks * 32 + 8 * g);
        } else {
            b0 = *(const bf16x8*)(aggr_bf + (size_t)c0 * 128 + (ks - 2) * 32 + 8 * g);
            b1 = *(const bf16x8*)(aggr_bf + (size_t)c1 * 128 + (ks - 2) * 32 + 8 * g);
        }
#pragma unroll
        for (int nf = 0; nf < 8; ++nf) {
            bf16x8 a = *(const bf16x8*)(pWn1 + ((ks * 8 + nf) * 64 + lane) * 8);
            acc[0][nf] = __builtin_amdgcn_mfma_f32_16x16x32_bf16(a, b0, acc[0][nf], 0, 0, 0);
            acc[1][nf] = __builtin_amdgcn_mfma_f32_16x16x32_bf16(a, b1, acc[1][nf], 0, 0, 0);
        }
    }

    // ---- epilogue 1: bias + fast softplus -> P (bf16) in LDS ----
#pragma unroll
    for (int nf = 0; nf < 8; ++nf) {
        f32x4 bb = *(const f32x4*)(bn1 + 16 * nf + 4 * g);
#pragma unroll
        for (int mf = 0; mf < 2; ++mf) {
            f32x4 c = acc[mf][nf];
            unsigned int u01 = pkbf(spf(c[0] + bb[0]), spf(c[1] + bb[1]));
            unsigned int u23 = pkbf(spf(c[2] + bb[2]), spf(c[3] + bb[3]));
            unsigned int* dst = (unsigned int*)&P[w][m + 16 * mf][16 * nf + 4 * g];
            dst[0] = u01; dst[1] = u23;
        }
    }

    f32x4 acc2[2][4];
#pragma unroll
    for (int mf = 0; mf < 2; ++mf)
#pragma unroll
        for (int nf = 0; nf < 4; ++nf) acc2[mf][nf] = (f32x4){0.f, 0.f, 0.f, 0.f};

    // ---- GEMM2: K = 128, N = 64 ----
#pragma unroll
    for (int ks = 0; ks < 4; ++ks) {
        bf16x8 b0 = *(const bf16x8*)&P[w][m][32 * ks + 8 * g];
        bf16x8 b1 = *(const bf16x8*)&P[w][m + 16][32 * ks + 8 * g];
#pragma unroll
        for (int nf = 0; nf < 4; ++nf) {
            bf16x8 a = *(const bf16x8*)(pWn2 + ((ks * 4 + nf) * 64 + lane) * 8);
            acc2[0][nf] = __builtin_amdgcn_mfma_f32_16x16x32_bf16(a, b0, acc2[0][nf], 0, 0, 0);
            acc2[1][nf] = __builtin_amdgcn_mfma_f32_16x16x32_bf16(a, b1, acc2[1][nf], 0, 0, 0);
        }
    }

    // ---- epilogue 2: +bn2 +h residual -> t; BN stats ----
#pragma unroll
    for (int nf = 0; nf < 4; ++nf) {
        f32x4 bb = *(const f32x4*)(bn2 + 16 * nf + 4 * g);
        f32x4 s0v = (f32x4){0.f, 0.f, 0.f, 0.f};
        f32x4 s1v = (f32x4){0.f, 0.f, 0.f, 0.f};
#pragma unroll
        for (int mf = 0; mf < 2; ++mf) {
            int cn = mf ? c1 : c0;
            bool vn = mf ? v1 : v0;
            f32x4 hv = *(const f32x4*)(h + (size_t)cn * 64 + 16 * nf + 4 * g);
            f32x4 c = acc2[mf][nf];
            f32x4 tn;
#pragma unroll
            for (int j = 0; j < 4; ++j) tn[j] = c[j] + bb[j] + hv[j];
            if (vn) *(f32x4*)(t + (size_t)cn * 64 + 16 * nf + 4 * g) = tn;
#pragma unroll
            for (int j = 0; j < 4; ++j) {
                float tv = vn ? tn[j] : 0.f;
                s0v[j] += tv;
                s1v[j] += tv * tv;
            }
        }
#pragma unroll
        for (int j = 0; j < 4; ++j) {
#pragma unroll
            for (int k = 1; k <= 8; k <<= 1) {
                s0v[j] += __shfl_xor(s0v[j], k);
                s1v[j] += __shfl_xor(s1v[j], k);
            }
        }
        if (m == 0) {
#pragma unroll
            for (int j = 0; j < 4; ++j) {
                atomicAdd(&stats[16 * nf + 4 * g + j], s0v[j]);
                atomicAdd(&stats[ND + 16 * nf + 4 * g + j], s1v[j]);
            }
        }
    }
}

// ---------------- pooling + readout (unchanged) -------------------------
__global__ __launch_bounds__(256) void k_pool(
    const float* __restrict__ h, const int* __restrict__ batch,
    float* __restrict__ pooled, float* __restrict__ cnt) {
    int lane = threadIdx.x & 63;
    int wave = (blockIdx.x * blockDim.x + threadIdx.x) >> 6;
    int nw = (gridDim.x * blockDim.x) >> 6;
    int chunk = (N_NODES + nw - 1) / nw;
    int s = wave * chunk;
    int epos = min(N_NODES, s + chunk);
    if (s >= N_NODES) return;
    int curg = batch[s];
    float acc = 0.f, c = 0.f;
    for (int i = s; i < epos; ++i) {
        int g = batch[i];
        if (g != curg) {
            atomicAdd(&pooled[curg * ND + lane], acc);
            if (lane == 0) atomicAdd(&cnt[curg], c);
            acc = 0.f; c = 0.f; curg = g;
        }
        acc += h[i * ND + lane];
        c += 1.f;
    }
    atomicAdd(&pooled[curg * ND + lane], acc);
    if (lane == 0) atomicAdd(&cnt[curg], c);
}

__global__ __launch_bounds__(256) void k_readout(
    const float* __restrict__ pooled, const float* __restrict__ cnt,
    const float* __restrict__ Wo1, const float* __restrict__ bo1,
    const float* __restrict__ Wo2, const float* __restrict__ bo2,
    float* __restrict__ out) {
    __shared__ float pbuf[WPB][ND];
    int lane = threadIdx.x & 63;
    int wid = threadIdx.x >> 6;
    int g = blockIdx.x * WPB + wid;
    bool valid = g < N_GRAPH;
    int gc = valid ? g : N_GRAPH - 1;
    float c = fmaxf(cnt[gc], 1.f);
    pbuf[wid][lane] = pooled[gc * ND + lane] / c;
    __syncthreads();
    float h0 = bo1[lane], h1 = bo1[64 + lane];
#pragma unroll 8
    for (int k = 0; k < ND; ++k) {
        float pk = pbuf[wid][k];
        h0 += pk * Wo1[k * HD + lane];
        h1 += pk * Wo1[k * HD + 64 + lane];
    }
    float s = sp(h0) * Wo2[lane] + sp(h1) * Wo2[64 + lane];
#pragma unroll
    for (int off = 32; off; off >>= 1) s += __shfl_down(s, off);
    if (valid && lane == 0) out[g] = s + bo2[0];
}

extern "C" void kernel_launch(void* const* d_in, const int* in_sizes, int n_in,
                              void* d_out, int out_size, void* d_ws, size_t ws_size,
                              hipStream_t stream) {
    const float* x       = (const float*)d_in[0];
    const float* ea      = (const float*)d_in[1];
    const int*   ei      = (const int*)d_in[2];
    const int*   batch   = (const int*)d_in[3];
    const float* Wnp     = (const float*)d_in[4];
    const float* bnp     = (const float*)d_in[5];
    const float* g_np    = (const float*)d_in[6];
    const float* be_np   = (const float*)d_in[7];
    const float* Wep     = (const float*)d_in[8];
    const float* bep     = (const float*)d_in[9];
    const float* We1     = (const float*)d_in[10];
    const float* be1     = (const float*)d_in[11];
    const float* We2     = (const float*)d_in[12];
    const float* be2     = (const float*)d_in[13];
    const float* Wn1     = (const float*)d_in[14];
    const float* bn1     = (const float*)d_in[15];
    const float* Wn2     = (const float*)d_in[16];
    const float* bn2     = (const float*)d_in[17];
    const float* g_bn    = (const float*)d_in[18];
    const float* b_bn    = (const float*)d_in[19];
    const float* Wo1     = (const float*)d_in[20];
    const float* bo1     = (const float*)d_in[21];
    const float* Wo2     = (const float*)d_in[22];
    const float* bo2     = (const float*)d_in[23];

    float* ws = (float*)d_ws;
    size_t off = 0;
    float* h      = ws + off; off += (size_t)N_NODES * ND;
    float* t      = ws + off; off += (size_t)N_NODES * ND;
    float* aggr   = ws + off; off += (size_t)N_NODES * HD;
    float* stats  = ws + off; off += 2 * ND;
    float* ss     = ws + off; off += 2 * ND;
    float* pooled = ws + off; off += N_GRAPH * ND;
    float* cnt    = ws + off; off += 512;
    unsigned short* h_bf = (unsigned short*)(ws + off); off += (size_t)N_NODES * ND / 2;
    unsigned short* aggr_bf = (unsigned short*)(ws + off); off += (size_t)N_NODES * HD / 2;
    unsigned short* pA1  = (unsigned short*)(ws + off); off += 5 * 8 * 64 * 8 / 2;
    unsigned short* pA2  = (unsigned short*)(ws + off); off += 4 * 8 * 64 * 8 / 2;
    unsigned short* pWn1 = (unsigned short*)(ws + off); off += 6 * 8 * 64 * 8 / 2;
    unsigned short* pWn2 = (unsigned short*)(ws + off); off += 4 * 4 * 64 * 8 / 2;
    int* sD       = (int*)(ws + off); off += N_EDGES;
    int* sS       = (int*)(ws + off); off += N_EDGES;
    int* sE       = (int*)(ws + off); off += N_EDGES;
    int* hist     = (int*)(ws + off); off += N_NODES;
    int* cursor   = (int*)(ws + off); off += N_NODES;
    int* rowptr   = (int*)(ws + off); off += N_NODES;
    int* chunksum = (int*)(ws + off); off += 64;
    size_t base_bytes = off * sizeof(float);
    unsigned short* e_bf = (unsigned short*)(ws + off);
    bool epre = (ws_size >= base_bytes + (size_t)N_EDGES * 32 * 2);

    float* outp = (float*)d_out;

    const int NCH = (N_NODES + 1023) / 1024;  // 49

    // ---- counting sort of edges by dst -> CSR (once per call) ----
    hipMemsetAsync(hist, 0, N_NODES * sizeof(int), stream);
    k_hist<<<(N_EDGES + 255) / 256, 256, 0, stream>>>(ei, hist);
    k_scan1<<<NCH, 1024, 0, stream>>>(hist, chunksum);
    k_scan2<<<1, 64, 0, stream>>>(chunksum, NCH);
    k_scan3<<<NCH, 1024, 0, stream>>>(hist, chunksum, cursor, rowptr);
    k_scatter<<<(N_EDGES + 255) / 256, 256, 0, stream>>>(ei, cursor, sD, sS, sE);
    if (epre)
        k_eproj_sorted<<<(int)(((long)N_EDGES * 32 + 255) / 256), 256, 0, stream>>>(
            ea, sE, Wep, bep, e_bf);

    // ---- node projection + BN ----
    hipMemsetAsync(stats, 0, 2 * ND * sizeof(float), stream);
    k_node_proj<<<512, 256, 0, stream>>>(x, Wnp, bnp, t, stats);
    k_bn_finalize<<<1, 64, 0, stream>>>(stats, g_np, be_np, ss);
    k_bn_apply<<<2048, 256, 0, stream>>>(t, ss, h, h_bf);

    for (int l = 0; l < 3; ++l) {
        k_pack_wg<<<(5 * 8 * 64 + 255) / 256, 256, 0, stream>>>(
            We1 + (size_t)l * 160 * HD, pA1, 5, 128);
        k_pack_wg<<<(4 * 8 * 64 + 255) / 256, 256, 0, stream>>>(
            We2 + (size_t)l * HD * HD, pA2, 4, 128);
        k_pack_wg<<<(6 * 8 * 64 + 255) / 256, 256, 0, stream>>>(
            Wn1 + (size_t)l * 192 * HD, pWn1, 6, 128);
        k_pack_wg<<<(4 * 4 * 64 + 255) / 256, 256, 0, stream>>>(
            Wn2 + (size_t)l * HD * ND, pWn2, 4, 64);

        hipMemsetAsync(aggr, 0, (size_t)N_NODES * HD * sizeof(float), stream);
        if (epre)
            k_edge_mfma_s<true><<<N_EDGES / 128, 256, 0, stream>>>(
                h_bf, e_bf, ea, sE, Wep, bep, sD, sS, rowptr, hist,
                pA1, be1 + l * HD, pA2, be2 + l * HD, aggr);
        else
            k_edge_mfma_s<false><<<N_EDGES / 128, 256, 0, stream>>>(
                h_bf, e_bf, ea, sE, Wep, bep, sD, sS, rowptr, hist,
                pA1, be1 + l * HD, pA2, be2 + l * HD, aggr);
        k_cvt_aggr<<<(N_NODES * HD / 8 + 255) / 256, 256, 0, stream>>>(aggr, aggr_bf);

        hipMemsetAsync(stats, 0, 2 * ND * sizeof(float), stream);
        k_node_mfma<<<(N_NODES + 127) / 128, 256, 0, stream>>>(
            h_bf, aggr_bf, h, pWn1, bn1 + l * HD, pWn2, bn2 + l * ND, t, stats);
        k_bn_finalize<<<1, 64, 0, stream>>>(stats, g_bn + l * ND, b_bn + l * ND, ss);
        k_bn_apply<<<2048, 256, 0, stream>>>(t, ss, h, h_bf);
    }

    hipMemsetAsync(pooled, 0, (size_t)(N_GRAPH * ND + 512) * sizeof(float), stream);
    k_pool<<<512, 256, 0, stream>>>(h, batch, pooled, cnt);
    k_readout<<<(N_GRAPH + WPB - 1) / WPB, 256, 0, stream>>>(
        pooled, cnt, Wo1, bo1, Wo2, bo2, outp);
}

// Round 16
// 1562.971 us; speedup vs baseline: 5.0096x; 1.0270x over previous
//
#include <hip/hip_runtime.h>
#include <hip/hip_bf16.h>

#define N_NODES 50000
#define N_EDGES 800000
#define N_GRAPH 500
#define ND 64
#define ED 32
#define HD 128
#define WPB 4   // waves per block (256 threads)

typedef __attribute__((ext_vector_type(8))) short bf16x8;
typedef __attribute__((ext_vector_type(4))) float f32x4;

__device__ __forceinline__ float sp(float x) {
    return fmaxf(x, 0.f) + log1pf(expf(-fabsf(x)));
}

// fast softplus for the bf16 path (v_exp_f32/v_log_f32 based)
__device__ __forceinline__ float spf(float x) {
    return fmaxf(x, 0.f) + __logf(1.f + __expf(-fabsf(x)));
}

__device__ __forceinline__ unsigned short f2bf(float v) {
    __hip_bfloat16 b = __float2bfloat16(v);
    return *(unsigned short*)&b;
}

__device__ __forceinline__ unsigned int pkbf(float a, float b) {
    return (unsigned int)f2bf(a) | ((unsigned int)f2bf(b) << 16);
}

__device__ __forceinline__ float lo_bf(unsigned int u) { return __uint_as_float(u << 16); }
__device__ __forceinline__ float hi_bf(unsigned int u) { return __uint_as_float(u & 0xffff0000u); }

// load 8 fp32 and round to bf16x8 (same RNE as k_bn_apply/f2bf)
__device__ __forceinline__ bf16x8 ld8_f32_bf(const float* p) {
    f32x4 v0 = *(const f32x4*)p;
    f32x4 v1 = *(const f32x4*)(p + 4);
    bf16x8 r;
    r[0] = (short)f2bf(v0[0]); r[1] = (short)f2bf(v0[1]);
    r[2] = (short)f2bf(v0[2]); r[3] = (short)f2bf(v0[3]);
    r[4] = (short)f2bf(v1[0]); r[5] = (short)f2bf(v1[1]);
    r[6] = (short)f2bf(v1[2]); r[7] = (short)f2bf(v1[3]);
    return r;
}

// ---------------- node projection + BN (fp32) ---------------------------
__global__ __launch_bounds__(256) void k_node_proj(
    const float* __restrict__ x, const float* __restrict__ Wnp,
    const float* __restrict__ bnp, float* __restrict__ t,
    float* __restrict__ stats) {
    int lane = threadIdx.x & 63;
    int wave = (blockIdx.x * blockDim.x + threadIdx.x) >> 6;
    int nw = (gridDim.x * blockDim.x) >> 6;
    float w[13];
#pragma unroll
    for (int k = 0; k < 13; ++k) w[k] = Wnp[k * ND + lane];
    float bb = bnp[lane];
    float s0 = 0.f, s1 = 0.f;
    for (int i = wave; i < N_NODES; i += nw) {
        float acc = bb;
#pragma unroll
        for (int k = 0; k < 13; ++k) acc += x[i * 13 + k] * w[k];
        float v = sp(acc);
        t[i * ND + lane] = v;
        s0 += v; s1 += v * v;
    }
    atomicAdd(&stats[lane], s0);
    atomicAdd(&stats[ND + lane], s1);
}

__global__ void k_bn_finalize(const float* __restrict__ stats,
                              const float* __restrict__ g,
                              const float* __restrict__ b,
                              float* __restrict__ ss) {
    int j = threadIdx.x;
    if (j >= ND) return;
    float inv_n = 1.f / (float)N_NODES;
    float mu = stats[j] * inv_n;
    float var = stats[ND + j] * inv_n - mu * mu;
    float rs = rsqrtf(var + 1e-5f);
    float sc = rs * g[j];
    ss[j] = sc;
    ss[ND + j] = b[j] - mu * sc;
}

__global__ __launch_bounds__(256) void k_bn_apply(
    const float* __restrict__ t, const float* __restrict__ ss,
    float* __restrict__ h, unsigned short* __restrict__ hb) {
    int idx = blockIdx.x * blockDim.x + threadIdx.x;
    int tot = N_NODES * ND;
    int stride = gridDim.x * blockDim.x;
    for (; idx < tot; idx += stride) {
        int c = idx & (ND - 1);
        float v = t[idx] * ss[c] + ss[ND + c];
        h[idx] = v;
        hb[idx] = f2bf(v);
    }
}

// ---------------- counting sort of edges by dst -------------------------
__global__ __launch_bounds__(256) void k_hist(const int* __restrict__ ei,
                                              int* __restrict__ hist) {
    int e = blockIdx.x * 256 + threadIdx.x;
    if (e < N_EDGES) atomicAdd(&hist[ei[N_EDGES + e]], 1);
}

__global__ __launch_bounds__(1024) void k_scan1(const int* __restrict__ hist,
                                                int* __restrict__ chunksum) {
    __shared__ int s[1024];
    int t = threadIdx.x;
    int i = blockIdx.x * 1024 + t;
    s[t] = (i < N_NODES) ? hist[i] : 0;
    __syncthreads();
    for (int off = 512; off; off >>= 1) {
        if (t < off) s[t] += s[t + off];
        __syncthreads();
    }
    if (t == 0) chunksum[blockIdx.x] = s[0];
}

__global__ void k_scan2(int* __restrict__ chunksum, int n) {
    if (threadIdx.x == 0) {
        int acc = 0;
        for (int i = 0; i < n; ++i) { int v = chunksum[i]; chunksum[i] = acc; acc += v; }
    }
}

__global__ __launch_bounds__(1024) void k_scan3(const int* __restrict__ hist,
                                                const int* __restrict__ chunksum,
                                                int* __restrict__ cursor,
                                                int* __restrict__ rowptr) {
    __shared__ int s[1024];
    int t = threadIdx.x;
    int i = blockIdx.x * 1024 + t;
    int v = (i < N_NODES) ? hist[i] : 0;
    s[t] = v;
    __syncthreads();
    for (int off = 1; off < 1024; off <<= 1) {
        int u = (t >= off) ? s[t - off] : 0;
        __syncthreads();
        s[t] += u;
        __syncthreads();
    }
    if (i < N_NODES) {
        int ex = chunksum[blockIdx.x] + s[t] - v;  // exclusive
        cursor[i] = ex;
        rowptr[i] = ex;
    }
}

__global__ __launch_bounds__(256) void k_scatter(const int* __restrict__ ei,
                                                 int* __restrict__ cursor,
                                                 int* __restrict__ sD,
                                                 int* __restrict__ sS,
                                                 int* __restrict__ sE) {
    int e = blockIdx.x * 256 + threadIdx.x;
    if (e >= N_EDGES) return;
    int d = ei[N_EDGES + e];
    int pos = atomicAdd(&cursor[d], 1);
    sD[pos] = d;
    sS[pos] = ei[e];
    sE[pos] = e;
}

// edge projection into sorted order (layer-invariant, once per call)
__global__ __launch_bounds__(256) void k_eproj_sorted(
    const float* __restrict__ ea, const int* __restrict__ sE,
    const float* __restrict__ Wep, const float* __restrict__ bep,
    unsigned short* __restrict__ e_bf) {
    long idx = (long)blockIdx.x * blockDim.x + threadIdx.x;
    long tot = (long)N_EDGES * 32;
    if (idx >= tot) return;
    int p = (int)(idx >> 5), col = (int)(idx & 31);
    int e = sE[p];
    float v = spf(ea[2 * e] * Wep[col] + ea[2 * e + 1] * Wep[32 + col] + bep[col]);
    e_bf[idx] = f2bf(v);
}

// ---- fused weight pack: all 3 layers x {We1,We2,Wn1,Wn2} in ONE launch --
// per-layer thread budget: We1 40*64 | We2 32*64 | Wn1 48*64 | Wn2 16*64
__global__ __launch_bounds__(256) void k_pack_all(
    const float* __restrict__ We1, const float* __restrict__ We2,
    const float* __restrict__ Wn1, const float* __restrict__ Wn2,
    unsigned short* __restrict__ pA1, unsigned short* __restrict__ pA2,
    unsigned short* __restrict__ pWn1, unsigned short* __restrict__ pWn2) {
    int tid = blockIdx.x * 256 + threadIdx.x;
    const int PER_L = (40 + 32 + 48 + 16) * 64;  // 8704
    if (tid >= 3 * PER_L) return;
    int layer = tid / PER_L;
    int r = tid % PER_L;
    const float* W;
    unsigned short* out;
    int ksteps, ncols, lt;
    if (r < 40 * 64) {
        lt = r; W = We1 + (size_t)layer * 160 * 128; out = pA1 + (size_t)layer * 40 * 64 * 8;
        ksteps = 5; ncols = 128;
    } else if (r < 72 * 64) {
        lt = r - 40 * 64; W = We2 + (size_t)layer * 128 * 128; out = pA2 + (size_t)layer * 32 * 64 * 8;
        ksteps = 4; ncols = 128;
    } else if (r < 120 * 64) {
        lt = r - 72 * 64; W = Wn1 + (size_t)layer * 192 * 128; out = pWn1 + (size_t)layer * 48 * 64 * 8;
        ksteps = 6; ncols = 128;
    } else {
        lt = r - 120 * 64; W = Wn2 + (size_t)layer * 128 * 64; out = pWn2 + (size_t)layer * 16 * 64 * 8;
        ksteps = 4; ncols = 64;
    }
    int nfrag = ncols >> 4;
    int l = lt & 63; int fr = lt >> 6; int nf = fr % nfrag; int ks = fr / nfrag;
    int n = 16 * nf + (l & 15);
    int k0 = 32 * ks + 8 * (l >> 4);
    (void)ksteps;
#pragma unroll
    for (int rr = 0; rr < 8; ++rr)
        out[lt * 8 + rr] = f2bf(W[(k0 + rr) * ncols + n]);
}

// ---------------- MFMA edge conv on dst-sorted edges --------------------
// Epilogue: stage all 128 edge-result rows (bf16) in LDS, then block-wide
// run-length segmented reduction. Interior nodes get plain stores; only
// block-boundary nodes use atomics. (256,4): VGPR=72 fits the 128 cap,
// LDS 35.3KB*4=141KB fits -> 4 blocks/CU for latency hiding.
template <bool EPRE>
__global__ __launch_bounds__(256, 4) void k_edge_mfma_s(
    const unsigned short* __restrict__ h_bf, const unsigned short* __restrict__ e_bf,
    const float* __restrict__ ea, const int* __restrict__ sE,
    const float* __restrict__ Wep, const float* __restrict__ bep,
    const int* __restrict__ sD, const int* __restrict__ sS,
    const int* __restrict__ rowptr, const int* __restrict__ hist,
    const unsigned short* __restrict__ pA1, const float* __restrict__ be1,
    const unsigned short* __restrict__ pA2, const float* __restrict__ be2,
    float* __restrict__ aggr) {
    __shared__ unsigned short P[WPB][32][136];   // per-wave P; reused as 128-row stage
    __shared__ int dstB[128];
    __shared__ unsigned short eL[EPRE ? 64 : 128 * 32];

    int lane = threadIdx.x & 63;
    int w = threadIdx.x >> 6;
    int m = lane & 15, g = lane >> 4;
    int tile0 = blockIdx.x * 128;
    int wbase = tile0 + 32 * w;

    int eD0 = sD[wbase + m];
    int eD1 = sD[wbase + 16 + m];
    int eS0 = sS[wbase + m];
    int eS1 = sS[wbase + 16 + m];

    if constexpr (!EPRE) {
        int col = threadIdx.x & 31;
        int r0 = threadIdx.x >> 5;
        float w0 = Wep[col], w1 = Wep[32 + col], bb = bep[col];
#pragma unroll
        for (int i = 0; i < 16; ++i) {
            int em = r0 + 8 * i;
            int e = sE[tile0 + em];
            eL[em * 32 + col] = f2bf(spf(ea[2 * e] * w0 + ea[2 * e + 1] * w1 + bb));
        }
        __syncthreads();
    }

    f32x4 acc[2][8];
#pragma unroll
    for (int mf = 0; mf < 2; ++mf)
#pragma unroll
        for (int nf = 0; nf < 8; ++nf) acc[mf][nf] = (f32x4){0.f, 0.f, 0.f, 0.f};

    // ---- GEMM1: K = 160 (dst 64 | src 64 | e 32) ----
#pragma unroll
    for (int ks = 0; ks < 5; ++ks) {
        bf16x8 b0, b1;
        if (ks < 2) {
            b0 = *(const bf16x8*)(h_bf + (size_t)eD0 * 64 + ks * 32 + 8 * g);
            b1 = *(const bf16x8*)(h_bf + (size_t)eD1 * 64 + ks * 32 + 8 * g);
        } else if (ks < 4) {
            b0 = *(const bf16x8*)(h_bf + (size_t)eS0 * 64 + (ks - 2) * 32 + 8 * g);
            b1 = *(const bf16x8*)(h_bf + (size_t)eS1 * 64 + (ks - 2) * 32 + 8 * g);
        } else {
            if constexpr (EPRE) {
                b0 = *(const bf16x8*)(e_bf + (size_t)(wbase + m) * 32 + 8 * g);
                b1 = *(const bf16x8*)(e_bf + (size_t)(wbase + 16 + m) * 32 + 8 * g);
            } else {
                b0 = *(const bf16x8*)&eL[(32 * w + m) * 32 + 8 * g];
                b1 = *(const bf16x8*)&eL[(32 * w + 16 + m) * 32 + 8 * g];
            }
        }
#pragma unroll
        for (int nf = 0; nf < 8; ++nf) {
            bf16x8 a = *(const bf16x8*)(pA1 + ((ks * 8 + nf) * 64 + lane) * 8);
            acc[0][nf] = __builtin_amdgcn_mfma_f32_16x16x32_bf16(a, b0, acc[0][nf], 0, 0, 0);
            acc[1][nf] = __builtin_amdgcn_mfma_f32_16x16x32_bf16(a, b1, acc[1][nf], 0, 0, 0);
        }
    }

    // ---- epilogue 1: bias + fast softplus -> P (bf16) in LDS ----
#pragma unroll
    for (int nf = 0; nf < 8; ++nf) {
        f32x4 bb = *(const f32x4*)(be1 + 16 * nf + 4 * g);
#pragma unroll
        for (int mf = 0; mf < 2; ++mf) {
            f32x4 c = acc[mf][nf];
            unsigned int u01 = pkbf(spf(c[0] + bb[0]), spf(c[1] + bb[1]));
            unsigned int u23 = pkbf(spf(c[2] + bb[2]), spf(c[3] + bb[3]));
            unsigned int* dst = (unsigned int*)&P[w][m + 16 * mf][16 * nf + 4 * g];
            dst[0] = u01; dst[1] = u23;
        }
    }

    f32x4 acc2[2][8];
#pragma unroll
    for (int mf = 0; mf < 2; ++mf)
#pragma unroll
        for (int nf = 0; nf < 8; ++nf) acc2[mf][nf] = (f32x4){0.f, 0.f, 0.f, 0.f};

    // ---- GEMM2: K = 128, B = P^T from LDS (wave-private rows) ----
#pragma unroll
    for (int ks = 0; ks < 4; ++ks) {
        bf16x8 b0 = *(const bf16x8*)&P[w][m][32 * ks + 8 * g];
        bf16x8 b1 = *(const bf16x8*)&P[w][m + 16][32 * ks + 8 * g];
#pragma unroll
        for (int nf = 0; nf < 8; ++nf) {
            bf16x8 a = *(const bf16x8*)(pA2 + ((ks * 8 + nf) * 64 + lane) * 8);
            acc2[0][nf] = __builtin_amdgcn_mfma_f32_16x16x32_bf16(a, b0, acc2[0][nf], 0, 0, 0);
            acc2[1][nf] = __builtin_amdgcn_mfma_f32_16x16x32_bf16(a, b1, acc2[1][nf], 0, 0, 0);
        }
    }

    // ---- epilogue 2: stage bf16 m rows (full block) + dst table ----
    unsigned short (*Pf)[136] = (unsigned short(*)[136]) & P[0][0][0];
#pragma unroll
    for (int nf = 0; nf < 8; ++nf) {
        f32x4 bb = *(const f32x4*)(be2 + 16 * nf + 4 * g);
#pragma unroll
        for (int mf = 0; mf < 2; ++mf) {
            f32x4 c = acc2[mf][nf];
            unsigned int* dst = (unsigned int*)&Pf[32 * w + 16 * mf + m][16 * nf + 4 * g];
            dst[0] = pkbf(spf(c[0] + bb[0]), spf(c[1] + bb[1]));
            dst[1] = pkbf(spf(c[2] + bb[2]), spf(c[3] + bb[3]));
        }
    }
    if (g == 0) {
        dstB[32 * w + m] = eD0;
        dstB[32 * w + 16 + m] = eD1;
    }
    __syncthreads();

    // ---- block-wide run-length segmented reduction ----
    int rbeg = 32 * w, rend = rbeg + 32;
    int r = rbeg;
    if (w) {  // skip rows continuing a run that started in a lower wave
        while (r < rend && dstB[r] == dstB[r - 1]) ++r;
    }
    while (r < rend) {
        int d = dstB[r];
        float a0 = 0.f, a1 = 0.f;
        int rr = r;
        do {
            unsigned int u = *(const unsigned int*)&Pf[rr][2 * lane];
            a0 += lo_bf(u);
            a1 += hi_bf(u);
            ++rr;
        } while (rr < 128 && dstB[rr] == d);
        int s0 = rowptr[d];
        bool interior = (s0 >= tile0) && (s0 + hist[d] <= tile0 + 128);
        float* base = aggr + (size_t)d * HD + 2 * lane;
        if (interior) {
            base[0] = a0;
            base[1] = a1;
        } else {
            atomicAdd(base, a0);
            atomicAdd(base + 1, a1);
        }
        r = rr;
    }
}

// ---------------- MFMA node update (reads fp32 aggr, inline bf16 cvt) ----
__global__ __launch_bounds__(256, 3) void k_node_mfma(
    const unsigned short* __restrict__ h_bf, const float* __restrict__ aggr,
    const float* __restrict__ h,
    const unsigned short* __restrict__ pWn1, const float* __restrict__ bn1,
    const unsigned short* __restrict__ pWn2, const float* __restrict__ bn2,
    float* __restrict__ t, float* __restrict__ stats) {
    __shared__ unsigned short P[WPB][32][136];

    int lane = threadIdx.x & 63;
    int w = threadIdx.x >> 6;
    int m = lane & 15, g = lane >> 4;
    int tile0 = blockIdx.x * 128;
    int wbase = tile0 + 32 * w;
    int n0 = wbase + m, n1 = wbase + 16 + m;
    bool v0 = n0 < N_NODES, v1 = n1 < N_NODES;
    int c0 = v0 ? n0 : N_NODES - 1;
    int c1 = v1 ? n1 : N_NODES - 1;

    f32x4 acc[2][8];
#pragma unroll
    for (int mf = 0; mf < 2; ++mf)
#pragma unroll
        for (int nf = 0; nf < 8; ++nf) acc[mf][nf] = (f32x4){0.f, 0.f, 0.f, 0.f};

    // ---- GEMM1: K = 192 (h 64 | aggr 128) ----
#pragma unroll
    for (int ks = 0; ks < 6; ++ks) {
        bf16x8 b0, b1;
        if (ks < 2) {
            b0 = *(const bf16x8*)(h_bf + (size_t)c0 * 64 + ks * 32 + 8 * g);
            b1 = *(const bf16x8*)(h_bf + (size_t)c1 * 64 + ks * 32 + 8 * g);
        } else {
            b0 = ld8_f32_bf(aggr + (size_t)c0 * 128 + (ks - 2) * 32 + 8 * g);
            b1 = ld8_f32_bf(aggr + (size_t)c1 * 128 + (ks - 2) * 32 + 8 * g);
        }
#pragma unroll
        for (int nf = 0; nf < 8; ++nf) {
            bf16x8 a = *(const bf16x8*)(pWn1 + ((ks * 8 + nf) * 64 + lane) * 8);
            acc[0][nf] = __builtin_amdgcn_mfma_f32_16x16x32_bf16(a, b0, acc[0][nf], 0, 0, 0);
            acc[1][nf] = __builtin_amdgcn_mfma_f32_16x16x32_bf16(a, b1, acc[1][nf], 0, 0, 0);
        }
    }

    // ---- epilogue 1: bias + fast softplus -> P (bf16) in LDS ----
#pragma unroll
    for (int nf = 0; nf < 8; ++nf) {
        f32x4 bb = *(const f32x4*)(bn1 + 16 * nf + 4 * g);
#pragma unroll
        for (int mf = 0; mf < 2; ++mf) {
            f32x4 c = acc[mf][nf];
            unsigned int u01 = pkbf(spf(c[0] + bb[0]), spf(c[1] + bb[1]));
            unsigned int u23 = pkbf(spf(c[2] + bb[2]), spf(c[3] + bb[3]));
            unsigned int* dst = (unsigned int*)&P[w][m + 16 * mf][16 * nf + 4 * g];
            dst[0] = u01; dst[1] = u23;
        }
    }

    f32x4 acc2[2][4];
#pragma unroll
    for (int mf = 0; mf < 2; ++mf)
#pragma unroll
        for (int nf = 0; nf < 4; ++nf) acc2[mf][nf] = (f32x4){0.f, 0.f, 0.f, 0.f};

    // ---- GEMM2: K = 128, N = 64 ----
#pragma unroll
    for (int ks = 0; ks < 4; ++ks) {
        bf16x8 b0 = *(const bf16x8*)&P[w][m][32 * ks + 8 * g];
        bf16x8 b1 = *(const bf16x8*)&P[w][m + 16][32 * ks + 8 * g];
#pragma unroll
        for (int nf = 0; nf < 4; ++nf) {
            bf16x8 a = *(const bf16x8*)(pWn2 + ((ks * 4 + nf) * 64 + lane) * 8);
            acc2[0][nf] = __builtin_amdgcn_mfma_f32_16x16x32_bf16(a, b0, acc2[0][nf], 0, 0, 0);
            acc2[1][nf] = __builtin_amdgcn_mfma_f32_16x16x32_bf16(a, b1, acc2[1][nf], 0, 0, 0);
        }
    }

    // ---- epilogue 2: +bn2 +h residual -> t; BN stats ----
#pragma unroll
    for (int nf = 0; nf < 4; ++nf) {
        f32x4 bb = *(const f32x4*)(bn2 + 16 * nf + 4 * g);
        f32x4 s0v = (f32x4){0.f, 0.f, 0.f, 0.f};
        f32x4 s1v = (f32x4){0.f, 0.f, 0.f, 0.f};
#pragma unroll
        for (int mf = 0; mf < 2; ++mf) {
            int cn = mf ? c1 : c0;
            bool vn = mf ? v1 : v0;
            f32x4 hv = *(const f32x4*)(h + (size_t)cn * 64 + 16 * nf + 4 * g);
            f32x4 c = acc2[mf][nf];
            f32x4 tn;
#pragma unroll
            for (int j = 0; j < 4; ++j) tn[j] = c[j] + bb[j] + hv[j];
            if (vn) *(f32x4*)(t + (size_t)cn * 64 + 16 * nf + 4 * g) = tn;
#pragma unroll
            for (int j = 0; j < 4; ++j) {
                float tv = vn ? tn[j] : 0.f;
                s0v[j] += tv;
                s1v[j] += tv * tv;
            }
        }
#pragma unroll
        for (int j = 0; j < 4; ++j) {
#pragma unroll
            for (int k = 1; k <= 8; k <<= 1) {
                s0v[j] += __shfl_xor(s0v[j], k);
                s1v[j] += __shfl_xor(s1v[j], k);
            }
        }
        if (m == 0) {
#pragma unroll
            for (int j = 0; j < 4; ++j) {
                atomicAdd(&stats[16 * nf + 4 * g + j], s0v[j]);
                atomicAdd(&stats[ND + 16 * nf + 4 * g + j], s1v[j]);
            }
        }
    }
}

// ---------------- pooling + readout (unchanged) -------------------------
__global__ __launch_bounds__(256) void k_pool(
    const float* __restrict__ h, const int* __restrict__ batch,
    float* __restrict__ pooled, float* __restrict__ cnt) {
    int lane = threadIdx.x & 63;
    int wave = (blockIdx.x * blockDim.x + threadIdx.x) >> 6;
    int nw = (gridDim.x * blockDim.x) >> 6;
    int chunk = (N_NODES + nw - 1) / nw;
    int s = wave * chunk;
    int epos = min(N_NODES, s + chunk);
    if (s >= N_NODES) return;
    int curg = batch[s];
    float acc = 0.f, c = 0.f;
    for (int i = s; i < epos; ++i) {
        int g = batch[i];
        if (g != curg) {
            atomicAdd(&pooled[curg * ND + lane], acc);
            if (lane == 0) atomicAdd(&cnt[curg], c);
            acc = 0.f; c = 0.f; curg = g;
        }
        acc += h[i * ND + lane];
        c += 1.f;
    }
    atomicAdd(&pooled[curg * ND + lane], acc);
    if (lane == 0) atomicAdd(&cnt[curg], c);
}

__global__ __launch_bounds__(256) void k_readout(
    const float* __restrict__ pooled, const float* __restrict__ cnt,
    const float* __restrict__ Wo1, const float* __restrict__ bo1,
    const float* __restrict__ Wo2, const float* __restrict__ bo2,
    float* __restrict__ out) {
    __shared__ float pbuf[WPB][ND];
    int lane = threadIdx.x & 63;
    int wid = threadIdx.x >> 6;
    int g = blockIdx.x * WPB + wid;
    bool valid = g < N_GRAPH;
    int gc = valid ? g : N_GRAPH - 1;
    float c = fmaxf(cnt[gc], 1.f);
    pbuf[wid][lane] = pooled[gc * ND + lane] / c;
    __syncthreads();
    float h0 = bo1[lane], h1 = bo1[64 + lane];
#pragma unroll 8
    for (int k = 0; k < ND; ++k) {
        float pk = pbuf[wid][k];
        h0 += pk * Wo1[k * HD + lane];
        h1 += pk * Wo1[k * HD + 64 + lane];
    }
    float s = sp(h0) * Wo2[lane] + sp(h1) * Wo2[64 + lane];
#pragma unroll
    for (int off = 32; off; off >>= 1) s += __shfl_down(s, off);
    if (valid && lane == 0) out[g] = s + bo2[0];
}

extern "C" void kernel_launch(void* const* d_in, const int* in_sizes, int n_in,
                              void* d_out, int out_size, void* d_ws, size_t ws_size,
                              hipStream_t stream) {
    const float* x       = (const float*)d_in[0];
    const float* ea      = (const float*)d_in[1];
    const int*   ei      = (const int*)d_in[2];
    const int*   batch   = (const int*)d_in[3];
    const float* Wnp     = (const float*)d_in[4];
    const float* bnp     = (const float*)d_in[5];
    const float* g_np    = (const float*)d_in[6];
    const float* be_np   = (const float*)d_in[7];
    const float* Wep     = (const float*)d_in[8];
    const float* bep     = (const float*)d_in[9];
    const float* We1     = (const float*)d_in[10];
    const float* be1     = (const float*)d_in[11];
    const float* We2     = (const float*)d_in[12];
    const float* be2     = (const float*)d_in[13];
    const float* Wn1     = (const float*)d_in[14];
    const float* bn1     = (const float*)d_in[15];
    const float* Wn2     = (const float*)d_in[16];
    const float* bn2     = (const float*)d_in[17];
    const float* g_bn    = (const float*)d_in[18];
    const float* b_bn    = (const float*)d_in[19];
    const float* Wo1     = (const float*)d_in[20];
    const float* bo1     = (const float*)d_in[21];
    const float* Wo2     = (const float*)d_in[22];
    const float* bo2     = (const float*)d_in[23];

    float* ws = (float*)d_ws;
    size_t off = 0;
    float* h      = ws + off; off += (size_t)N_NODES * ND;
    float* t      = ws + off; off += (size_t)N_NODES * ND;
    float* aggr   = ws + off; off += (size_t)N_NODES * HD;
    float* stats  = ws + off; off += 2 * ND;
    float* ss     = ws + off; off += 2 * ND;
    float* pooled = ws + off; off += N_GRAPH * ND;
    float* cnt    = ws + off; off += 512;
    unsigned short* h_bf = (unsigned short*)(ws + off); off += (size_t)N_NODES * ND / 2;
    unsigned short* pA1  = (unsigned short*)(ws + off); off += 3 * 5 * 8 * 64 * 8 / 2;
    unsigned short* pA2  = (unsigned short*)(ws + off); off += 3 * 4 * 8 * 64 * 8 / 2;
    unsigned short* pWn1 = (unsigned short*)(ws + off); off += 3 * 6 * 8 * 64 * 8 / 2;
    unsigned short* pWn2 = (unsigned short*)(ws + off); off += 3 * 4 * 4 * 64 * 8 / 2;
    int* sD       = (int*)(ws + off); off += N_EDGES;
    int* sS       = (int*)(ws + off); off += N_EDGES;
    int* sE       = (int*)(ws + off); off += N_EDGES;
    int* hist     = (int*)(ws + off); off += N_NODES;
    int* cursor   = (int*)(ws + off); off += N_NODES;
    int* rowptr   = (int*)(ws + off); off += N_NODES;
    int* chunksum = (int*)(ws + off); off += 64;
    size_t base_bytes = off * sizeof(float);
    unsigned short* e_bf = (unsigned short*)(ws + off);
    bool epre = (ws_size >= base_bytes + (size_t)N_EDGES * 32 * 2);

    float* outp = (float*)d_out;

    const int NCH = (N_NODES + 1023) / 1024;  // 49

    // ---- counting sort of edges by dst -> CSR (once per call) ----
    hipMemsetAsync(hist, 0, N_NODES * sizeof(int), stream);
    k_hist<<<(N_EDGES + 255) / 256, 256, 0, stream>>>(ei, hist);
    k_scan1<<<NCH, 1024, 0, stream>>>(hist, chunksum);
    k_scan2<<<1, 64, 0, stream>>>(chunksum, NCH);
    k_scan3<<<NCH, 1024, 0, stream>>>(hist, chunksum, cursor, rowptr);
    k_scatter<<<(N_EDGES + 255) / 256, 256, 0, stream>>>(ei, cursor, sD, sS, sE);
    if (epre)
        k_eproj_sorted<<<(int)(((long)N_EDGES * 32 + 255) / 256), 256, 0, stream>>>(
            ea, sE, Wep, bep, e_bf);

    // ---- pack all weights (3 layers x 4 matrices) in one launch ----
    k_pack_all<<<(3 * 8704 + 255) / 256, 256, 0, stream>>>(
        We1, We2, Wn1, Wn2, pA1, pA2, pWn1, pWn2);

    // ---- node projection + BN ----
    hipMemsetAsync(stats, 0, 2 * ND * sizeof(float), stream);
    k_node_proj<<<512, 256, 0, stream>>>(x, Wnp, bnp, t, stats);
    k_bn_finalize<<<1, 64, 0, stream>>>(stats, g_np, be_np, ss);
    k_bn_apply<<<2048, 256, 0, stream>>>(t, ss, h, h_bf);

    for (int l = 0; l < 3; ++l) {
        hipMemsetAsync(aggr, 0, (size_t)N_NODES * HD * sizeof(float), stream);
        if (epre)
            k_edge_mfma_s<true><<<N_EDGES / 128, 256, 0, stream>>>(
                h_bf, e_bf, ea, sE, Wep, bep, sD, sS, rowptr, hist,
                pA1 + (size_t)l * 40 * 64 * 8, be1 + l * HD,
                pA2 + (size_t)l * 32 * 64 * 8, be2 + l * HD, aggr);
        else
            k_edge_mfma_s<false><<<N_EDGES / 128, 256, 0, stream>>>(
                h_bf, e_bf, ea, sE, Wep, bep, sD, sS, rowptr, hist,
                pA1 + (size_t)l * 40 * 64 * 8, be1 + l * HD,
                pA2 + (size_t)l * 32 * 64 * 8, be2 + l * HD, aggr);

        hipMemsetAsync(stats, 0, 2 * ND * sizeof(float), stream);
        k_node_mfma<<<(N_NODES + 127) / 128, 256, 0, stream>>>(
            h_bf, aggr, h,
            pWn1 + (size_t)l * 48 * 64 * 8, bn1 + l * HD,
            pWn2 + (size_t)l * 16 * 64 * 8, bn2 + l * ND, t, stats);
        k_bn_finalize<<<1, 64, 0, stream>>>(stats, g_bn + l * ND, b_bn + l * ND, ss);
        k_bn_apply<<<2048, 256, 0, stream>>>(t, ss, h, h_bf);
    }

    hipMemsetAsync(pooled, 0, (size_t)(N_GRAPH * ND + 512) * sizeof(float), stream);
    k_pool<<<512, 256, 0, stream>>>(h, batch, pooled, cnt);
    k_readout<<<(N_GRAPH + WPB - 1) / WPB, 256, 0, stream>>>(
        pooled, cnt, Wo1, bo1, Wo2, bo2, outp);
}

// Round 17
// 1554.750 us; speedup vs baseline: 5.0361x; 1.0053x over previous
//
#include <hip/hip_runtime.h>
#include <hip/hip_bf16.h>

#define N_NODES 50000
#define N_EDGES 800000
#define N_GRAPH 500
#define ND 64
#define ED 32
#define HD 128
#define WPB 4   // waves per block (256 threads)

typedef __attribute__((ext_vector_type(8))) short bf16x8;
typedef __attribute__((ext_vector_type(4))) float f32x4;

__device__ __forceinline__ float sp(float x) {
    return fmaxf(x, 0.f) + log1pf(expf(-fabsf(x)));
}

// fast softplus for the bf16 path (v_exp_f32/v_log_f32 based)
__device__ __forceinline__ float spf(float x) {
    return fmaxf(x, 0.f) + __logf(1.f + __expf(-fabsf(x)));
}

__device__ __forceinline__ unsigned short f2bf(float v) {
    __hip_bfloat16 b = __float2bfloat16(v);
    return *(unsigned short*)&b;
}

__device__ __forceinline__ unsigned int pkbf(float a, float b) {
    return (unsigned int)f2bf(a) | ((unsigned int)f2bf(b) << 16);
}

__device__ __forceinline__ float lo_bf(unsigned int u) { return __uint_as_float(u << 16); }
__device__ __forceinline__ float hi_bf(unsigned int u) { return __uint_as_float(u & 0xffff0000u); }

// load 8 fp32 and round to bf16x8 (same RNE as k_bn_apply/f2bf)
__device__ __forceinline__ bf16x8 ld8_f32_bf(const float* p) {
    f32x4 v0 = *(const f32x4*)p;
    f32x4 v1 = *(const f32x4*)(p + 4);
    bf16x8 r;
    r[0] = (short)f2bf(v0[0]); r[1] = (short)f2bf(v0[1]);
    r[2] = (short)f2bf(v0[2]); r[3] = (short)f2bf(v0[3]);
    r[4] = (short)f2bf(v1[0]); r[5] = (short)f2bf(v1[1]);
    r[6] = (short)f2bf(v1[2]); r[7] = (short)f2bf(v1[3]);
    return r;
}

// ---------------- node projection + BN (fp32) ---------------------------
__global__ __launch_bounds__(256) void k_node_proj(
    const float* __restrict__ x, const float* __restrict__ Wnp,
    const float* __restrict__ bnp, float* __restrict__ t,
    float* __restrict__ stats) {
    int lane = threadIdx.x & 63;
    int wave = (blockIdx.x * blockDim.x + threadIdx.x) >> 6;
    int nw = (gridDim.x * blockDim.x) >> 6;
    float w[13];
#pragma unroll
    for (int k = 0; k < 13; ++k) w[k] = Wnp[k * ND + lane];
    float bb = bnp[lane];
    float s0 = 0.f, s1 = 0.f;
    for (int i = wave; i < N_NODES; i += nw) {
        float acc = bb;
#pragma unroll
        for (int k = 0; k < 13; ++k) acc += x[i * 13 + k] * w[k];
        float v = sp(acc);
        t[i * ND + lane] = v;
        s0 += v; s1 += v * v;
    }
    atomicAdd(&stats[lane], s0);
    atomicAdd(&stats[ND + lane], s1);
}

__global__ void k_bn_finalize(const float* __restrict__ stats,
                              const float* __restrict__ g,
                              const float* __restrict__ b,
                              float* __restrict__ ss) {
    int j = threadIdx.x;
    if (j >= ND) return;
    float inv_n = 1.f / (float)N_NODES;
    float mu = stats[j] * inv_n;
    float var = stats[ND + j] * inv_n - mu * mu;
    float rs = rsqrtf(var + 1e-5f);
    float sc = rs * g[j];
    ss[j] = sc;
    ss[ND + j] = b[j] - mu * sc;
}

__global__ __launch_bounds__(256) void k_bn_apply(
    const float* __restrict__ t, const float* __restrict__ ss,
    float* __restrict__ h, unsigned short* __restrict__ hb) {
    int idx = blockIdx.x * blockDim.x + threadIdx.x;
    int tot = N_NODES * ND;
    int stride = gridDim.x * blockDim.x;
    for (; idx < tot; idx += stride) {
        int c = idx & (ND - 1);
        float v = t[idx] * ss[c] + ss[ND + c];
        h[idx] = v;
        hb[idx] = f2bf(v);
    }
}

// ---------------- counting sort of edges by dst -------------------------
__global__ __launch_bounds__(256) void k_hist(const int* __restrict__ ei,
                                              int* __restrict__ hist) {
    int e = blockIdx.x * 256 + threadIdx.x;
    if (e < N_EDGES) atomicAdd(&hist[ei[N_EDGES + e]], 1);
}

__global__ __launch_bounds__(1024) void k_scan1(const int* __restrict__ hist,
                                                int* __restrict__ chunksum) {
    __shared__ int s[1024];
    int t = threadIdx.x;
    int i = blockIdx.x * 1024 + t;
    s[t] = (i < N_NODES) ? hist[i] : 0;
    __syncthreads();
    for (int off = 512; off; off >>= 1) {
        if (t < off) s[t] += s[t + off];
        __syncthreads();
    }
    if (t == 0) chunksum[blockIdx.x] = s[0];
}

__global__ void k_scan2(int* __restrict__ chunksum, int n) {
    if (threadIdx.x == 0) {
        int acc = 0;
        for (int i = 0; i < n; ++i) { int v = chunksum[i]; chunksum[i] = acc; acc += v; }
    }
}

__global__ __launch_bounds__(1024) void k_scan3(const int* __restrict__ hist,
                                                const int* __restrict__ chunksum,
                                                int* __restrict__ cursor,
                                                int* __restrict__ rowptr) {
    __shared__ int s[1024];
    int t = threadIdx.x;
    int i = blockIdx.x * 1024 + t;
    int v = (i < N_NODES) ? hist[i] : 0;
    s[t] = v;
    __syncthreads();
    for (int off = 1; off < 1024; off <<= 1) {
        int u = (t >= off) ? s[t - off] : 0;
        __syncthreads();
        s[t] += u;
        __syncthreads();
    }
    if (i < N_NODES) {
        int ex = chunksum[blockIdx.x] + s[t] - v;  // exclusive
        cursor[i] = ex;
        rowptr[i] = ex;
    }
}

__global__ __launch_bounds__(256) void k_scatter(const int* __restrict__ ei,
                                                 int* __restrict__ cursor,
                                                 int* __restrict__ sD,
                                                 int* __restrict__ sS,
                                                 int* __restrict__ sE) {
    int e = blockIdx.x * 256 + threadIdx.x;
    if (e >= N_EDGES) return;
    int d = ei[N_EDGES + e];
    int pos = atomicAdd(&cursor[d], 1);
    sD[pos] = d;
    sS[pos] = ei[e];
    sE[pos] = e;
}

// edge projection into sorted order (layer-invariant, once per call)
__global__ __launch_bounds__(256) void k_eproj_sorted(
    const float* __restrict__ ea, const int* __restrict__ sE,
    const float* __restrict__ Wep, const float* __restrict__ bep,
    unsigned short* __restrict__ e_bf) {
    long idx = (long)blockIdx.x * blockDim.x + threadIdx.x;
    long tot = (long)N_EDGES * 32;
    if (idx >= tot) return;
    int p = (int)(idx >> 5), col = (int)(idx & 31);
    int e = sE[p];
    float v = spf(ea[2 * e] * Wep[col] + ea[2 * e + 1] * Wep[32 + col] + bep[col]);
    e_bf[idx] = f2bf(v);
}

// ---- fused weight pack: all 3 layers x {We1,We2,Wn1,Wn2} in ONE launch --
__global__ __launch_bounds__(256) void k_pack_all(
    const float* __restrict__ We1, const float* __restrict__ We2,
    const float* __restrict__ Wn1, const float* __restrict__ Wn2,
    unsigned short* __restrict__ pA1, unsigned short* __restrict__ pA2,
    unsigned short* __restrict__ pWn1, unsigned short* __restrict__ pWn2) {
    int tid = blockIdx.x * 256 + threadIdx.x;
    const int PER_L = (40 + 32 + 48 + 16) * 64;  // 8704
    if (tid >= 3 * PER_L) return;
    int layer = tid / PER_L;
    int r = tid % PER_L;
    const float* W;
    unsigned short* out;
    int ncols, lt;
    if (r < 40 * 64) {
        lt = r; W = We1 + (size_t)layer * 160 * 128; out = pA1 + (size_t)layer * 40 * 64 * 8;
        ncols = 128;
    } else if (r < 72 * 64) {
        lt = r - 40 * 64; W = We2 + (size_t)layer * 128 * 128; out = pA2 + (size_t)layer * 32 * 64 * 8;
        ncols = 128;
    } else if (r < 120 * 64) {
        lt = r - 72 * 64; W = Wn1 + (size_t)layer * 192 * 128; out = pWn1 + (size_t)layer * 48 * 64 * 8;
        ncols = 128;
    } else {
        lt = r - 120 * 64; W = Wn2 + (size_t)layer * 128 * 64; out = pWn2 + (size_t)layer * 16 * 64 * 8;
        ncols = 64;
    }
    int nfrag = ncols >> 4;
    int l = lt & 63; int fr = lt >> 6; int nf = fr % nfrag; int ks = fr / nfrag;
    int n = 16 * nf + (l & 15);
    int k0 = 32 * ks + 8 * (l >> 4);
#pragma unroll
    for (int rr = 0; rr < 8; ++rr)
        out[lt * 8 + rr] = f2bf(W[(k0 + rr) * ncols + n]);
}

// ---------------- MFMA edge conv on dst-sorted edges --------------------
// (256,3): 170-reg budget fits the ~136-reg live set (acc+acc2 = 64 AGPR)
// with NO spill, at 3 blocks/CU (round 16's (256,4) spilled ~230 MB).
template <bool EPRE>
__global__ __launch_bounds__(256, 3) void k_edge_mfma_s(
    const unsigned short* __restrict__ h_bf, const unsigned short* __restrict__ e_bf,
    const float* __restrict__ ea, const int* __restrict__ sE,
    const float* __restrict__ Wep, const float* __restrict__ bep,
    const int* __restrict__ sD, const int* __restrict__ sS,
    const int* __restrict__ rowptr, const int* __restrict__ hist,
    const unsigned short* __restrict__ pA1, const float* __restrict__ be1,
    const unsigned short* __restrict__ pA2, const float* __restrict__ be2,
    float* __restrict__ aggr) {
    __shared__ unsigned short P[WPB][32][136];   // per-wave P; reused as 128-row stage
    __shared__ int dstB[128];
    __shared__ unsigned short eL[EPRE ? 64 : 128 * 32];

    int lane = threadIdx.x & 63;
    int w = threadIdx.x >> 6;
    int m = lane & 15, g = lane >> 4;
    int tile0 = blockIdx.x * 128;
    int wbase = tile0 + 32 * w;

    int eD0 = sD[wbase + m];
    int eD1 = sD[wbase + 16 + m];
    int eS0 = sS[wbase + m];
    int eS1 = sS[wbase + 16 + m];

    if constexpr (!EPRE) {
        int col = threadIdx.x & 31;
        int r0 = threadIdx.x >> 5;
        float w0 = Wep[col], w1 = Wep[32 + col], bb = bep[col];
#pragma unroll
        for (int i = 0; i < 16; ++i) {
            int em = r0 + 8 * i;
            int e = sE[tile0 + em];
            eL[em * 32 + col] = f2bf(spf(ea[2 * e] * w0 + ea[2 * e + 1] * w1 + bb));
        }
        __syncthreads();
    }

    f32x4 acc[2][8];
#pragma unroll
    for (int mf = 0; mf < 2; ++mf)
#pragma unroll
        for (int nf = 0; nf < 8; ++nf) acc[mf][nf] = (f32x4){0.f, 0.f, 0.f, 0.f};

    // ---- GEMM1: K = 160 (dst 64 | src 64 | e 32) ----
#pragma unroll
    for (int ks = 0; ks < 5; ++ks) {
        bf16x8 b0, b1;
        if (ks < 2) {
            b0 = *(const bf16x8*)(h_bf + (size_t)eD0 * 64 + ks * 32 + 8 * g);
            b1 = *(const bf16x8*)(h_bf + (size_t)eD1 * 64 + ks * 32 + 8 * g);
        } else if (ks < 4) {
            b0 = *(const bf16x8*)(h_bf + (size_t)eS0 * 64 + (ks - 2) * 32 + 8 * g);
            b1 = *(const bf16x8*)(h_bf + (size_t)eS1 * 64 + (ks - 2) * 32 + 8 * g);
        } else {
            if constexpr (EPRE) {
                b0 = *(const bf16x8*)(e_bf + (size_t)(wbase + m) * 32 + 8 * g);
                b1 = *(const bf16x8*)(e_bf + (size_t)(wbase + 16 + m) * 32 + 8 * g);
            } else {
                b0 = *(const bf16x8*)&eL[(32 * w + m) * 32 + 8 * g];
                b1 = *(const bf16x8*)&eL[(32 * w + 16 + m) * 32 + 8 * g];
            }
        }
#pragma unroll
        for (int nf = 0; nf < 8; ++nf) {
            bf16x8 a = *(const bf16x8*)(pA1 + ((ks * 8 + nf) * 64 + lane) * 8);
            acc[0][nf] = __builtin_amdgcn_mfma_f32_16x16x32_bf16(a, b0, acc[0][nf], 0, 0, 0);
            acc[1][nf] = __builtin_amdgcn_mfma_f32_16x16x32_bf16(a, b1, acc[1][nf], 0, 0, 0);
        }
    }

    // ---- epilogue 1: bias + fast softplus -> P (bf16) in LDS ----
#pragma unroll
    for (int nf = 0; nf < 8; ++nf) {
        f32x4 bb = *(const f32x4*)(be1 + 16 * nf + 4 * g);
#pragma unroll
        for (int mf = 0; mf < 2; ++mf) {
            f32x4 c = acc[mf][nf];
            unsigned int u01 = pkbf(spf(c[0] + bb[0]), spf(c[1] + bb[1]));
            unsigned int u23 = pkbf(spf(c[2] + bb[2]), spf(c[3] + bb[3]));
            unsigned int* dst = (unsigned int*)&P[w][m + 16 * mf][16 * nf + 4 * g];
            dst[0] = u01; dst[1] = u23;
        }
    }

    f32x4 acc2[2][8];
#pragma unroll
    for (int mf = 0; mf < 2; ++mf)
#pragma unroll
        for (int nf = 0; nf < 8; ++nf) acc2[mf][nf] = (f32x4){0.f, 0.f, 0.f, 0.f};

    // ---- GEMM2: K = 128, B = P^T from LDS (wave-private rows) ----
#pragma unroll
    for (int ks = 0; ks < 4; ++ks) {
        bf16x8 b0 = *(const bf16x8*)&P[w][m][32 * ks + 8 * g];
        bf16x8 b1 = *(const bf16x8*)&P[w][m + 16][32 * ks + 8 * g];
#pragma unroll
        for (int nf = 0; nf < 8; ++nf) {
            bf16x8 a = *(const bf16x8*)(pA2 + ((ks * 8 + nf) * 64 + lane) * 8);
            acc2[0][nf] = __builtin_amdgcn_mfma_f32_16x16x32_bf16(a, b0, acc2[0][nf], 0, 0, 0);
            acc2[1][nf] = __builtin_amdgcn_mfma_f32_16x16x32_bf16(a, b1, acc2[1][nf], 0, 0, 0);
        }
    }

    // ---- epilogue 2: stage bf16 m rows (full block) + dst table ----
    unsigned short (*Pf)[136] = (unsigned short(*)[136]) & P[0][0][0];
#pragma unroll
    for (int nf = 0; nf < 8; ++nf) {
        f32x4 bb = *(const f32x4*)(be2 + 16 * nf + 4 * g);
#pragma unroll
        for (int mf = 0; mf < 2; ++mf) {
            f32x4 c = acc2[mf][nf];
            unsigned int* dst = (unsigned int*)&Pf[32 * w + 16 * mf + m][16 * nf + 4 * g];
            dst[0] = pkbf(spf(c[0] + bb[0]), spf(c[1] + bb[1]));
            dst[1] = pkbf(spf(c[2] + bb[2]), spf(c[3] + bb[3]));
        }
    }
    if (g == 0) {
        dstB[32 * w + m] = eD0;
        dstB[32 * w + 16 + m] = eD1;
    }
    __syncthreads();

    // ---- block-wide run-length segmented reduction ----
    int rbeg = 32 * w, rend = rbeg + 32;
    int r = rbeg;
    if (w) {  // skip rows continuing a run that started in a lower wave
        while (r < rend && dstB[r] == dstB[r - 1]) ++r;
    }
    while (r < rend) {
        int d = dstB[r];
        float a0 = 0.f, a1 = 0.f;
        int rr = r;
        do {
            unsigned int u = *(const unsigned int*)&Pf[rr][2 * lane];
            a0 += lo_bf(u);
            a1 += hi_bf(u);
            ++rr;
        } while (rr < 128 && dstB[rr] == d);
        int s0 = rowptr[d];
        bool interior = (s0 >= tile0) && (s0 + hist[d] <= tile0 + 128);
        float* base = aggr + (size_t)d * HD + 2 * lane;
        if (interior) {
            base[0] = a0;
            base[1] = a1;
        } else {
            atomicAdd(base, a0);
            atomicAdd(base + 1, a1);
        }
        r = rr;
    }
}

// ---------------- MFMA node update: 1-wave blocks, 32 nodes each ---------
// 1563 blocks (vs 391) removes grid starvation; LDS 8.7KB/block.
__global__ __launch_bounds__(64, 3) void k_node_mfma(
    const unsigned short* __restrict__ h_bf, const float* __restrict__ aggr,
    const float* __restrict__ h,
    const unsigned short* __restrict__ pWn1, const float* __restrict__ bn1,
    const unsigned short* __restrict__ pWn2, const float* __restrict__ bn2,
    float* __restrict__ t, float* __restrict__ stats) {
    __shared__ unsigned short P[32][136];

    int lane = threadIdx.x;
    int m = lane & 15, g = lane >> 4;
    int wbase = blockIdx.x * 32;
    int n0 = wbase + m, n1 = wbase + 16 + m;
    bool v0 = n0 < N_NODES, v1 = n1 < N_NODES;
    int c0 = v0 ? n0 : N_NODES - 1;
    int c1 = v1 ? n1 : N_NODES - 1;

    f32x4 acc[2][8];
#pragma unroll
    for (int mf = 0; mf < 2; ++mf)
#pragma unroll
        for (int nf = 0; nf < 8; ++nf) acc[mf][nf] = (f32x4){0.f, 0.f, 0.f, 0.f};

    // ---- GEMM1: K = 192 (h 64 | aggr 128) ----
#pragma unroll
    for (int ks = 0; ks < 6; ++ks) {
        bf16x8 b0, b1;
        if (ks < 2) {
            b0 = *(const bf16x8*)(h_bf + (size_t)c0 * 64 + ks * 32 + 8 * g);
            b1 = *(const bf16x8*)(h_bf + (size_t)c1 * 64 + ks * 32 + 8 * g);
        } else {
            b0 = ld8_f32_bf(aggr + (size_t)c0 * 128 + (ks - 2) * 32 + 8 * g);
            b1 = ld8_f32_bf(aggr + (size_t)c1 * 128 + (ks - 2) * 32 + 8 * g);
        }
#pragma unroll
        for (int nf = 0; nf < 8; ++nf) {
            bf16x8 a = *(const bf16x8*)(pWn1 + ((ks * 8 + nf) * 64 + lane) * 8);
            acc[0][nf] = __builtin_amdgcn_mfma_f32_16x16x32_bf16(a, b0, acc[0][nf], 0, 0, 0);
            acc[1][nf] = __builtin_amdgcn_mfma_f32_16x16x32_bf16(a, b1, acc[1][nf], 0, 0, 0);
        }
    }

    // ---- epilogue 1: bias + fast softplus -> P (bf16) in LDS ----
#pragma unroll
    for (int nf = 0; nf < 8; ++nf) {
        f32x4 bb = *(const f32x4*)(bn1 + 16 * nf + 4 * g);
#pragma unroll
        for (int mf = 0; mf < 2; ++mf) {
            f32x4 c = acc[mf][nf];
            unsigned int u01 = pkbf(spf(c[0] + bb[0]), spf(c[1] + bb[1]));
            unsigned int u23 = pkbf(spf(c[2] + bb[2]), spf(c[3] + bb[3]));
            unsigned int* dst = (unsigned int*)&P[m + 16 * mf][16 * nf + 4 * g];
            dst[0] = u01; dst[1] = u23;
        }
    }

    f32x4 acc2[2][4];
#pragma unroll
    for (int mf = 0; mf < 2; ++mf)
#pragma unroll
        for (int nf = 0; nf < 4; ++nf) acc2[mf][nf] = (f32x4){0.f, 0.f, 0.f, 0.f};

    // ---- GEMM2: K = 128, N = 64 ----
#pragma unroll
    for (int ks = 0; ks < 4; ++ks) {
        bf16x8 b0 = *(const bf16x8*)&P[m][32 * ks + 8 * g];
        bf16x8 b1 = *(const bf16x8*)&P[m + 16][32 * ks + 8 * g];
#pragma unroll
        for (int nf = 0; nf < 4; ++nf) {
            bf16x8 a = *(const bf16x8*)(pWn2 + ((ks * 4 + nf) * 64 + lane) * 8);
            acc2[0][nf] = __builtin_amdgcn_mfma_f32_16x16x32_bf16(a, b0, acc2[0][nf], 0, 0, 0);
            acc2[1][nf] = __builtin_amdgcn_mfma_f32_16x16x32_bf16(a, b1, acc2[1][nf], 0, 0, 0);
        }
    }

    // ---- epilogue 2: +bn2 +h residual -> t; BN stats ----
#pragma unroll
    for (int nf = 0; nf < 4; ++nf) {
        f32x4 bb = *(const f32x4*)(bn2 + 16 * nf + 4 * g);
        f32x4 s0v = (f32x4){0.f, 0.f, 0.f, 0.f};
        f32x4 s1v = (f32x4){0.f, 0.f, 0.f, 0.f};
#pragma unroll
        for (int mf = 0; mf < 2; ++mf) {
            int cn = mf ? c1 : c0;
            bool vn = mf ? v1 : v0;
            f32x4 hv = *(const f32x4*)(h + (size_t)cn * 64 + 16 * nf + 4 * g);
            f32x4 c = acc2[mf][nf];
            f32x4 tn;
#pragma unroll
            for (int j = 0; j < 4; ++j) tn[j] = c[j] + bb[j] + hv[j];
            if (vn) *(f32x4*)(t + (size_t)cn * 64 + 16 * nf + 4 * g) = tn;
#pragma unroll
            for (int j = 0; j < 4; ++j) {
                float tv = vn ? tn[j] : 0.f;
                s0v[j] += tv;
                s1v[j] += tv * tv;
            }
        }
#pragma unroll
        for (int j = 0; j < 4; ++j) {
#pragma unroll
            for (int k = 1; k <= 8; k <<= 1) {
                s0v[j] += __shfl_xor(s0v[j], k);
                s1v[j] += __shfl_xor(s1v[j], k);
            }
        }
        if (m == 0) {
#pragma unroll
            for (int j = 0; j < 4; ++j) {
                atomicAdd(&stats[16 * nf + 4 * g + j], s0v[j]);
                atomicAdd(&stats[ND + 16 * nf + 4 * g + j], s1v[j]);
            }
        }
    }
}

// ---------------- pooling + readout (unchanged) -------------------------
__global__ __launch_bounds__(256) void k_pool(
    const float* __restrict__ h, const int* __restrict__ batch,
    float* __restrict__ pooled, float* __restrict__ cnt) {
    int lane = threadIdx.x & 63;
    int wave = (blockIdx.x * blockDim.x + threadIdx.x) >> 6;
    int nw = (gridDim.x * blockDim.x) >> 6;
    int chunk = (N_NODES + nw - 1) / nw;
    int s = wave * chunk;
    int epos = min(N_NODES, s + chunk);
    if (s >= N_NODES) return;
    int curg = batch[s];
    float acc = 0.f, c = 0.f;
    for (int i = s; i < epos; ++i) {
        int g = batch[i];
        if (g != curg) {
            atomicAdd(&pooled[curg * ND + lane], acc);
            if (lane == 0) atomicAdd(&cnt[curg], c);
            acc = 0.f; c = 0.f; curg = g;
        }
        acc += h[i * ND + lane];
        c += 1.f;
    }
    atomicAdd(&pooled[curg * ND + lane], acc);
    if (lane == 0) atomicAdd(&cnt[curg], c);
}

__global__ __launch_bounds__(256) void k_readout(
    const float* __restrict__ pooled, const float* __restrict__ cnt,
    const float* __restrict__ Wo1, const float* __restrict__ bo1,
    const float* __restrict__ Wo2, const float* __restrict__ bo2,
    float* __restrict__ out) {
    __shared__ float pbuf[WPB][ND];
    int lane = threadIdx.x & 63;
    int wid = threadIdx.x >> 6;
    int g = blockIdx.x * WPB + wid;
    bool valid = g < N_GRAPH;
    int gc = valid ? g : N_GRAPH - 1;
    float c = fmaxf(cnt[gc], 1.f);
    pbuf[wid][lane] = pooled[gc * ND + lane] / c;
    __syncthreads();
    float h0 = bo1[lane], h1 = bo1[64 + lane];
#pragma unroll 8
    for (int k = 0; k < ND; ++k) {
        float pk = pbuf[wid][k];
        h0 += pk * Wo1[k * HD + lane];
        h1 += pk * Wo1[k * HD + 64 + lane];
    }
    float s = sp(h0) * Wo2[lane] + sp(h1) * Wo2[64 + lane];
#pragma unroll
    for (int off = 32; off; off >>= 1) s += __shfl_down(s, off);
    if (valid && lane == 0) out[g] = s + bo2[0];
}

extern "C" void kernel_launch(void* const* d_in, const int* in_sizes, int n_in,
                              void* d_out, int out_size, void* d_ws, size_t ws_size,
                              hipStream_t stream) {
    const float* x       = (const float*)d_in[0];
    const float* ea      = (const float*)d_in[1];
    const int*   ei      = (const int*)d_in[2];
    const int*   batch   = (const int*)d_in[3];
    const float* Wnp     = (const float*)d_in[4];
    const float* bnp     = (const float*)d_in[5];
    const float* g_np    = (const float*)d_in[6];
    const float* be_np   = (const float*)d_in[7];
    const float* Wep     = (const float*)d_in[8];
    const float* bep     = (const float*)d_in[9];
    const float* We1     = (const float*)d_in[10];
    const float* be1     = (const float*)d_in[11];
    const float* We2     = (const float*)d_in[12];
    const float* be2     = (const float*)d_in[13];
    const float* Wn1     = (const float*)d_in[14];
    const float* bn1     = (const float*)d_in[15];
    const float* Wn2     = (const float*)d_in[16];
    const float* bn2     = (const float*)d_in[17];
    const float* g_bn    = (const float*)d_in[18];
    const float* b_bn    = (const float*)d_in[19];
    const float* Wo1     = (const float*)d_in[20];
    const float* bo1     = (const float*)d_in[21];
    const float* Wo2     = (const float*)d_in[22];
    const float* bo2     = (const float*)d_in[23];

    float* ws = (float*)d_ws;
    size_t off = 0;
    float* h      = ws + off; off += (size_t)N_NODES * ND;
    float* t      = ws + off; off += (size_t)N_NODES * ND;
    float* aggr   = ws + off; off += (size_t)N_NODES * HD;
    float* stats  = ws + off; off += 2 * ND;
    float* ss     = ws + off; off += 2 * ND;
    float* pooled = ws + off; off += N_GRAPH * ND;
    float* cnt    = ws + off; off += 512;
    unsigned short* h_bf = (unsigned short*)(ws + off); off += (size_t)N_NODES * ND / 2;
    unsigned short* pA1  = (unsigned short*)(ws + off); off += 3 * 5 * 8 * 64 * 8 / 2;
    unsigned short* pA2  = (unsigned short*)(ws + off); off += 3 * 4 * 8 * 64 * 8 / 2;
    unsigned short* pWn1 = (unsigned short*)(ws + off); off += 3 * 6 * 8 * 64 * 8 / 2;
    unsigned short* pWn2 = (unsigned short*)(ws + off); off += 3 * 4 * 4 * 64 * 8 / 2;
    int* sD       = (int*)(ws + off); off += N_EDGES;
    int* sS       = (int*)(ws + off); off += N_EDGES;
    int* sE       = (int*)(ws + off); off += N_EDGES;
    int* hist     = (int*)(ws + off); off += N_NODES;
    int* cursor   = (int*)(ws + off); off += N_NODES;
    int* rowptr   = (int*)(ws + off); off += N_NODES;
    int* chunksum = (int*)(ws + off); off += 64;
    size_t base_bytes = off * sizeof(float);
    unsigned short* e_bf = (unsigned short*)(ws + off);
    bool epre = (ws_size >= base_bytes + (size_t)N_EDGES * 32 * 2);

    float* outp = (float*)d_out;

    const int NCH = (N_NODES + 1023) / 1024;  // 49

    // ---- counting sort of edges by dst -> CSR (once per call) ----
    hipMemsetAsync(hist, 0, N_NODES * sizeof(int), stream);
    k_hist<<<(N_EDGES + 255) / 256, 256, 0, stream>>>(ei, hist);
    k_scan1<<<NCH, 1024, 0, stream>>>(hist, chunksum);
    k_scan2<<<1, 64, 0, stream>>>(chunksum, NCH);
    k_scan3<<<NCH, 1024, 0, stream>>>(hist, chunksum, cursor, rowptr);
    k_scatter<<<(N_EDGES + 255) / 256, 256, 0, stream>>>(ei, cursor, sD, sS, sE);
    if (epre)
        k_eproj_sorted<<<(int)(((long)N_EDGES * 32 + 255) / 256), 256, 0, stream>>>(
            ea, sE, Wep, bep, e_bf);

    // ---- pack all weights (3 layers x 4 matrices) in one launch ----
    k_pack_all<<<(3 * 8704 + 255) / 256, 256, 0, stream>>>(
        We1, We2, Wn1, Wn2, pA1, pA2, pWn1, pWn2);

    // ---- node projection + BN ----
    hipMemsetAsync(stats, 0, 2 * ND * sizeof(float), stream);
    k_node_proj<<<512, 256, 0, stream>>>(x, Wnp, bnp, t, stats);
    k_bn_finalize<<<1, 64, 0, stream>>>(stats, g_np, be_np, ss);
    k_bn_apply<<<2048, 256, 0, stream>>>(t, ss, h, h_bf);

    for (int l = 0; l < 3; ++l) {
        hipMemsetAsync(aggr, 0, (size_t)N_NODES * HD * sizeof(float), stream);
        if (epre)
            k_edge_mfma_s<true><<<N_EDGES / 128, 256, 0, stream>>>(
                h_bf, e_bf, ea, sE, Wep, bep, sD, sS, rowptr, hist,
                pA1 + (size_t)l * 40 * 64 * 8, be1 + l * HD,
                pA2 + (size_t)l * 32 * 64 * 8, be2 + l * HD, aggr);
        else
            k_edge_mfma_s<false><<<N_EDGES / 128, 256, 0, stream>>>(
                h_bf, e_bf, ea, sE, Wep, bep, sD, sS, rowptr, hist,
                pA1 + (size_t)l * 40 * 64 * 8, be1 + l * HD,
                pA2 + (size_t)l * 32 * 64 * 8, be2 + l * HD, aggr);

        hipMemsetAsync(stats, 0, 2 * ND * sizeof(float), stream);
        k_node_mfma<<<(N_NODES + 31) / 32, 64, 0, stream>>>(
            h_bf, aggr, h,
            pWn1 + (size_t)l * 48 * 64 * 8, bn1 + l * HD,
            pWn2 + (size_t)l * 16 * 64 * 8, bn2 + l * ND, t, stats);
        k_bn_finalize<<<1, 64, 0, stream>>>(stats, g_bn + l * ND, b_bn + l * ND, ss);
        k_bn_apply<<<2048, 256, 0, stream>>>(t, ss, h, h_bf);
    }

    hipMemsetAsync(pooled, 0, (size_t)(N_GRAPH * ND + 512) * sizeof(float), stream);
    k_pool<<<512, 256, 0, stream>>>(h, batch, pooled, cnt);
    k_readout<<<(N_GRAPH + WPB - 1) / WPB, 256, 0, stream>>>(
        pooled, cnt, Wo1, bo1, Wo2, bo2, outp);
}

// Round 18
// 1296.730 us; speedup vs baseline: 6.0382x; 1.1990x over previous
//
#include <hip/hip_runtime.h>
#include <hip/hip_bf16.h>

#define N_NODES 50000
#define N_EDGES 800000
#define N_GRAPH 500
#define ND 64
#define ED 32
#define HD 128
#define WPB 4   // waves per block (256 threads)
#define NBU ((N_NODES + 31) / 32)   // 1563 one-wave node blocks

typedef __attribute__((ext_vector_type(8))) short bf16x8;
typedef __attribute__((ext_vector_type(4))) float f32x4;

__device__ __forceinline__ float sp(float x) {
    return fmaxf(x, 0.f) + log1pf(expf(-fabsf(x)));
}

// fast softplus for the bf16 path (v_exp_f32/v_log_f32 based)
__device__ __forceinline__ float spf(float x) {
    return fmaxf(x, 0.f) + __logf(1.f + __expf(-fabsf(x)));
}

__device__ __forceinline__ unsigned short f2bf(float v) {
    __hip_bfloat16 b = __float2bfloat16(v);
    return *(unsigned short*)&b;
}

__device__ __forceinline__ unsigned int pkbf(float a, float b) {
    return (unsigned int)f2bf(a) | ((unsigned int)f2bf(b) << 16);
}

__device__ __forceinline__ float lo_bf(unsigned int u) { return __uint_as_float(u << 16); }
__device__ __forceinline__ float hi_bf(unsigned int u) { return __uint_as_float(u & 0xffff0000u); }

// load 8 fp32 and round to bf16x8 (same RNE as k_bn_apply/f2bf)
__device__ __forceinline__ bf16x8 ld8_f32_bf(const float* p) {
    f32x4 v0 = *(const f32x4*)p;
    f32x4 v1 = *(const f32x4*)(p + 4);
    bf16x8 r;
    r[0] = (short)f2bf(v0[0]); r[1] = (short)f2bf(v0[1]);
    r[2] = (short)f2bf(v0[2]); r[3] = (short)f2bf(v0[3]);
    r[4] = (short)f2bf(v1[0]); r[5] = (short)f2bf(v1[1]);
    r[6] = (short)f2bf(v1[2]); r[7] = (short)f2bf(v1[3]);
    return r;
}

// ---------------- node projection: partial BN stats per block -----------
__global__ __launch_bounds__(256) void k_node_proj(
    const float* __restrict__ x, const float* __restrict__ Wnp,
    const float* __restrict__ bnp, float* __restrict__ t,
    float* __restrict__ partN) {
    __shared__ float red0[4][64], red1[4][64];
    int lane = threadIdx.x & 63;
    int wid = threadIdx.x >> 6;
    int wave = (blockIdx.x * blockDim.x + threadIdx.x) >> 6;
    int nw = (gridDim.x * blockDim.x) >> 6;
    float w[13];
#pragma unroll
    for (int k = 0; k < 13; ++k) w[k] = Wnp[k * ND + lane];
    float bb = bnp[lane];
    float s0 = 0.f, s1 = 0.f;
    for (int i = wave; i < N_NODES; i += nw) {
        float acc = bb;
#pragma unroll
        for (int k = 0; k < 13; ++k) acc += x[i * 13 + k] * w[k];
        float v = sp(acc);
        t[i * ND + lane] = v;
        s0 += v; s1 += v * v;
    }
    red0[wid][lane] = s0;
    red1[wid][lane] = s1;
    __syncthreads();
    int tid = threadIdx.x;
    if (tid < 64)
        partN[blockIdx.x * 128 + tid] =
            red0[0][tid] + red0[1][tid] + red0[2][tid] + red0[3][tid];
    else if (tid < 128) {
        int c = tid - 64;
        partN[blockIdx.x * 128 + tid] =
            red1[0][c] + red1[1][c] + red1[2][c] + red1[3][c];
    }
}

// ---- two-stage BN stats: sum R partial rows, emit scale/shift ----------
__global__ void k_stats_reduce(const float* __restrict__ part, int R,
                               const float* __restrict__ g,
                               const float* __restrict__ b,
                               float* __restrict__ ss) {
    __shared__ float r0[4][64], r1[4][64];
    int q = threadIdx.x >> 6, c = threadIdx.x & 63;
    float S0 = 0.f, S1 = 0.f;
    for (int r = q; r < R; r += 4) {
        S0 += part[(size_t)r * 128 + c];
        S1 += part[(size_t)r * 128 + 64 + c];
    }
    r0[q][c] = S0; r1[q][c] = S1;
    __syncthreads();
    if (threadIdx.x < 64) {
        float s0 = r0[0][c] + r0[1][c] + r0[2][c] + r0[3][c];
        float s1 = r1[0][c] + r1[1][c] + r1[2][c] + r1[3][c];
        float inv_n = 1.f / (float)N_NODES;
        float mu = s0 * inv_n;
        float var = s1 * inv_n - mu * mu;
        float rs = rsqrtf(var + 1e-5f);
        float sc = rs * g[c];
        ss[c] = sc;
        ss[64 + c] = b[c] - mu * sc;
    }
}

__global__ __launch_bounds__(256) void k_bn_apply(
    const float* __restrict__ t, const float* __restrict__ ss,
    float* __restrict__ h, unsigned short* __restrict__ hb) {
    int idx = blockIdx.x * blockDim.x + threadIdx.x;
    int tot = N_NODES * ND;
    int stride = gridDim.x * blockDim.x;
    for (; idx < tot; idx += stride) {
        int c = idx & (ND - 1);
        float v = t[idx] * ss[c] + ss[ND + c];
        h[idx] = v;
        hb[idx] = f2bf(v);
    }
}

// ---------------- counting sort of edges by dst -------------------------
__global__ __launch_bounds__(256) void k_hist(const int* __restrict__ ei,
                                              int* __restrict__ hist) {
    int e = blockIdx.x * 256 + threadIdx.x;
    if (e < N_EDGES) atomicAdd(&hist[ei[N_EDGES + e]], 1);
}

__global__ __launch_bounds__(1024) void k_scan1(const int* __restrict__ hist,
                                                int* __restrict__ chunksum) {
    __shared__ int s[1024];
    int t = threadIdx.x;
    int i = blockIdx.x * 1024 + t;
    s[t] = (i < N_NODES) ? hist[i] : 0;
    __syncthreads();
    for (int off = 512; off; off >>= 1) {
        if (t < off) s[t] += s[t + off];
        __syncthreads();
    }
    if (t == 0) chunksum[blockIdx.x] = s[0];
}

__global__ void k_scan2(int* __restrict__ chunksum, int n) {
    if (threadIdx.x == 0) {
        int acc = 0;
        for (int i = 0; i < n; ++i) { int v = chunksum[i]; chunksum[i] = acc; acc += v; }
    }
}

__global__ __launch_bounds__(1024) void k_scan3(const int* __restrict__ hist,
                                                const int* __restrict__ chunksum,
                                                int* __restrict__ cursor,
                                                int* __restrict__ rowptr) {
    __shared__ int s[1024];
    int t = threadIdx.x;
    int i = blockIdx.x * 1024 + t;
    int v = (i < N_NODES) ? hist[i] : 0;
    s[t] = v;
    __syncthreads();
    for (int off = 1; off < 1024; off <<= 1) {
        int u = (t >= off) ? s[t - off] : 0;
        __syncthreads();
        s[t] += u;
        __syncthreads();
    }
    if (i < N_NODES) {
        int ex = chunksum[blockIdx.x] + s[t] - v;  // exclusive
        cursor[i] = ex;
        rowptr[i] = ex;
    }
}

__global__ __launch_bounds__(256) void k_scatter(const int* __restrict__ ei,
                                                 int* __restrict__ cursor,
                                                 int* __restrict__ sD,
                                                 int* __restrict__ sS,
                                                 int* __restrict__ sE) {
    int e = blockIdx.x * 256 + threadIdx.x;
    if (e >= N_EDGES) return;
    int d = ei[N_EDGES + e];
    int pos = atomicAdd(&cursor[d], 1);
    sD[pos] = d;
    sS[pos] = ei[e];
    sE[pos] = e;
}

// edge projection into sorted order (layer-invariant, once per call)
__global__ __launch_bounds__(256) void k_eproj_sorted(
    const float* __restrict__ ea, const int* __restrict__ sE,
    const float* __restrict__ Wep, const float* __restrict__ bep,
    unsigned short* __restrict__ e_bf) {
    long idx = (long)blockIdx.x * blockDim.x + threadIdx.x;
    long tot = (long)N_EDGES * 32;
    if (idx >= tot) return;
    int p = (int)(idx >> 5), col = (int)(idx & 31);
    int e = sE[p];
    float v = spf(ea[2 * e] * Wep[col] + ea[2 * e + 1] * Wep[32 + col] + bep[col]);
    e_bf[idx] = f2bf(v);
}

// ---- fused weight pack: all 3 layers x {We1,We2,Wn1,Wn2} in ONE launch --
__global__ __launch_bounds__(256) void k_pack_all(
    const float* __restrict__ We1, const float* __restrict__ We2,
    const float* __restrict__ Wn1, const float* __restrict__ Wn2,
    unsigned short* __restrict__ pA1, unsigned short* __restrict__ pA2,
    unsigned short* __restrict__ pWn1, unsigned short* __restrict__ pWn2) {
    int tid = blockIdx.x * 256 + threadIdx.x;
    const int PER_L = (40 + 32 + 48 + 16) * 64;  // 8704
    if (tid >= 3 * PER_L) return;
    int layer = tid / PER_L;
    int r = tid % PER_L;
    const float* W;
    unsigned short* out;
    int ncols, lt;
    if (r < 40 * 64) {
        lt = r; W = We1 + (size_t)layer * 160 * 128; out = pA1 + (size_t)layer * 40 * 64 * 8;
        ncols = 128;
    } else if (r < 72 * 64) {
        lt = r - 40 * 64; W = We2 + (size_t)layer * 128 * 128; out = pA2 + (size_t)layer * 32 * 64 * 8;
        ncols = 128;
    } else if (r < 120 * 64) {
        lt = r - 72 * 64; W = Wn1 + (size_t)layer * 192 * 128; out = pWn1 + (size_t)layer * 48 * 64 * 8;
        ncols = 128;
    } else {
        lt = r - 120 * 64; W = Wn2 + (size_t)layer * 128 * 64; out = pWn2 + (size_t)layer * 16 * 64 * 8;
        ncols = 64;
    }
    int nfrag = ncols >> 4;
    int l = lt & 63; int fr = lt >> 6; int nf = fr % nfrag; int ks = fr / nfrag;
    int n = 16 * nf + (l & 15);
    int k0 = 32 * ks + 8 * (l >> 4);
#pragma unroll
    for (int rr = 0; rr < 8; ++rr)
        out[lt * 8 + rr] = f2bf(W[(k0 + rr) * ncols + n]);
}

// ---------------- MFMA edge conv on dst-sorted edges (unchanged) --------
template <bool EPRE>
__global__ __launch_bounds__(256, 3) void k_edge_mfma_s(
    const unsigned short* __restrict__ h_bf, const unsigned short* __restrict__ e_bf,
    const float* __restrict__ ea, const int* __restrict__ sE,
    const float* __restrict__ Wep, const float* __restrict__ bep,
    const int* __restrict__ sD, const int* __restrict__ sS,
    const int* __restrict__ rowptr, const int* __restrict__ hist,
    const unsigned short* __restrict__ pA1, const float* __restrict__ be1,
    const unsigned short* __restrict__ pA2, const float* __restrict__ be2,
    float* __restrict__ aggr) {
    __shared__ unsigned short P[WPB][32][136];   // per-wave P; reused as 128-row stage
    __shared__ int dstB[128];
    __shared__ unsigned short eL[EPRE ? 64 : 128 * 32];

    int lane = threadIdx.x & 63;
    int w = threadIdx.x >> 6;
    int m = lane & 15, g = lane >> 4;
    int tile0 = blockIdx.x * 128;
    int wbase = tile0 + 32 * w;

    int eD0 = sD[wbase + m];
    int eD1 = sD[wbase + 16 + m];
    int eS0 = sS[wbase + m];
    int eS1 = sS[wbase + 16 + m];

    if constexpr (!EPRE) {
        int col = threadIdx.x & 31;
        int r0 = threadIdx.x >> 5;
        float w0 = Wep[col], w1 = Wep[32 + col], bb = bep[col];
#pragma unroll
        for (int i = 0; i < 16; ++i) {
            int em = r0 + 8 * i;
            int e = sE[tile0 + em];
            eL[em * 32 + col] = f2bf(spf(ea[2 * e] * w0 + ea[2 * e + 1] * w1 + bb));
        }
        __syncthreads();
    }

    f32x4 acc[2][8];
#pragma unroll
    for (int mf = 0; mf < 2; ++mf)
#pragma unroll
        for (int nf = 0; nf < 8; ++nf) acc[mf][nf] = (f32x4){0.f, 0.f, 0.f, 0.f};

    // ---- GEMM1: K = 160 (dst 64 | src 64 | e 32) ----
#pragma unroll
    for (int ks = 0; ks < 5; ++ks) {
        bf16x8 b0, b1;
        if (ks < 2) {
            b0 = *(const bf16x8*)(h_bf + (size_t)eD0 * 64 + ks * 32 + 8 * g);
            b1 = *(const bf16x8*)(h_bf + (size_t)eD1 * 64 + ks * 32 + 8 * g);
        } else if (ks < 4) {
            b0 = *(const bf16x8*)(h_bf + (size_t)eS0 * 64 + (ks - 2) * 32 + 8 * g);
            b1 = *(const bf16x8*)(h_bf + (size_t)eS1 * 64 + (ks - 2) * 32 + 8 * g);
        } else {
            if constexpr (EPRE) {
                b0 = *(const bf16x8*)(e_bf + (size_t)(wbase + m) * 32 + 8 * g);
                b1 = *(const bf16x8*)(e_bf + (size_t)(wbase + 16 + m) * 32 + 8 * g);
            } else {
                b0 = *(const bf16x8*)&eL[(32 * w + m) * 32 + 8 * g];
                b1 = *(const bf16x8*)&eL[(32 * w + 16 + m) * 32 + 8 * g];
            }
        }
#pragma unroll
        for (int nf = 0; nf < 8; ++nf) {
            bf16x8 a = *(const bf16x8*)(pA1 + ((ks * 8 + nf) * 64 + lane) * 8);
            acc[0][nf] = __builtin_amdgcn_mfma_f32_16x16x32_bf16(a, b0, acc[0][nf], 0, 0, 0);
            acc[1][nf] = __builtin_amdgcn_mfma_f32_16x16x32_bf16(a, b1, acc[1][nf], 0, 0, 0);
        }
    }

    // ---- epilogue 1: bias + fast softplus -> P (bf16) in LDS ----
#pragma unroll
    for (int nf = 0; nf < 8; ++nf) {
        f32x4 bb = *(const f32x4*)(be1 + 16 * nf + 4 * g);
#pragma unroll
        for (int mf = 0; mf < 2; ++mf) {
            f32x4 c = acc[mf][nf];
            unsigned int u01 = pkbf(spf(c[0] + bb[0]), spf(c[1] + bb[1]));
            unsigned int u23 = pkbf(spf(c[2] + bb[2]), spf(c[3] + bb[3]));
            unsigned int* dst = (unsigned int*)&P[w][m + 16 * mf][16 * nf + 4 * g];
            dst[0] = u01; dst[1] = u23;
        }
    }

    f32x4 acc2[2][8];
#pragma unroll
    for (int mf = 0; mf < 2; ++mf)
#pragma unroll
        for (int nf = 0; nf < 8; ++nf) acc2[mf][nf] = (f32x4){0.f, 0.f, 0.f, 0.f};

    // ---- GEMM2: K = 128, B = P^T from LDS (wave-private rows) ----
#pragma unroll
    for (int ks = 0; ks < 4; ++ks) {
        bf16x8 b0 = *(const bf16x8*)&P[w][m][32 * ks + 8 * g];
        bf16x8 b1 = *(const bf16x8*)&P[w][m + 16][32 * ks + 8 * g];
#pragma unroll
        for (int nf = 0; nf < 8; ++nf) {
            bf16x8 a = *(const bf16x8*)(pA2 + ((ks * 8 + nf) * 64 + lane) * 8);
            acc2[0][nf] = __builtin_amdgcn_mfma_f32_16x16x32_bf16(a, b0, acc2[0][nf], 0, 0, 0);
            acc2[1][nf] = __builtin_amdgcn_mfma_f32_16x16x32_bf16(a, b1, acc2[1][nf], 0, 0, 0);
        }
    }

    // ---- epilogue 2: stage bf16 m rows (full block) + dst table ----
    unsigned short (*Pf)[136] = (unsigned short(*)[136]) & P[0][0][0];
#pragma unroll
    for (int nf = 0; nf < 8; ++nf) {
        f32x4 bb = *(const f32x4*)(be2 + 16 * nf + 4 * g);
#pragma unroll
        for (int mf = 0; mf < 2; ++mf) {
            f32x4 c = acc2[mf][nf];
            unsigned int* dst = (unsigned int*)&Pf[32 * w + 16 * mf + m][16 * nf + 4 * g];
            dst[0] = pkbf(spf(c[0] + bb[0]), spf(c[1] + bb[1]));
            dst[1] = pkbf(spf(c[2] + bb[2]), spf(c[3] + bb[3]));
        }
    }
    if (g == 0) {
        dstB[32 * w + m] = eD0;
        dstB[32 * w + 16 + m] = eD1;
    }
    __syncthreads();

    // ---- block-wide run-length segmented reduction ----
    int rbeg = 32 * w, rend = rbeg + 32;
    int r = rbeg;
    if (w) {  // skip rows continuing a run that started in a lower wave
        while (r < rend && dstB[r] == dstB[r - 1]) ++r;
    }
    while (r < rend) {
        int d = dstB[r];
        float a0 = 0.f, a1 = 0.f;
        int rr = r;
        do {
            unsigned int u = *(const unsigned int*)&Pf[rr][2 * lane];
            a0 += lo_bf(u);
            a1 += hi_bf(u);
            ++rr;
        } while (rr < 128 && dstB[rr] == d);
        int s0 = rowptr[d];
        bool interior = (s0 >= tile0) && (s0 + hist[d] <= tile0 + 128);
        float* base = aggr + (size_t)d * HD + 2 * lane;
        if (interior) {
            base[0] = a0;
            base[1] = a1;
        } else {
            atomicAdd(base, a0);
            atomicAdd(base + 1, a1);
        }
        r = rr;
    }
}

// ---------------- MFMA node update: 1-wave blocks, partial BN stats -----
__global__ __launch_bounds__(64, 3) void k_node_mfma(
    const unsigned short* __restrict__ h_bf, const float* __restrict__ aggr,
    const float* __restrict__ h,
    const unsigned short* __restrict__ pWn1, const float* __restrict__ bn1,
    const unsigned short* __restrict__ pWn2, const float* __restrict__ bn2,
    float* __restrict__ t, float* __restrict__ partU) {
    __shared__ unsigned short P[32][136];

    int lane = threadIdx.x;
    int m = lane & 15, g = lane >> 4;
    int wbase = blockIdx.x * 32;
    int n0 = wbase + m, n1 = wbase + 16 + m;
    bool v0 = n0 < N_NODES, v1 = n1 < N_NODES;
    int c0 = v0 ? n0 : N_NODES - 1;
    int c1 = v1 ? n1 : N_NODES - 1;

    f32x4 acc[2][8];
#pragma unroll
    for (int mf = 0; mf < 2; ++mf)
#pragma unroll
        for (int nf = 0; nf < 8; ++nf) acc[mf][nf] = (f32x4){0.f, 0.f, 0.f, 0.f};

    // ---- GEMM1: K = 192 (h 64 | aggr 128) ----
#pragma unroll
    for (int ks = 0; ks < 6; ++ks) {
        bf16x8 b0, b1;
        if (ks < 2) {
            b0 = *(const bf16x8*)(h_bf + (size_t)c0 * 64 + ks * 32 + 8 * g);
            b1 = *(const bf16x8*)(h_bf + (size_t)c1 * 64 + ks * 32 + 8 * g);
        } else {
            b0 = ld8_f32_bf(aggr + (size_t)c0 * 128 + (ks - 2) * 32 + 8 * g);
            b1 = ld8_f32_bf(aggr + (size_t)c1 * 128 + (ks - 2) * 32 + 8 * g);
        }
#pragma unroll
        for (int nf = 0; nf < 8; ++nf) {
            bf16x8 a = *(const bf16x8*)(pWn1 + ((ks * 8 + nf) * 64 + lane) * 8);
            acc[0][nf] = __builtin_amdgcn_mfma_f32_16x16x32_bf16(a, b0, acc[0][nf], 0, 0, 0);
            acc[1][nf] = __builtin_amdgcn_mfma_f32_16x16x32_bf16(a, b1, acc[1][nf], 0, 0, 0);
        }
    }

    // ---- epilogue 1: bias + fast softplus -> P (bf16) in LDS ----
#pragma unroll
    for (int nf = 0; nf < 8; ++nf) {
        f32x4 bb = *(const f32x4*)(bn1 + 16 * nf + 4 * g);
#pragma unroll
        for (int mf = 0; mf < 2; ++mf) {
            f32x4 c = acc[mf][nf];
            unsigned int u01 = pkbf(spf(c[0] + bb[0]), spf(c[1] + bb[1]));
            unsigned int u23 = pkbf(spf(c[2] + bb[2]), spf(c[3] + bb[3]));
            unsigned int* dst = (unsigned int*)&P[m + 16 * mf][16 * nf + 4 * g];
            dst[0] = u01; dst[1] = u23;
        }
    }

    f32x4 acc2[2][4];
#pragma unroll
    for (int mf = 0; mf < 2; ++mf)
#pragma unroll
        for (int nf = 0; nf < 4; ++nf) acc2[mf][nf] = (f32x4){0.f, 0.f, 0.f, 0.f};

    // ---- GEMM2: K = 128, N = 64 ----
#pragma unroll
    for (int ks = 0; ks < 4; ++ks) {
        bf16x8 b0 = *(const bf16x8*)&P[m][32 * ks + 8 * g];
        bf16x8 b1 = *(const bf16x8*)&P[m + 16][32 * ks + 8 * g];
#pragma unroll
        for (int nf = 0; nf < 4; ++nf) {
            bf16x8 a = *(const bf16x8*)(pWn2 + ((ks * 4 + nf) * 64 + lane) * 8);
            acc2[0][nf] = __builtin_amdgcn_mfma_f32_16x16x32_bf16(a, b0, acc2[0][nf], 0, 0, 0);
            acc2[1][nf] = __builtin_amdgcn_mfma_f32_16x16x32_bf16(a, b1, acc2[1][nf], 0, 0, 0);
        }
    }

    // ---- epilogue 2: +bn2 +h residual -> t; partial BN stats (no atomics)
#pragma unroll
    for (int nf = 0; nf < 4; ++nf) {
        f32x4 bb = *(const f32x4*)(bn2 + 16 * nf + 4 * g);
        f32x4 s0v = (f32x4){0.f, 0.f, 0.f, 0.f};
        f32x4 s1v = (f32x4){0.f, 0.f, 0.f, 0.f};
#pragma unroll
        for (int mf = 0; mf < 2; ++mf) {
            int cn = mf ? c1 : c0;
            bool vn = mf ? v1 : v0;
            f32x4 hv = *(const f32x4*)(h + (size_t)cn * 64 + 16 * nf + 4 * g);
            f32x4 c = acc2[mf][nf];
            f32x4 tn;
#pragma unroll
            for (int j = 0; j < 4; ++j) tn[j] = c[j] + bb[j] + hv[j];
            if (vn) *(f32x4*)(t + (size_t)cn * 64 + 16 * nf + 4 * g) = tn;
#pragma unroll
            for (int j = 0; j < 4; ++j) {
                float tv = vn ? tn[j] : 0.f;
                s0v[j] += tv;
                s1v[j] += tv * tv;
            }
        }
#pragma unroll
        for (int j = 0; j < 4; ++j) {
#pragma unroll
            for (int k = 1; k <= 8; k <<= 1) {
                s0v[j] += __shfl_xor(s0v[j], k);
                s1v[j] += __shfl_xor(s1v[j], k);
            }
        }
        if (m == 0) {
#pragma unroll
            for (int j = 0; j < 4; ++j) {
                int ch = 16 * nf + 4 * g + j;
                partU[(size_t)blockIdx.x * 128 + ch] = s0v[j];
                partU[(size_t)blockIdx.x * 128 + 64 + ch] = s1v[j];
            }
        }
    }
}

// ---------------- pooling + readout (unchanged) -------------------------
__global__ __launch_bounds__(256) void k_pool(
    const float* __restrict__ h, const int* __restrict__ batch,
    float* __restrict__ pooled, float* __restrict__ cnt) {
    int lane = threadIdx.x & 63;
    int wave = (blockIdx.x * blockDim.x + threadIdx.x) >> 6;
    int nw = (gridDim.x * blockDim.x) >> 6;
    int chunk = (N_NODES + nw - 1) / nw;
    int s = wave * chunk;
    int epos = min(N_NODES, s + chunk);
    if (s >= N_NODES) return;
    int curg = batch[s];
    float acc = 0.f, c = 0.f;
    for (int i = s; i < epos; ++i) {
        int g = batch[i];
        if (g != curg) {
            atomicAdd(&pooled[curg * ND + lane], acc);
            if (lane == 0) atomicAdd(&cnt[curg], c);
            acc = 0.f; c = 0.f; curg = g;
        }
        acc += h[i * ND + lane];
        c += 1.f;
    }
    atomicAdd(&pooled[curg * ND + lane], acc);
    if (lane == 0) atomicAdd(&cnt[curg], c);
}

__global__ __launch_bounds__(256) void k_readout(
    const float* __restrict__ pooled, const float* __restrict__ cnt,
    const float* __restrict__ Wo1, const float* __restrict__ bo1,
    const float* __restrict__ Wo2, const float* __restrict__ bo2,
    float* __restrict__ out) {
    __shared__ float pbuf[WPB][ND];
    int lane = threadIdx.x & 63;
    int wid = threadIdx.x >> 6;
    int g = blockIdx.x * WPB + wid;
    bool valid = g < N_GRAPH;
    int gc = valid ? g : N_GRAPH - 1;
    float c = fmaxf(cnt[gc], 1.f);
    pbuf[wid][lane] = pooled[gc * ND + lane] / c;
    __syncthreads();
    float h0 = bo1[lane], h1 = bo1[64 + lane];
#pragma unroll 8
    for (int k = 0; k < ND; ++k) {
        float pk = pbuf[wid][k];
        h0 += pk * Wo1[k * HD + lane];
        h1 += pk * Wo1[k * HD + 64 + lane];
    }
    float s = sp(h0) * Wo2[lane] + sp(h1) * Wo2[64 + lane];
#pragma unroll
    for (int off = 32; off; off >>= 1) s += __shfl_down(s, off);
    if (valid && lane == 0) out[g] = s + bo2[0];
}

extern "C" void kernel_launch(void* const* d_in, const int* in_sizes, int n_in,
                              void* d_out, int out_size, void* d_ws, size_t ws_size,
                              hipStream_t stream) {
    const float* x       = (const float*)d_in[0];
    const float* ea      = (const float*)d_in[1];
    const int*   ei      = (const int*)d_in[2];
    const int*   batch   = (const int*)d_in[3];
    const float* Wnp     = (const float*)d_in[4];
    const float* bnp     = (const float*)d_in[5];
    const float* g_np    = (const float*)d_in[6];
    const float* be_np   = (const float*)d_in[7];
    const float* Wep     = (const float*)d_in[8];
    const float* bep     = (const float*)d_in[9];
    const float* We1     = (const float*)d_in[10];
    const float* be1     = (const float*)d_in[11];
    const float* We2     = (const float*)d_in[12];
    const float* be2     = (const float*)d_in[13];
    const float* Wn1     = (const float*)d_in[14];
    const float* bn1     = (const float*)d_in[15];
    const float* Wn2     = (const float*)d_in[16];
    const float* bn2     = (const float*)d_in[17];
    const float* g_bn    = (const float*)d_in[18];
    const float* b_bn    = (const float*)d_in[19];
    const float* Wo1     = (const float*)d_in[20];
    const float* bo1     = (const float*)d_in[21];
    const float* Wo2     = (const float*)d_in[22];
    const float* bo2     = (const float*)d_in[23];

    float* ws = (float*)d_ws;
    size_t off = 0;
    float* h      = ws + off; off += (size_t)N_NODES * ND;
    float* t      = ws + off; off += (size_t)N_NODES * ND;
    float* aggr   = ws + off; off += (size_t)N_NODES * HD;
    float* ss     = ws + off; off += 2 * ND;
    float* pooled = ws + off; off += N_GRAPH * ND;
    float* cnt    = ws + off; off += 512;
    unsigned short* h_bf = (unsigned short*)(ws + off); off += (size_t)N_NODES * ND / 2;
    unsigned short* pA1  = (unsigned short*)(ws + off); off += 3 * 5 * 8 * 64 * 8 / 2;
    unsigned short* pA2  = (unsigned short*)(ws + off); off += 3 * 4 * 8 * 64 * 8 / 2;
    unsigned short* pWn1 = (unsigned short*)(ws + off); off += 3 * 6 * 8 * 64 * 8 / 2;
    unsigned short* pWn2 = (unsigned short*)(ws + off); off += 3 * 4 * 4 * 64 * 8 / 2;
    int* sD       = (int*)(ws + off); off += N_EDGES;
    int* sS       = (int*)(ws + off); off += N_EDGES;
    int* sE       = (int*)(ws + off); off += N_EDGES;
    int* hist     = (int*)(ws + off); off += N_NODES;
    int* cursor   = (int*)(ws + off); off += N_NODES;
    int* rowptr   = (int*)(ws + off); off += N_NODES;
    int* chunksum = (int*)(ws + off); off += 64;
    float* partN  = ws + off; off += 512 * 128;
    float* partU  = ws + off; off += (size_t)NBU * 128;
    size_t base_bytes = off * sizeof(float);
    unsigned short* e_bf = (unsigned short*)(ws + off);
    bool epre = (ws_size >= base_bytes + (size_t)N_EDGES * 32 * 2);

    float* outp = (float*)d_out;

    const int NCH = (N_NODES + 1023) / 1024;  // 49

    // ---- counting sort of edges by dst -> CSR (once per call) ----
    hipMemsetAsync(hist, 0, N_NODES * sizeof(int), stream);
    k_hist<<<(N_EDGES + 255) / 256, 256, 0, stream>>>(ei, hist);
    k_scan1<<<NCH, 1024, 0, stream>>>(hist, chunksum);
    k_scan2<<<1, 64, 0, stream>>>(chunksum, NCH);
    k_scan3<<<NCH, 1024, 0, stream>>>(hist, chunksum, cursor, rowptr);
    k_scatter<<<(N_EDGES + 255) / 256, 256, 0, stream>>>(ei, cursor, sD, sS, sE);
    if (epre)
        k_eproj_sorted<<<(int)(((long)N_EDGES * 32 + 255) / 256), 256, 0, stream>>>(
            ea, sE, Wep, bep, e_bf);

    // ---- pack all weights (3 layers x 4 matrices) in one launch ----
    k_pack_all<<<(3 * 8704 + 255) / 256, 256, 0, stream>>>(
        We1, We2, Wn1, Wn2, pA1, pA2, pWn1, pWn2);

    // ---- node projection + BN (two-stage stats, no contended atomics) ----
    k_node_proj<<<512, 256, 0, stream>>>(x, Wnp, bnp, t, partN);
    k_stats_reduce<<<1, 256, 0, stream>>>(partN, 512, g_np, be_np, ss);
    k_bn_apply<<<2048, 256, 0, stream>>>(t, ss, h, h_bf);

    for (int l = 0; l < 3; ++l) {
        hipMemsetAsync(aggr, 0, (size_t)N_NODES * HD * sizeof(float), stream);
        if (epre)
            k_edge_mfma_s<true><<<N_EDGES / 128, 256, 0, stream>>>(
                h_bf, e_bf, ea, sE, Wep, bep, sD, sS, rowptr, hist,
                pA1 + (size_t)l * 40 * 64 * 8, be1 + l * HD,
                pA2 + (size_t)l * 32 * 64 * 8, be2 + l * HD, aggr);
        else
            k_edge_mfma_s<false><<<N_EDGES / 128, 256, 0, stream>>>(
                h_bf, e_bf, ea, sE, Wep, bep, sD, sS, rowptr, hist,
                pA1 + (size_t)l * 40 * 64 * 8, be1 + l * HD,
                pA2 + (size_t)l * 32 * 64 * 8, be2 + l * HD, aggr);

        k_node_mfma<<<NBU, 64, 0, stream>>>(
            h_bf, aggr, h,
            pWn1 + (size_t)l * 48 * 64 * 8, bn1 + l * HD,
            pWn2 + (size_t)l * 16 * 64 * 8, bn2 + l * ND, t, partU);
        k_stats_reduce<<<1, 256, 0, stream>>>(partU, NBU, g_bn + l * ND, b_bn + l * ND, ss);
        k_bn_apply<<<2048, 256, 0, stream>>>(t, ss, h, h_bf);
    }

    hipMemsetAsync(pooled, 0, (size_t)(N_GRAPH * ND + 512) * sizeof(float), stream);
    k_pool<<<512, 256, 0, stream>>>(h, batch, pooled, cnt);
    k_readout<<<(N_GRAPH + WPB - 1) / WPB, 256, 0, stream>>>(
        pooled, cnt, Wo1, bo1, Wo2, bo2, outp);
}

// Round 19
// 1198.296 us; speedup vs baseline: 6.5342x; 1.0821x over previous
//
#include <hip/hip_runtime.h>
#include <hip/hip_bf16.h>

#define N_NODES 50000
#define N_EDGES 800000
#define N_GRAPH 500
#define ND 64
#define ED 32
#define HD 128
#define WPB 4   // waves per block (256 threads)
#define NBU ((N_NODES + 31) / 32)   // 1563 one-wave node blocks

typedef __attribute__((ext_vector_type(8))) short bf16x8;
typedef __attribute__((ext_vector_type(4))) float f32x4;

__device__ __forceinline__ float sp(float x) {
    return fmaxf(x, 0.f) + log1pf(expf(-fabsf(x)));
}

// fast softplus for the bf16 path (v_exp_f32/v_log_f32 based)
__device__ __forceinline__ float spf(float x) {
    return fmaxf(x, 0.f) + __logf(1.f + __expf(-fabsf(x)));
}

__device__ __forceinline__ unsigned short f2bf(float v) {
    __hip_bfloat16 b = __float2bfloat16(v);
    return *(unsigned short*)&b;
}

__device__ __forceinline__ unsigned int pkbf(float a, float b) {
    return (unsigned int)f2bf(a) | ((unsigned int)f2bf(b) << 16);
}

__device__ __forceinline__ float lo_bf(unsigned int u) { return __uint_as_float(u << 16); }
__device__ __forceinline__ float hi_bf(unsigned int u) { return __uint_as_float(u & 0xffff0000u); }

// load 8 fp32 and round to bf16x8 (same RNE as k_bn_apply/f2bf)
__device__ __forceinline__ bf16x8 ld8_f32_bf(const float* p) {
    f32x4 v0 = *(const f32x4*)p;
    f32x4 v1 = *(const f32x4*)(p + 4);
    bf16x8 r;
    r[0] = (short)f2bf(v0[0]); r[1] = (short)f2bf(v0[1]);
    r[2] = (short)f2bf(v0[2]); r[3] = (short)f2bf(v0[3]);
    r[4] = (short)f2bf(v1[0]); r[5] = (short)f2bf(v1[1]);
    r[6] = (short)f2bf(v1[2]); r[7] = (short)f2bf(v1[3]);
    return r;
}

// ---------------- node projection: partial BN stats per block -----------
__global__ __launch_bounds__(256) void k_node_proj(
    const float* __restrict__ x, const float* __restrict__ Wnp,
    const float* __restrict__ bnp, float* __restrict__ t,
    float* __restrict__ partN) {
    __shared__ float red0[4][64], red1[4][64];
    int lane = threadIdx.x & 63;
    int wid = threadIdx.x >> 6;
    int wave = (blockIdx.x * blockDim.x + threadIdx.x) >> 6;
    int nw = (gridDim.x * blockDim.x) >> 6;
    float w[13];
#pragma unroll
    for (int k = 0; k < 13; ++k) w[k] = Wnp[k * ND + lane];
    float bb = bnp[lane];
    float s0 = 0.f, s1 = 0.f;
    for (int i = wave; i < N_NODES; i += nw) {
        float acc = bb;
#pragma unroll
        for (int k = 0; k < 13; ++k) acc += x[i * 13 + k] * w[k];
        float v = sp(acc);
        t[i * ND + lane] = v;
        s0 += v; s1 += v * v;
    }
    red0[wid][lane] = s0;
    red1[wid][lane] = s1;
    __syncthreads();
    int tid = threadIdx.x;
    if (tid < 64)
        partN[blockIdx.x * 128 + tid] =
            red0[0][tid] + red0[1][tid] + red0[2][tid] + red0[3][tid];
    else if (tid < 128) {
        int c = tid - 64;
        partN[blockIdx.x * 128 + tid] =
            red1[0][c] + red1[1][c] + red1[2][c] + red1[3][c];
    }
}

// ---- two-stage BN stats: sum R partial rows, emit scale/shift ----------
__global__ void k_stats_reduce(const float* __restrict__ part, int R,
                               const float* __restrict__ g,
                               const float* __restrict__ b,
                               float* __restrict__ ss) {
    __shared__ float r0[4][64], r1[4][64];
    int q = threadIdx.x >> 6, c = threadIdx.x & 63;
    float S0 = 0.f, S1 = 0.f;
    for (int r = q; r < R; r += 4) {
        S0 += part[(size_t)r * 128 + c];
        S1 += part[(size_t)r * 128 + 64 + c];
    }
    r0[q][c] = S0; r1[q][c] = S1;
    __syncthreads();
    if (threadIdx.x < 64) {
        float s0 = r0[0][c] + r0[1][c] + r0[2][c] + r0[3][c];
        float s1 = r1[0][c] + r1[1][c] + r1[2][c] + r1[3][c];
        float inv_n = 1.f / (float)N_NODES;
        float mu = s0 * inv_n;
        float var = s1 * inv_n - mu * mu;
        float rs = rsqrtf(var + 1e-5f);
        float sc = rs * g[c];
        ss[c] = sc;
        ss[64 + c] = b[c] - mu * sc;
    }
}

__global__ __launch_bounds__(256) void k_bn_apply(
    const float* __restrict__ t, const float* __restrict__ ss,
    float* __restrict__ h, unsigned short* __restrict__ hb) {
    int idx = blockIdx.x * blockDim.x + threadIdx.x;
    int tot = N_NODES * ND;
    int stride = gridDim.x * blockDim.x;
    for (; idx < tot; idx += stride) {
        int c = idx & (ND - 1);
        float v = t[idx] * ss[c] + ss[ND + c];
        h[idx] = v;
        hb[idx] = f2bf(v);
    }
}

// ---------------- counting sort of edges by dst -------------------------
__global__ __launch_bounds__(256) void k_hist(const int* __restrict__ ei,
                                              int* __restrict__ hist) {
    int e = blockIdx.x * 256 + threadIdx.x;
    if (e < N_EDGES) atomicAdd(&hist[ei[N_EDGES + e]], 1);
}

__global__ __launch_bounds__(1024) void k_scan1(const int* __restrict__ hist,
                                                int* __restrict__ chunksum) {
    __shared__ int s[1024];
    int t = threadIdx.x;
    int i = blockIdx.x * 1024 + t;
    s[t] = (i < N_NODES) ? hist[i] : 0;
    __syncthreads();
    for (int off = 512; off; off >>= 1) {
        if (t < off) s[t] += s[t + off];
        __syncthreads();
    }
    if (t == 0) chunksum[blockIdx.x] = s[0];
}

__global__ void k_scan2(int* __restrict__ chunksum, int n) {
    if (threadIdx.x == 0) {
        int acc = 0;
        for (int i = 0; i < n; ++i) { int v = chunksum[i]; chunksum[i] = acc; acc += v; }
    }
}

__global__ __launch_bounds__(1024) void k_scan3(const int* __restrict__ hist,
                                                const int* __restrict__ chunksum,
                                                int* __restrict__ cursor,
                                                int* __restrict__ rowptr) {
    __shared__ int s[1024];
    int t = threadIdx.x;
    int i = blockIdx.x * 1024 + t;
    int v = (i < N_NODES) ? hist[i] : 0;
    s[t] = v;
    __syncthreads();
    for (int off = 1; off < 1024; off <<= 1) {
        int u = (t >= off) ? s[t - off] : 0;
        __syncthreads();
        s[t] += u;
        __syncthreads();
    }
    if (i < N_NODES) {
        int ex = chunksum[blockIdx.x] + s[t] - v;  // exclusive
        cursor[i] = ex;
        rowptr[i] = ex;
    }
}

__global__ __launch_bounds__(256) void k_scatter(const int* __restrict__ ei,
                                                 int* __restrict__ cursor,
                                                 int* __restrict__ sD,
                                                 int* __restrict__ sS,
                                                 int* __restrict__ sE) {
    int e = blockIdx.x * 256 + threadIdx.x;
    if (e >= N_EDGES) return;
    int d = ei[N_EDGES + e];
    int pos = atomicAdd(&cursor[d], 1);
    sD[pos] = d;
    sS[pos] = ei[e];
    sE[pos] = e;
}

// edge projection into sorted order (layer-invariant, once per call)
__global__ __launch_bounds__(256) void k_eproj_sorted(
    const float* __restrict__ ea, const int* __restrict__ sE,
    const float* __restrict__ Wep, const float* __restrict__ bep,
    unsigned short* __restrict__ e_bf) {
    long idx = (long)blockIdx.x * blockDim.x + threadIdx.x;
    long tot = (long)N_EDGES * 32;
    if (idx >= tot) return;
    int p = (int)(idx >> 5), col = (int)(idx & 31);
    int e = sE[p];
    float v = spf(ea[2 * e] * Wep[col] + ea[2 * e + 1] * Wep[32 + col] + bep[col]);
    e_bf[idx] = f2bf(v);
}

// ---- fused weight pack: all 3 layers x {We1,We2,Wn1,Wn2} in ONE launch --
__global__ __launch_bounds__(256) void k_pack_all(
    const float* __restrict__ We1, const float* __restrict__ We2,
    const float* __restrict__ Wn1, const float* __restrict__ Wn2,
    unsigned short* __restrict__ pA1, unsigned short* __restrict__ pA2,
    unsigned short* __restrict__ pWn1, unsigned short* __restrict__ pWn2) {
    int tid = blockIdx.x * 256 + threadIdx.x;
    const int PER_L = (40 + 32 + 48 + 16) * 64;  // 8704
    if (tid >= 3 * PER_L) return;
    int layer = tid / PER_L;
    int r = tid % PER_L;
    const float* W;
    unsigned short* out;
    int ncols, lt;
    if (r < 40 * 64) {
        lt = r; W = We1 + (size_t)layer * 160 * 128; out = pA1 + (size_t)layer * 40 * 64 * 8;
        ncols = 128;
    } else if (r < 72 * 64) {
        lt = r - 40 * 64; W = We2 + (size_t)layer * 128 * 128; out = pA2 + (size_t)layer * 32 * 64 * 8;
        ncols = 128;
    } else if (r < 120 * 64) {
        lt = r - 72 * 64; W = Wn1 + (size_t)layer * 192 * 128; out = pWn1 + (size_t)layer * 48 * 64 * 8;
        ncols = 128;
    } else {
        lt = r - 120 * 64; W = Wn2 + (size_t)layer * 128 * 64; out = pWn2 + (size_t)layer * 16 * 64 * 8;
        ncols = 64;
    }
    int nfrag = ncols >> 4;
    int l = lt & 63; int fr = lt >> 6; int nf = fr % nfrag; int ks = fr / nfrag;
    int n = 16 * nf + (l & 15);
    int k0 = 32 * ks + 8 * (l >> 4);
#pragma unroll
    for (int rr = 0; rr < 8; ++rr)
        out[lt * 8 + rr] = f2bf(W[(k0 + rr) * ncols + n]);
}

// ---------------- MFMA edge conv on dst-sorted edges --------------------
// Register-bounded for 4 blocks/CU: both GEMMs split into two nf-halves
// (acc = 32 AGPR peak, not 64); GEMM2 halves defer their packed bf16
// outputs in 16 VGPRs each so the LDS P stage isn't overwritten while it
// still serves B-operands. Peak regs ~118 < 128 -> (256,4) without spill.
template <bool EPRE>
__global__ __launch_bounds__(256, 4) void k_edge_mfma_s(
    const unsigned short* __restrict__ h_bf, const unsigned short* __restrict__ e_bf,
    const float* __restrict__ ea, const int* __restrict__ sE,
    const float* __restrict__ Wep, const float* __restrict__ bep,
    const int* __restrict__ sD, const int* __restrict__ sS,
    const int* __restrict__ rowptr, const int* __restrict__ hist,
    const unsigned short* __restrict__ pA1, const float* __restrict__ be1,
    const unsigned short* __restrict__ pA2, const float* __restrict__ be2,
    float* __restrict__ aggr) {
    __shared__ unsigned short P[WPB][32][136];   // per-wave P; reused as 128-row stage
    __shared__ int dstB[128];
    __shared__ unsigned short eL[EPRE ? 64 : 128 * 32];

    int lane = threadIdx.x & 63;
    int w = threadIdx.x >> 6;
    int m = lane & 15, g = lane >> 4;
    int tile0 = blockIdx.x * 128;
    int wbase = tile0 + 32 * w;

    int eD0 = sD[wbase + m];
    int eD1 = sD[wbase + 16 + m];
    int eS0 = sS[wbase + m];
    int eS1 = sS[wbase + 16 + m];

    if constexpr (!EPRE) {
        int col = threadIdx.x & 31;
        int r0 = threadIdx.x >> 5;
        float w0 = Wep[col], w1 = Wep[32 + col], bb = bep[col];
#pragma unroll
        for (int i = 0; i < 16; ++i) {
            int em = r0 + 8 * i;
            int e = sE[tile0 + em];
            eL[em * 32 + col] = f2bf(spf(ea[2 * e] * w0 + ea[2 * e + 1] * w1 + bb));
        }
        __syncthreads();
    }

    // ---- GEMM1 (K=160) in two nf-halves: acc holds 32 AGPR, not 64 ----
#pragma unroll
    for (int half = 0; half < 2; ++half) {
        f32x4 acc[2][4];
#pragma unroll
        for (int mf = 0; mf < 2; ++mf)
#pragma unroll
            for (int n2 = 0; n2 < 4; ++n2) acc[mf][n2] = (f32x4){0.f, 0.f, 0.f, 0.f};
#pragma unroll
        for (int ks = 0; ks < 5; ++ks) {
            bf16x8 b0, b1;
            if (ks < 2) {
                b0 = *(const bf16x8*)(h_bf + (size_t)eD0 * 64 + ks * 32 + 8 * g);
                b1 = *(const bf16x8*)(h_bf + (size_t)eD1 * 64 + ks * 32 + 8 * g);
            } else if (ks < 4) {
                b0 = *(const bf16x8*)(h_bf + (size_t)eS0 * 64 + (ks - 2) * 32 + 8 * g);
                b1 = *(const bf16x8*)(h_bf + (size_t)eS1 * 64 + (ks - 2) * 32 + 8 * g);
            } else {
                if constexpr (EPRE) {
                    b0 = *(const bf16x8*)(e_bf + (size_t)(wbase + m) * 32 + 8 * g);
                    b1 = *(const bf16x8*)(e_bf + (size_t)(wbase + 16 + m) * 32 + 8 * g);
                } else {
                    b0 = *(const bf16x8*)&eL[(32 * w + m) * 32 + 8 * g];
                    b1 = *(const bf16x8*)&eL[(32 * w + 16 + m) * 32 + 8 * g];
                }
            }
#pragma unroll
            for (int n2 = 0; n2 < 4; ++n2) {
                int nf = half * 4 + n2;
                bf16x8 a = *(const bf16x8*)(pA1 + ((ks * 8 + nf) * 64 + lane) * 8);
                acc[0][n2] = __builtin_amdgcn_mfma_f32_16x16x32_bf16(a, b0, acc[0][n2], 0, 0, 0);
                acc[1][n2] = __builtin_amdgcn_mfma_f32_16x16x32_bf16(a, b1, acc[1][n2], 0, 0, 0);
            }
        }
        // epilogue 1 (this half): bias + fast softplus -> P (bf16) in LDS
#pragma unroll
        for (int n2 = 0; n2 < 4; ++n2) {
            int nf = half * 4 + n2;
            f32x4 bb = *(const f32x4*)(be1 + 16 * nf + 4 * g);
#pragma unroll
            for (int mf = 0; mf < 2; ++mf) {
                f32x4 c = acc[mf][n2];
                unsigned int u01 = pkbf(spf(c[0] + bb[0]), spf(c[1] + bb[1]));
                unsigned int u23 = pkbf(spf(c[2] + bb[2]), spf(c[3] + bb[3]));
                unsigned int* dst = (unsigned int*)&P[w][m + 16 * mf][16 * nf + 4 * g];
                dst[0] = u01; dst[1] = u23;
            }
        }
    }

    // ---- GEMM2 (K=128) in two nf-halves; defer packed outputs in regs --
    unsigned int pk[2][16];
#pragma unroll
    for (int half = 0; half < 2; ++half) {
        f32x4 acc2[2][4];
#pragma unroll
        for (int mf = 0; mf < 2; ++mf)
#pragma unroll
            for (int n2 = 0; n2 < 4; ++n2) acc2[mf][n2] = (f32x4){0.f, 0.f, 0.f, 0.f};
#pragma unroll
        for (int ks = 0; ks < 4; ++ks) {
            bf16x8 b0 = *(const bf16x8*)&P[w][m][32 * ks + 8 * g];
            bf16x8 b1 = *(const bf16x8*)&P[w][m + 16][32 * ks + 8 * g];
#pragma unroll
            for (int n2 = 0; n2 < 4; ++n2) {
                int nf = half * 4 + n2;
                bf16x8 a = *(const bf16x8*)(pA2 + ((ks * 8 + nf) * 64 + lane) * 8);
                acc2[0][n2] = __builtin_amdgcn_mfma_f32_16x16x32_bf16(a, b0, acc2[0][n2], 0, 0, 0);
                acc2[1][n2] = __builtin_amdgcn_mfma_f32_16x16x32_bf16(a, b1, acc2[1][n2], 0, 0, 0);
            }
        }
        // bias + softplus, pack bf16 into registers (P still serves B!)
#pragma unroll
        for (int mf = 0; mf < 2; ++mf)
#pragma unroll
            for (int n2 = 0; n2 < 4; ++n2) {
                int nf = half * 4 + n2;
                f32x4 bb = *(const f32x4*)(be2 + 16 * nf + 4 * g);
                f32x4 c = acc2[mf][n2];
                pk[half][mf * 8 + 2 * n2] = pkbf(spf(c[0] + bb[0]), spf(c[1] + bb[1]));
                pk[half][mf * 8 + 2 * n2 + 1] = pkbf(spf(c[2] + bb[2]), spf(c[3] + bb[3]));
            }
    }

    // ---- epilogue 2: write both halves to the 128-row LDS stage --------
    unsigned short (*Pf)[136] = (unsigned short(*)[136]) & P[0][0][0];
#pragma unroll
    for (int half = 0; half < 2; ++half)
#pragma unroll
        for (int mf = 0; mf < 2; ++mf)
#pragma unroll
            for (int n2 = 0; n2 < 4; ++n2) {
                int nf = half * 4 + n2;
                unsigned int* dst = (unsigned int*)&Pf[32 * w + 16 * mf + m][16 * nf + 4 * g];
                dst[0] = pk[half][mf * 8 + 2 * n2];
                dst[1] = pk[half][mf * 8 + 2 * n2 + 1];
            }
    if (g == 0) {
        dstB[32 * w + m] = eD0;
        dstB[32 * w + 16 + m] = eD1;
    }
    __syncthreads();

    // ---- block-wide run-length segmented reduction ----
    int rbeg = 32 * w, rend = rbeg + 32;
    int r = rbeg;
    if (w) {  // skip rows continuing a run that started in a lower wave
        while (r < rend && dstB[r] == dstB[r - 1]) ++r;
    }
    while (r < rend) {
        int d = dstB[r];
        float a0 = 0.f, a1 = 0.f;
        int rr = r;
        do {
            unsigned int u = *(const unsigned int*)&Pf[rr][2 * lane];
            a0 += lo_bf(u);
            a1 += hi_bf(u);
            ++rr;
        } while (rr < 128 && dstB[rr] == d);
        int s0 = rowptr[d];
        bool interior = (s0 >= tile0) && (s0 + hist[d] <= tile0 + 128);
        float* base = aggr + (size_t)d * HD + 2 * lane;
        if (interior) {
            base[0] = a0;
            base[1] = a1;
        } else {
            atomicAdd(base, a0);
            atomicAdd(base + 1, a1);
        }
        r = rr;
    }
}

// ---------------- MFMA node update: 1-wave blocks, partial BN stats -----
__global__ __launch_bounds__(64, 3) void k_node_mfma(
    const unsigned short* __restrict__ h_bf, const float* __restrict__ aggr,
    const float* __restrict__ h,
    const unsigned short* __restrict__ pWn1, const float* __restrict__ bn1,
    const unsigned short* __restrict__ pWn2, const float* __restrict__ bn2,
    float* __restrict__ t, float* __restrict__ partU) {
    __shared__ unsigned short P[32][136];

    int lane = threadIdx.x;
    int m = lane & 15, g = lane >> 4;
    int wbase = blockIdx.x * 32;
    int n0 = wbase + m, n1 = wbase + 16 + m;
    bool v0 = n0 < N_NODES, v1 = n1 < N_NODES;
    int c0 = v0 ? n0 : N_NODES - 1;
    int c1 = v1 ? n1 : N_NODES - 1;

    f32x4 acc[2][8];
#pragma unroll
    for (int mf = 0; mf < 2; ++mf)
#pragma unroll
        for (int nf = 0; nf < 8; ++nf) acc[mf][nf] = (f32x4){0.f, 0.f, 0.f, 0.f};

    // ---- GEMM1: K = 192 (h 64 | aggr 128) ----
#pragma unroll
    for (int ks = 0; ks < 6; ++ks) {
        bf16x8 b0, b1;
        if (ks < 2) {
            b0 = *(const bf16x8*)(h_bf + (size_t)c0 * 64 + ks * 32 + 8 * g);
            b1 = *(const bf16x8*)(h_bf + (size_t)c1 * 64 + ks * 32 + 8 * g);
        } else {
            b0 = ld8_f32_bf(aggr + (size_t)c0 * 128 + (ks - 2) * 32 + 8 * g);
            b1 = ld8_f32_bf(aggr + (size_t)c1 * 128 + (ks - 2) * 32 + 8 * g);
        }
#pragma unroll
        for (int nf = 0; nf < 8; ++nf) {
            bf16x8 a = *(const bf16x8*)(pWn1 + ((ks * 8 + nf) * 64 + lane) * 8);
            acc[0][nf] = __builtin_amdgcn_mfma_f32_16x16x32_bf16(a, b0, acc[0][nf], 0, 0, 0);
            acc[1][nf] = __builtin_amdgcn_mfma_f32_16x16x32_bf16(a, b1, acc[1][nf], 0, 0, 0);
        }
    }

    // ---- epilogue 1: bias + fast softplus -> P (bf16) in LDS ----
#pragma unroll
    for (int nf = 0; nf < 8; ++nf) {
        f32x4 bb = *(const f32x4*)(bn1 + 16 * nf + 4 * g);
#pragma unroll
        for (int mf = 0; mf < 2; ++mf) {
            f32x4 c = acc[mf][nf];
            unsigned int u01 = pkbf(spf(c[0] + bb[0]), spf(c[1] + bb[1]));
            unsigned int u23 = pkbf(spf(c[2] + bb[2]), spf(c[3] + bb[3]));
            unsigned int* dst = (unsigned int*)&P[m + 16 * mf][16 * nf + 4 * g];
            dst[0] = u01; dst[1] = u23;
        }
    }

    f32x4 acc2[2][4];
#pragma unroll
    for (int mf = 0; mf < 2; ++mf)
#pragma unroll
        for (int nf = 0; nf < 4; ++nf) acc2[mf][nf] = (f32x4){0.f, 0.f, 0.f, 0.f};

    // ---- GEMM2: K = 128, N = 64 ----
#pragma unroll
    for (int ks = 0; ks < 4; ++ks) {
        bf16x8 b0 = *(const bf16x8*)&P[m][32 * ks + 8 * g];
        bf16x8 b1 = *(const bf16x8*)&P[m + 16][32 * ks + 8 * g];
#pragma unroll
        for (int nf = 0; nf < 4; ++nf) {
            bf16x8 a = *(const bf16x8*)(pWn2 + ((ks * 4 + nf) * 64 + lane) * 8);
            acc2[0][nf] = __builtin_amdgcn_mfma_f32_16x16x32_bf16(a, b0, acc2[0][nf], 0, 0, 0);
            acc2[1][nf] = __builtin_amdgcn_mfma_f32_16x16x32_bf16(a, b1, acc2[1][nf], 0, 0, 0);
        }
    }

    // ---- epilogue 2: +bn2 +h residual -> t; partial BN stats (no atomics)
#pragma unroll
    for (int nf = 0; nf < 4; ++nf) {
        f32x4 bb = *(const f32x4*)(bn2 + 16 * nf + 4 * g);
        f32x4 s0v = (f32x4){0.f, 0.f, 0.f, 0.f};
        f32x4 s1v = (f32x4){0.f, 0.f, 0.f, 0.f};
#pragma unroll
        for (int mf = 0; mf < 2; ++mf) {
            int cn = mf ? c1 : c0;
            bool vn = mf ? v1 : v0;
            f32x4 hv = *(const f32x4*)(h + (size_t)cn * 64 + 16 * nf + 4 * g);
            f32x4 c = acc2[mf][nf];
            f32x4 tn;
#pragma unroll
            for (int j = 0; j < 4; ++j) tn[j] = c[j] + bb[j] + hv[j];
            if (vn) *(f32x4*)(t + (size_t)cn * 64 + 16 * nf + 4 * g) = tn;
#pragma unroll
            for (int j = 0; j < 4; ++j) {
                float tv = vn ? tn[j] : 0.f;
                s0v[j] += tv;
                s1v[j] += tv * tv;
            }
        }
#pragma unroll
        for (int j = 0; j < 4; ++j) {
#pragma unroll
            for (int k = 1; k <= 8; k <<= 1) {
                s0v[j] += __shfl_xor(s0v[j], k);
                s1v[j] += __shfl_xor(s1v[j], k);
            }
        }
        if (m == 0) {
#pragma unroll
            for (int j = 0; j < 4; ++j) {
                int ch = 16 * nf + 4 * g + j;
                partU[(size_t)blockIdx.x * 128 + ch] = s0v[j];
                partU[(size_t)blockIdx.x * 128 + 64 + ch] = s1v[j];
            }
        }
    }
}

// ---------------- pooling + readout (unchanged) -------------------------
__global__ __launch_bounds__(256) void k_pool(
    const float* __restrict__ h, const int* __restrict__ batch,
    float* __restrict__ pooled, float* __restrict__ cnt) {
    int lane = threadIdx.x & 63;
    int wave = (blockIdx.x * blockDim.x + threadIdx.x) >> 6;
    int nw = (gridDim.x * blockDim.x) >> 6;
    int chunk = (N_NODES + nw - 1) / nw;
    int s = wave * chunk;
    int epos = min(N_NODES, s + chunk);
    if (s >= N_NODES) return;
    int curg = batch[s];
    float acc = 0.f, c = 0.f;
    for (int i = s; i < epos; ++i) {
        int g = batch[i];
        if (g != curg) {
            atomicAdd(&pooled[curg * ND + lane], acc);
            if (lane == 0) atomicAdd(&cnt[curg], c);
            acc = 0.f; c = 0.f; curg = g;
        }
        acc += h[i * ND + lane];
        c += 1.f;
    }
    atomicAdd(&pooled[curg * ND + lane], acc);
    if (lane == 0) atomicAdd(&cnt[curg], c);
}

__global__ __launch_bounds__(256) void k_readout(
    const float* __restrict__ pooled, const float* __restrict__ cnt,
    const float* __restrict__ Wo1, const float* __restrict__ bo1,
    const float* __restrict__ Wo2, const float* __restrict__ bo2,
    float* __restrict__ out) {
    __shared__ float pbuf[WPB][ND];
    int lane = threadIdx.x & 63;
    int wid = threadIdx.x >> 6;
    int g = blockIdx.x * WPB + wid;
    bool valid = g < N_GRAPH;
    int gc = valid ? g : N_GRAPH - 1;
    float c = fmaxf(cnt[gc], 1.f);
    pbuf[wid][lane] = pooled[gc * ND + lane] / c;
    __syncthreads();
    float h0 = bo1[lane], h1 = bo1[64 + lane];
#pragma unroll 8
    for (int k = 0; k < ND; ++k) {
        float pk = pbuf[wid][k];
        h0 += pk * Wo1[k * HD + lane];
        h1 += pk * Wo1[k * HD + 64 + lane];
    }
    float s = sp(h0) * Wo2[lane] + sp(h1) * Wo2[64 + lane];
#pragma unroll
    for (int off = 32; off; off >>= 1) s += __shfl_down(s, off);
    if (valid && lane == 0) out[g] = s + bo2[0];
}

extern "C" void kernel_launch(void* const* d_in, const int* in_sizes, int n_in,
                              void* d_out, int out_size, void* d_ws, size_t ws_size,
                              hipStream_t stream) {
    const float* x       = (const float*)d_in[0];
    const float* ea      = (const float*)d_in[1];
    const int*   ei      = (const int*)d_in[2];
    const int*   batch   = (const int*)d_in[3];
    const float* Wnp     = (const float*)d_in[4];
    const float* bnp     = (const float*)d_in[5];
    const float* g_np    = (const float*)d_in[6];
    const float* be_np   = (const float*)d_in[7];
    const float* Wep     = (const float*)d_in[8];
    const float* bep     = (const float*)d_in[9];
    const float* We1     = (const float*)d_in[10];
    const float* be1     = (const float*)d_in[11];
    const float* We2     = (const float*)d_in[12];
    const float* be2     = (const float*)d_in[13];
    const float* Wn1     = (const float*)d_in[14];
    const float* bn1     = (const float*)d_in[15];
    const float* Wn2     = (const float*)d_in[16];
    const float* bn2     = (const float*)d_in[17];
    const float* g_bn    = (const float*)d_in[18];
    const float* b_bn    = (const float*)d_in[19];
    const float* Wo1     = (const float*)d_in[20];
    const float* bo1     = (const float*)d_in[21];
    const float* Wo2     = (const float*)d_in[22];
    const float* bo2     = (const float*)d_in[23];

    float* ws = (float*)d_ws;
    size_t off = 0;
    float* h      = ws + off; off += (size_t)N_NODES * ND;
    float* t      = ws + off; off += (size_t)N_NODES * ND;
    float* aggr   = ws + off; off += (size_t)N_NODES * HD;
    float* ss     = ws + off; off += 2 * ND;
    float* pooled = ws + off; off += N_GRAPH * ND;
    float* cnt    = ws + off; off += 512;
    unsigned short* h_bf = (unsigned short*)(ws + off); off += (size_t)N_NODES * ND / 2;
    unsigned short* pA1  = (unsigned short*)(ws + off); off += 3 * 5 * 8 * 64 * 8 / 2;
    unsigned short* pA2  = (unsigned short*)(ws + off); off += 3 * 4 * 8 * 64 * 8 / 2;
    unsigned short* pWn1 = (unsigned short*)(ws + off); off += 3 * 6 * 8 * 64 * 8 / 2;
    unsigned short* pWn2 = (unsigned short*)(ws + off); off += 3 * 4 * 4 * 64 * 8 / 2;
    int* sD       = (int*)(ws + off); off += N_EDGES;
    int* sS       = (int*)(ws + off); off += N_EDGES;
    int* sE       = (int*)(ws + off); off += N_EDGES;
    int* hist     = (int*)(ws + off); off += N_NODES;
    int* cursor   = (int*)(ws + off); off += N_NODES;
    int* rowptr   = (int*)(ws + off); off += N_NODES;
    int* chunksum = (int*)(ws + off); off += 64;
    float* partN  = ws + off; off += 512 * 128;
    float* partU  = ws + off; off += (size_t)NBU * 128;
    size_t base_bytes = off * sizeof(float);
    unsigned short* e_bf = (unsigned short*)(ws + off);
    bool epre = (ws_size >= base_bytes + (size_t)N_EDGES * 32 * 2);

    float* outp = (float*)d_out;

    const int NCH = (N_NODES + 1023) / 1024;  // 49

    // ---- counting sort of edges by dst -> CSR (once per call) ----
    hipMemsetAsync(hist, 0, N_NODES * sizeof(int), stream);
    k_hist<<<(N_EDGES + 255) / 256, 256, 0, stream>>>(ei, hist);
    k_scan1<<<NCH, 1024, 0, stream>>>(hist, chunksum);
    k_scan2<<<1, 64, 0, stream>>>(chunksum, NCH);
    k_scan3<<<NCH, 1024, 0, stream>>>(hist, chunksum, cursor, rowptr);
    k_scatter<<<(N_EDGES + 255) / 256, 256, 0, stream>>>(ei, cursor, sD, sS, sE);
    if (epre)
        k_eproj_sorted<<<(int)(((long)N_EDGES * 32 + 255) / 256), 256, 0, stream>>>(
            ea, sE, Wep, bep, e_bf);

    // ---- pack all weights (3 layers x 4 matrices) in one launch ----
    k_pack_all<<<(3 * 8704 + 255) / 256, 256, 0, stream>>>(
        We1, We2, Wn1, Wn2, pA1, pA2, pWn1, pWn2);

    // ---- node projection + BN (two-stage stats, no contended atomics) ----
    k_node_proj<<<512, 256, 0, stream>>>(x, Wnp, bnp, t, partN);
    k_stats_reduce<<<1, 256, 0, stream>>>(partN, 512, g_np, be_np, ss);
    k_bn_apply<<<2048, 256, 0, stream>>>(t, ss, h, h_bf);

    for (int l = 0; l < 3; ++l) {
        hipMemsetAsync(aggr, 0, (size_t)N_NODES * HD * sizeof(float), stream);
        if (epre)
            k_edge_mfma_s<true><<<N_EDGES / 128, 256, 0, stream>>>(
                h_bf, e_bf, ea, sE, Wep, bep, sD, sS, rowptr, hist,
                pA1 + (size_t)l * 40 * 64 * 8, be1 + l * HD,
                pA2 + (size_t)l * 32 * 64 * 8, be2 + l * HD, aggr);
        else
            k_edge_mfma_s<false><<<N_EDGES / 128, 256, 0, stream>>>(
                h_bf, e_bf, ea, sE, Wep, bep, sD, sS, rowptr, hist,
                pA1 + (size_t)l * 40 * 64 * 8, be1 + l * HD,
                pA2 + (size_t)l * 32 * 64 * 8, be2 + l * HD, aggr);

        k_node_mfma<<<NBU, 64, 0, stream>>>(
            h_bf, aggr, h,
            pWn1 + (size_t)l * 48 * 64 * 8, bn1 + l * HD,
            pWn2 + (size_t)l * 16 * 64 * 8, bn2 + l * ND, t, partU);
        k_stats_reduce<<<1, 256, 0, stream>>>(partU, NBU, g_bn + l * ND, b_bn + l * ND, ss);
        k_bn_apply<<<2048, 256, 0, stream>>>(t, ss, h, h_bf);
    }

    hipMemsetAsync(pooled, 0, (size_t)(N_GRAPH * ND + 512) * sizeof(float), stream);
    k_pool<<<512, 256, 0, stream>>>(h, batch, pooled, cnt);
    k_readout<<<(N_GRAPH + WPB - 1) / WPB, 256, 0, stream>>>(
        pooled, cnt, Wo1, bo1, Wo2, bo2, outp);
}

// Round 22
// 1167.925 us; speedup vs baseline: 6.7041x; 1.0260x over previous
//
#include <hip/hip_runtime.h>
#include <hip/hip_bf16.h>

#define N_NODES 50000
#define N_EDGES 800000
#define N_GRAPH 500
#define ND 64
#define ED 32
#define HD 128
#define WPB 4   // waves per block (256 threads)
#define NBU ((N_NODES + 31) / 32)   // 1563 one-wave node blocks

typedef __attribute__((ext_vector_type(8))) short bf16x8;
typedef __attribute__((ext_vector_type(4))) float f32x4;

__device__ __forceinline__ float sp(float x) {
    return fmaxf(x, 0.f) + log1pf(expf(-fabsf(x)));
}

// fast softplus for the bf16 path (v_exp_f32/v_log_f32 based)
__device__ __forceinline__ float spf(float x) {
    return fmaxf(x, 0.f) + __logf(1.f + __expf(-fabsf(x)));
}

__device__ __forceinline__ unsigned short f2bf(float v) {
    __hip_bfloat16 b = __float2bfloat16(v);
    return *(unsigned short*)&b;
}

__device__ __forceinline__ unsigned int pkbf(float a, float b) {
    return (unsigned int)f2bf(a) | ((unsigned int)f2bf(b) << 16);
}

__device__ __forceinline__ float lo_bf(unsigned int u) { return __uint_as_float(u << 16); }
__device__ __forceinline__ float hi_bf(unsigned int u) { return __uint_as_float(u & 0xffff0000u); }

// load 8 fp32 and round to bf16x8 (same RNE as k_bn_apply/f2bf)
__device__ __forceinline__ bf16x8 ld8_f32_bf(const float* p) {
    f32x4 v0 = *(const f32x4*)p;
    f32x4 v1 = *(const f32x4*)(p + 4);
    bf16x8 r;
    r[0] = (short)f2bf(v0[0]); r[1] = (short)f2bf(v0[1]);
    r[2] = (short)f2bf(v0[2]); r[3] = (short)f2bf(v0[3]);
    r[4] = (short)f2bf(v1[0]); r[5] = (short)f2bf(v1[1]);
    r[6] = (short)f2bf(v1[2]); r[7] = (short)f2bf(v1[3]);
    return r;
}

// ---------------- node projection: partial BN stats per block -----------
__global__ __launch_bounds__(256) void k_node_proj(
    const float* __restrict__ x, const float* __restrict__ Wnp,
    const float* __restrict__ bnp, float* __restrict__ t,
    float* __restrict__ partN) {
    __shared__ float red0[4][64], red1[4][64];
    int lane = threadIdx.x & 63;
    int wid = threadIdx.x >> 6;
    int wave = (blockIdx.x * blockDim.x + threadIdx.x) >> 6;
    int nw = (gridDim.x * blockDim.x) >> 6;
    float w[13];
#pragma unroll
    for (int k = 0; k < 13; ++k) w[k] = Wnp[k * ND + lane];
    float bb = bnp[lane];
    float s0 = 0.f, s1 = 0.f;
    for (int i = wave; i < N_NODES; i += nw) {
        float acc = bb;
#pragma unroll
        for (int k = 0; k < 13; ++k) acc += x[i * 13 + k] * w[k];
        float v = sp(acc);
        t[i * ND + lane] = v;
        s0 += v; s1 += v * v;
    }
    red0[wid][lane] = s0;
    red1[wid][lane] = s1;
    __syncthreads();
    int tid = threadIdx.x;
    if (tid < 64)
        partN[blockIdx.x * 128 + tid] =
            red0[0][tid] + red0[1][tid] + red0[2][tid] + red0[3][tid];
    else if (tid < 128) {
        int c = tid - 64;
        partN[blockIdx.x * 128 + tid] =
            red1[0][c] + red1[1][c] + red1[2][c] + red1[3][c];
    }
}

// ---- two-stage BN stats: sum R partial rows, emit scale/shift ----------
__global__ void k_stats_reduce(const float* __restrict__ part, int R,
                               const float* __restrict__ g,
                               const float* __restrict__ b,
                               float* __restrict__ ss) {
    __shared__ float r0[4][64], r1[4][64];
    int q = threadIdx.x >> 6, c = threadIdx.x & 63;
    float S0 = 0.f, S1 = 0.f;
    for (int r = q; r < R; r += 4) {
        S0 += part[(size_t)r * 128 + c];
        S1 += part[(size_t)r * 128 + 64 + c];
    }
    r0[q][c] = S0; r1[q][c] = S1;
    __syncthreads();
    if (threadIdx.x < 64) {
        float s0 = r0[0][c] + r0[1][c] + r0[2][c] + r0[3][c];
        float s1 = r1[0][c] + r1[1][c] + r1[2][c] + r1[3][c];
        float inv_n = 1.f / (float)N_NODES;
        float mu = s0 * inv_n;
        float var = s1 * inv_n - mu * mu;
        float rs = rsqrtf(var + 1e-5f);
        float sc = rs * g[c];
        ss[c] = sc;
        ss[64 + c] = b[c] - mu * sc;
    }
}

__global__ __launch_bounds__(256) void k_bn_apply(
    const float* __restrict__ t, const float* __restrict__ ss,
    float* __restrict__ h, unsigned short* __restrict__ hb) {
    int idx = blockIdx.x * blockDim.x + threadIdx.x;
    int tot = N_NODES * ND;
    int stride = gridDim.x * blockDim.x;
    for (; idx < tot; idx += stride) {
        int c = idx & (ND - 1);
        float v = t[idx] * ss[c] + ss[ND + c];
        h[idx] = v;
        hb[idx] = f2bf(v);
    }
}

// ---------------- counting sort of edges by dst -------------------------
__global__ __launch_bounds__(256) void k_hist(const int* __restrict__ ei,
                                              int* __restrict__ hist) {
    int e = blockIdx.x * 256 + threadIdx.x;
    if (e < N_EDGES) atomicAdd(&hist[ei[N_EDGES + e]], 1);
}

__global__ __launch_bounds__(1024) void k_scan1(const int* __restrict__ hist,
                                                int* __restrict__ chunksum) {
    __shared__ int s[1024];
    int t = threadIdx.x;
    int i = blockIdx.x * 1024 + t;
    s[t] = (i < N_NODES) ? hist[i] : 0;
    __syncthreads();
    for (int off = 512; off; off >>= 1) {
        if (t < off) s[t] += s[t + off];
        __syncthreads();
    }
    if (t == 0) chunksum[blockIdx.x] = s[0];
}

__global__ void k_scan2(int* __restrict__ chunksum, int n) {
    if (threadIdx.x == 0) {
        int acc = 0;
        for (int i = 0; i < n; ++i) { int v = chunksum[i]; chunksum[i] = acc; acc += v; }
    }
}

__global__ __launch_bounds__(1024) void k_scan3(const int* __restrict__ hist,
                                                const int* __restrict__ chunksum,
                                                int* __restrict__ cursor,
                                                int* __restrict__ rowptr) {
    __shared__ int s[1024];
    int t = threadIdx.x;
    int i = blockIdx.x * 1024 + t;
    int v = (i < N_NODES) ? hist[i] : 0;
    s[t] = v;
    __syncthreads();
    for (int off = 1; off < 1024; off <<= 1) {
        int u = (t >= off) ? s[t - off] : 0;
        __syncthreads();
        s[t] += u;
        __syncthreads();
    }
    if (i < N_NODES) {
        int ex = chunksum[blockIdx.x] + s[t] - v;  // exclusive
        cursor[i] = ex;
        rowptr[i] = ex;
    }
}

__global__ __launch_bounds__(256) void k_scatter(const int* __restrict__ ei,
                                                 int* __restrict__ cursor,
                                                 int* __restrict__ sD,
                                                 int* __restrict__ sS,
                                                 int* __restrict__ sE) {
    int e = blockIdx.x * 256 + threadIdx.x;
    if (e >= N_EDGES) return;
    int d = ei[N_EDGES + e];
    int pos = atomicAdd(&cursor[d], 1);
    sD[pos] = d;
    sS[pos] = ei[e];
    sE[pos] = e;
}

// edge projection into sorted order (layer-invariant, once per call)
__global__ __launch_bounds__(256) void k_eproj_sorted(
    const float* __restrict__ ea, const int* __restrict__ sE,
    const float* __restrict__ Wep, const float* __restrict__ bep,
    unsigned short* __restrict__ e_bf) {
    long idx = (long)blockIdx.x * blockDim.x + threadIdx.x;
    long tot = (long)N_EDGES * 32;
    if (idx >= tot) return;
    int p = (int)(idx >> 5), col = (int)(idx & 31);
    int e = sE[p];
    float v = spf(ea[2 * e] * Wep[col] + ea[2 * e + 1] * Wep[32 + col] + bep[col]);
    e_bf[idx] = f2bf(v);
}

// ---- fused weight pack: all 3 layers x {We1,We2,Wn1,Wn2} in ONE launch --
__global__ __launch_bounds__(256) void k_pack_all(
    const float* __restrict__ We1, const float* __restrict__ We2,
    const float* __restrict__ Wn1, const float* __restrict__ Wn2,
    unsigned short* __restrict__ pA1, unsigned short* __restrict__ pA2,
    unsigned short* __restrict__ pWn1, unsigned short* __restrict__ pWn2) {
    int tid = blockIdx.x * 256 + threadIdx.x;
    const int PER_L = (40 + 32 + 48 + 16) * 64;  // 8704
    if (tid >= 3 * PER_L) return;
    int layer = tid / PER_L;
    int r = tid % PER_L;
    const float* W;
    unsigned short* out;
    int ncols, lt;
    if (r < 40 * 64) {
        lt = r; W = We1 + (size_t)layer * 160 * 128; out = pA1 + (size_t)layer * 40 * 64 * 8;
        ncols = 128;
    } else if (r < 72 * 64) {
        lt = r - 40 * 64; W = We2 + (size_t)layer * 128 * 128; out = pA2 + (size_t)layer * 32 * 64 * 8;
        ncols = 128;
    } else if (r < 120 * 64) {
        lt = r - 72 * 64; W = Wn1 + (size_t)layer * 192 * 128; out = pWn1 + (size_t)layer * 48 * 64 * 8;
        ncols = 128;
    } else {
        lt = r - 120 * 64; W = Wn2 + (size_t)layer * 128 * 64; out = pWn2 + (size_t)layer * 16 * 64 * 8;
        ncols = 64;
    }
    int nfrag = ncols >> 4;
    int l = lt & 63; int fr = lt >> 6; int nf = fr % nfrag; int ks = fr / nfrag;
    int n = 16 * nf + (l & 15);
    int k0 = 32 * ks + 8 * (l >> 4);
#pragma unroll
    for (int rr = 0; rr < 8; ++rr)
        out[lt * 8 + rr] = f2bf(W[(k0 + rr) * ncols + n]);
}

// ---------------- MFMA edge conv on dst-sorted edges --------------------
// Register-bounded for 4 blocks/CU with NO deferral spill:
//  - GEMM1 split into two nf-halves (acc = 32 AGPR peak).
//  - GEMM2 split by m-fragment: mf reads ONLY P rows [16mf,16mf+16) and its
//    outputs overwrite exactly those rows, so each half writes its packed
//    bf16 results straight to LDS after its MFMAs (no pk[] registers).
// Peak ~105 regs < 128.
template <bool EPRE>
__global__ __launch_bounds__(256, 4) void k_edge_mfma_s(
    const unsigned short* __restrict__ h_bf, const unsigned short* __restrict__ e_bf,
    const float* __restrict__ ea, const int* __restrict__ sE,
    const float* __restrict__ Wep, const float* __restrict__ bep,
    const int* __restrict__ sD, const int* __restrict__ sS,
    const int* __restrict__ rowptr, const int* __restrict__ hist,
    const unsigned short* __restrict__ pA1, const float* __restrict__ be1,
    const unsigned short* __restrict__ pA2, const float* __restrict__ be2,
    float* __restrict__ aggr) {
    __shared__ unsigned short P[WPB][32][136];   // per-wave P; reused as 128-row stage
    __shared__ int dstB[128];
    __shared__ unsigned short eL[EPRE ? 64 : 128 * 32];

    int lane = threadIdx.x & 63;
    int w = threadIdx.x >> 6;
    int m = lane & 15, g = lane >> 4;
    int tile0 = blockIdx.x * 128;
    int wbase = tile0 + 32 * w;

    int eD0 = sD[wbase + m];
    int eD1 = sD[wbase + 16 + m];
    int eS0 = sS[wbase + m];
    int eS1 = sS[wbase + 16 + m];

    if constexpr (!EPRE) {
        int col = threadIdx.x & 31;
        int r0 = threadIdx.x >> 5;
        float w0 = Wep[col], w1 = Wep[32 + col], bb = bep[col];
#pragma unroll
        for (int i = 0; i < 16; ++i) {
            int em = r0 + 8 * i;
            int e = sE[tile0 + em];
            eL[em * 32 + col] = f2bf(spf(ea[2 * e] * w0 + ea[2 * e + 1] * w1 + bb));
        }
        __syncthreads();
    }

    // ---- GEMM1 (K=160) in two nf-halves: acc holds 32 AGPR, not 64 ----
#pragma unroll
    for (int half = 0; half < 2; ++half) {
        f32x4 acc[2][4];
#pragma unroll
        for (int mf = 0; mf < 2; ++mf)
#pragma unroll
            for (int n2 = 0; n2 < 4; ++n2) acc[mf][n2] = (f32x4){0.f, 0.f, 0.f, 0.f};
#pragma unroll
        for (int ks = 0; ks < 5; ++ks) {
            bf16x8 b0, b1;
            if (ks < 2) {
                b0 = *(const bf16x8*)(h_bf + (size_t)eD0 * 64 + ks * 32 + 8 * g);
                b1 = *(const bf16x8*)(h_bf + (size_t)eD1 * 64 + ks * 32 + 8 * g);
            } else if (ks < 4) {
                b0 = *(const bf16x8*)(h_bf + (size_t)eS0 * 64 + (ks - 2) * 32 + 8 * g);
                b1 = *(const bf16x8*)(h_bf + (size_t)eS1 * 64 + (ks - 2) * 32 + 8 * g);
            } else {
                if constexpr (EPRE) {
                    b0 = *(const bf16x8*)(e_bf + (size_t)(wbase + m) * 32 + 8 * g);
                    b1 = *(const bf16x8*)(e_bf + (size_t)(wbase + 16 + m) * 32 + 8 * g);
                } else {
                    b0 = *(const bf16x8*)&eL[(32 * w + m) * 32 + 8 * g];
                    b1 = *(const bf16x8*)&eL[(32 * w + 16 + m) * 32 + 8 * g];
                }
            }
#pragma unroll
            for (int n2 = 0; n2 < 4; ++n2) {
                int nf = half * 4 + n2;
                bf16x8 a = *(const bf16x8*)(pA1 + ((ks * 8 + nf) * 64 + lane) * 8);
                acc[0][n2] = __builtin_amdgcn_mfma_f32_16x16x32_bf16(a, b0, acc[0][n2], 0, 0, 0);
                acc[1][n2] = __builtin_amdgcn_mfma_f32_16x16x32_bf16(a, b1, acc[1][n2], 0, 0, 0);
            }
        }
        // epilogue 1 (this half): bias + fast softplus -> P (bf16) in LDS
#pragma unroll
        for (int n2 = 0; n2 < 4; ++n2) {
            int nf = half * 4 + n2;
            f32x4 bb = *(const f32x4*)(be1 + 16 * nf + 4 * g);
#pragma unroll
            for (int mf = 0; mf < 2; ++mf) {
                f32x4 c = acc[mf][n2];
                unsigned int u01 = pkbf(spf(c[0] + bb[0]), spf(c[1] + bb[1]));
                unsigned int u23 = pkbf(spf(c[2] + bb[2]), spf(c[3] + bb[3]));
                unsigned int* dst = (unsigned int*)&P[w][m + 16 * mf][16 * nf + 4 * g];
                dst[0] = u01; dst[1] = u23;
            }
        }
    }

    // ---- GEMM2 (K=128) split by m-fragment; direct LDS writes ----------
    // mf reads only P[w] rows [16mf,16mf+16); outputs overwrite those rows.
    unsigned short (*Pf)[136] = (unsigned short(*)[136]) & P[0][0][0];
#pragma unroll
    for (int mf = 0; mf < 2; ++mf) {
        f32x4 acc2[8];
#pragma unroll
        for (int nf = 0; nf < 8; ++nf) acc2[nf] = (f32x4){0.f, 0.f, 0.f, 0.f};
#pragma unroll
        for (int ks = 0; ks < 4; ++ks) {
            bf16x8 b = *(const bf16x8*)&P[w][m + 16 * mf][32 * ks + 8 * g];
#pragma unroll
            for (int nf = 0; nf < 8; ++nf) {
                bf16x8 a = *(const bf16x8*)(pA2 + ((ks * 8 + nf) * 64 + lane) * 8);
                acc2[nf] = __builtin_amdgcn_mfma_f32_16x16x32_bf16(a, b, acc2[nf], 0, 0, 0);
            }
        }
        // bias + softplus -> write straight to the stage rows (this mf's own)
#pragma unroll
        for (int nf = 0; nf < 8; ++nf) {
            f32x4 bb = *(const f32x4*)(be2 + 16 * nf + 4 * g);
            f32x4 c = acc2[nf];
            unsigned int* dst = (unsigned int*)&Pf[32 * w + 16 * mf + m][16 * nf + 4 * g];
            dst[0] = pkbf(spf(c[0] + bb[0]), spf(c[1] + bb[1]));
            dst[1] = pkbf(spf(c[2] + bb[2]), spf(c[3] + bb[3]));
        }
    }
    if (g == 0) {
        dstB[32 * w + m] = eD0;
        dstB[32 * w + 16 + m] = eD1;
    }
    __syncthreads();

    // ---- block-wide run-length segmented reduction ----
    int rbeg = 32 * w, rend = rbeg + 32;
    int r = rbeg;
    if (w) {  // skip rows continuing a run that started in a lower wave
        while (r < rend && dstB[r] == dstB[r - 1]) ++r;
    }
    while (r < rend) {
        int d = dstB[r];
        float a0 = 0.f, a1 = 0.f;
        int rr = r;
        do {
            unsigned int u = *(const unsigned int*)&Pf[rr][2 * lane];
            a0 += lo_bf(u);
            a1 += hi_bf(u);
            ++rr;
        } while (rr < 128 && dstB[rr] == d);
        int s0 = rowptr[d];
        bool interior = (s0 >= tile0) && (s0 + hist[d] <= tile0 + 128);
        float* base = aggr + (size_t)d * HD + 2 * lane;
        if (interior) {
            base[0] = a0;
            base[1] = a1;
        } else {
            atomicAdd(base, a0);
            atomicAdd(base + 1, a1);
        }
        r = rr;
    }
}

// ---------------- MFMA node update: 1-wave blocks, partial BN stats -----
__global__ __launch_bounds__(64, 3) void k_node_mfma(
    const unsigned short* __restrict__ h_bf, const float* __restrict__ aggr,
    const float* __restrict__ h,
    const unsigned short* __restrict__ pWn1, const float* __restrict__ bn1,
    const unsigned short* __restrict__ pWn2, const float* __restrict__ bn2,
    float* __restrict__ t, float* __restrict__ partU) {
    __shared__ unsigned short P[32][136];

    int lane = threadIdx.x;
    int m = lane & 15, g = lane >> 4;
    int wbase = blockIdx.x * 32;
    int n0 = wbase + m, n1 = wbase + 16 + m;
    bool v0 = n0 < N_NODES, v1 = n1 < N_NODES;
    int c0 = v0 ? n0 : N_NODES - 1;
    int c1 = v1 ? n1 : N_NODES - 1;

    f32x4 acc[2][8];
#pragma unroll
    for (int mf = 0; mf < 2; ++mf)
#pragma unroll
        for (int nf = 0; nf < 8; ++nf) acc[mf][nf] = (f32x4){0.f, 0.f, 0.f, 0.f};

    // ---- GEMM1: K = 192 (h 64 | aggr 128) ----
#pragma unroll
    for (int ks = 0; ks < 6; ++ks) {
        bf16x8 b0, b1;
        if (ks < 2) {
            b0 = *(const bf16x8*)(h_bf + (size_t)c0 * 64 + ks * 32 + 8 * g);
            b1 = *(const bf16x8*)(h_bf + (size_t)c1 * 64 + ks * 32 + 8 * g);
        } else {
            b0 = ld8_f32_bf(aggr + (size_t)c0 * 128 + (ks - 2) * 32 + 8 * g);
            b1 = ld8_f32_bf(aggr + (size_t)c1 * 128 + (ks - 2) * 32 + 8 * g);
        }
#pragma unroll
        for (int nf = 0; nf < 8; ++nf) {
            bf16x8 a = *(const bf16x8*)(pWn1 + ((ks * 8 + nf) * 64 + lane) * 8);
            acc[0][nf] = __builtin_amdgcn_mfma_f32_16x16x32_bf16(a, b0, acc[0][nf], 0, 0, 0);
            acc[1][nf] = __builtin_amdgcn_mfma_f32_16x16x32_bf16(a, b1, acc[1][nf], 0, 0, 0);
        }
    }

    // ---- epilogue 1: bias + fast softplus -> P (bf16) in LDS ----
#pragma unroll
    for (int nf = 0; nf < 8; ++nf) {
        f32x4 bb = *(const f32x4*)(bn1 + 16 * nf + 4 * g);
#pragma unroll
        for (int mf = 0; mf < 2; ++mf) {
            f32x4 c = acc[mf][nf];
            unsigned int u01 = pkbf(spf(c[0] + bb[0]), spf(c[1] + bb[1]));
            unsigned int u23 = pkbf(spf(c[2] + bb[2]), spf(c[3] + bb[3]));
            unsigned int* dst = (unsigned int*)&P[m + 16 * mf][16 * nf + 4 * g];
            dst[0] = u01; dst[1] = u23;
        }
    }

    f32x4 acc2[2][4];
#pragma unroll
    for (int mf = 0; mf < 2; ++mf)
#pragma unroll
        for (int nf = 0; nf < 4; ++nf) acc2[mf][nf] = (f32x4){0.f, 0.f, 0.f, 0.f};

    // ---- GEMM2: K = 128, N = 64 ----
#pragma unroll
    for (int ks = 0; ks < 4; ++ks) {
        bf16x8 b0 = *(const bf16x8*)&P[m][32 * ks + 8 * g];
        bf16x8 b1 = *(const bf16x8*)&P[m + 16][32 * ks + 8 * g];
#pragma unroll
        for (int nf = 0; nf < 4; ++nf) {
            bf16x8 a = *(const bf16x8*)(pWn2 + ((ks * 4 + nf) * 64 + lane) * 8);
            acc2[0][nf] = __builtin_amdgcn_mfma_f32_16x16x32_bf16(a, b0, acc2[0][nf], 0, 0, 0);
            acc2[1][nf] = __builtin_amdgcn_mfma_f32_16x16x32_bf16(a, b1, acc2[1][nf], 0, 0, 0);
        }
    }

    // ---- epilogue 2: +bn2 +h residual -> t; partial BN stats (no atomics)
#pragma unroll
    for (int nf = 0; nf < 4; ++nf) {
        f32x4 bb = *(const f32x4*)(bn2 + 16 * nf + 4 * g);
        f32x4 s0v = (f32x4){0.f, 0.f, 0.f, 0.f};
        f32x4 s1v = (f32x4){0.f, 0.f, 0.f, 0.f};
#pragma unroll
        for (int mf = 0; mf < 2; ++mf) {
            int cn = mf ? c1 : c0;
            bool vn = mf ? v1 : v0;
            f32x4 hv = *(const f32x4*)(h + (size_t)cn * 64 + 16 * nf + 4 * g);
            f32x4 c = acc2[mf][nf];
            f32x4 tn;
#pragma unroll
            for (int j = 0; j < 4; ++j) tn[j] = c[j] + bb[j] + hv[j];
            if (vn) *(f32x4*)(t + (size_t)cn * 64 + 16 * nf + 4 * g) = tn;
#pragma unroll
            for (int j = 0; j < 4; ++j) {
                float tv = vn ? tn[j] : 0.f;
                s0v[j] += tv;
                s1v[j] += tv * tv;
            }
        }
#pragma unroll
        for (int j = 0; j < 4; ++j) {
#pragma unroll
            for (int k = 1; k <= 8; k <<= 1) {
                s0v[j] += __shfl_xor(s0v[j], k);
                s1v[j] += __shfl_xor(s1v[j], k);
            }
        }
        if (m == 0) {
#pragma unroll
            for (int j = 0; j < 4; ++j) {
                int ch = 16 * nf + 4 * g + j;
                partU[(size_t)blockIdx.x * 128 + ch] = s0v[j];
                partU[(size_t)blockIdx.x * 128 + 64 + ch] = s1v[j];
            }
        }
    }
}

// ---------------- pooling + readout (unchanged) -------------------------
__global__ __launch_bounds__(256) void k_pool(
    const float* __restrict__ h, const int* __restrict__ batch,
    float* __restrict__ pooled, float* __restrict__ cnt) {
    int lane = threadIdx.x & 63;
    int wave = (blockIdx.x * blockDim.x + threadIdx.x) >> 6;
    int nw = (gridDim.x * blockDim.x) >> 6;
    int chunk = (N_NODES + nw - 1) / nw;
    int s = wave * chunk;
    int epos = min(N_NODES, s + chunk);
    if (s >= N_NODES) return;
    int curg = batch[s];
    float acc = 0.f, c = 0.f;
    for (int i = s; i < epos; ++i) {
        int g = batch[i];
        if (g != curg) {
            atomicAdd(&pooled[curg * ND + lane], acc);
            if (lane == 0) atomicAdd(&cnt[curg], c);
            acc = 0.f; c = 0.f; curg = g;
        }
        acc += h[i * ND + lane];
        c += 1.f;
    }
    atomicAdd(&pooled[curg * ND + lane], acc);
    if (lane == 0) atomicAdd(&cnt[curg], c);
}

__global__ __launch_bounds__(256) void k_readout(
    const float* __restrict__ pooled, const float* __restrict__ cnt,
    const float* __restrict__ Wo1, const float* __restrict__ bo1,
    const float* __restrict__ Wo2, const float* __restrict__ bo2,
    float* __restrict__ out) {
    __shared__ float pbuf[WPB][ND];
    int lane = threadIdx.x & 63;
    int wid = threadIdx.x >> 6;
    int g = blockIdx.x * WPB + wid;
    bool valid = g < N_GRAPH;
    int gc = valid ? g : N_GRAPH - 1;
    float c = fmaxf(cnt[gc], 1.f);
    pbuf[wid][lane] = pooled[gc * ND + lane] / c;
    __syncthreads();
    float h0 = bo1[lane], h1 = bo1[64 + lane];
#pragma unroll 8
    for (int k = 0; k < ND; ++k) {
        float pk = pbuf[wid][k];
        h0 += pk * Wo1[k * HD + lane];
        h1 += pk * Wo1[k * HD + 64 + lane];
    }
    float s = sp(h0) * Wo2[lane] + sp(h1) * Wo2[64 + lane];
#pragma unroll
    for (int off = 32; off; off >>= 1) s += __shfl_down(s, off);
    if (valid && lane == 0) out[g] = s + bo2[0];
}

extern "C" void kernel_launch(void* const* d_in, const int* in_sizes, int n_in,
                              void* d_out, int out_size, void* d_ws, size_t ws_size,
                              hipStream_t stream) {
    const float* x       = (const float*)d_in[0];
    const float* ea      = (const float*)d_in[1];
    const int*   ei      = (const int*)d_in[2];
    const int*   batch   = (const int*)d_in[3];
    const float* Wnp     = (const float*)d_in[4];
    const float* bnp     = (const float*)d_in[5];
    const float* g_np    = (const float*)d_in[6];
    const float* be_np   = (const float*)d_in[7];
    const float* Wep     = (const float*)d_in[8];
    const float* bep     = (const float*)d_in[9];
    const float* We1     = (const float*)d_in[10];
    const float* be1     = (const float*)d_in[11];
    const float* We2     = (const float*)d_in[12];
    const float* be2     = (const float*)d_in[13];
    const float* Wn1     = (const float*)d_in[14];
    const float* bn1     = (const float*)d_in[15];
    const float* Wn2     = (const float*)d_in[16];
    const float* bn2     = (const float*)d_in[17];
    const float* g_bn    = (const float*)d_in[18];
    const float* b_bn    = (const float*)d_in[19];
    const float* Wo1     = (const float*)d_in[20];
    const float* bo1     = (const float*)d_in[21];
    const float* Wo2     = (const float*)d_in[22];
    const float* bo2     = (const float*)d_in[23];

    float* ws = (float*)d_ws;
    size_t off = 0;
    float* h      = ws + off; off += (size_t)N_NODES * ND;
    float* t      = ws + off; off += (size_t)N_NODES * ND;
    float* aggr   = ws + off; off += (size_t)N_NODES * HD;
    float* ss     = ws + off; off += 2 * ND;
    float* pooled = ws + off; off += N_GRAPH * ND;
    float* cnt    = ws + off; off += 512;
    unsigned short* h_bf = (unsigned short*)(ws + off); off += (size_t)N_NODES * ND / 2;
    unsigned short* pA1  = (unsigned short*)(ws + off); off += 3 * 5 * 8 * 64 * 8 / 2;
    unsigned short* pA2  = (unsigned short*)(ws + off); off += 3 * 4 * 8 * 64 * 8 / 2;
    unsigned short* pWn1 = (unsigned short*)(ws + off); off += 3 * 6 * 8 * 64 * 8 / 2;
    unsigned short* pWn2 = (unsigned short*)(ws + off); off += 3 * 4 * 4 * 64 * 8 / 2;
    int* sD       = (int*)(ws + off); off += N_EDGES;
    int* sS       = (int*)(ws + off); off += N_EDGES;
    int* sE       = (int*)(ws + off); off += N_EDGES;
    int* hist     = (int*)(ws + off); off += N_NODES;
    int* cursor   = (int*)(ws + off); off += N_NODES;
    int* rowptr   = (int*)(ws + off); off += N_NODES;
    int* chunksum = (int*)(ws + off); off += 64;
    float* partN  = ws + off; off += 512 * 128;
    float* partU  = ws + off; off += (size_t)NBU * 128;
    size_t base_bytes = off * sizeof(float);
    unsigned short* e_bf = (unsigned short*)(ws + off);
    bool epre = (ws_size >= base_bytes + (size_t)N_EDGES * 32 * 2);

    float* outp = (float*)d_out;

    const int NCH = (N_NODES + 1023) / 1024;  // 49

    // ---- counting sort of edges by dst -> CSR (once per call) ----
    hipMemsetAsync(hist, 0, N_NODES * sizeof(int), stream);
    k_hist<<<(N_EDGES + 255) / 256, 256, 0, stream>>>(ei, hist);
    k_scan1<<<NCH, 1024, 0, stream>>>(hist, chunksum);
    k_scan2<<<1, 64, 0, stream>>>(chunksum, NCH);
    k_scan3<<<NCH, 1024, 0, stream>>>(hist, chunksum, cursor, rowptr);
    k_scatter<<<(N_EDGES + 255) / 256, 256, 0, stream>>>(ei, cursor, sD, sS, sE);
    if (epre)
        k_eproj_sorted<<<(int)(((long)N_EDGES * 32 + 255) / 256), 256, 0, stream>>>(
            ea, sE, Wep, bep, e_bf);

    // ---- pack all weights (3 layers x 4 matrices) in one launch ----
    k_pack_all<<<(3 * 8704 + 255) / 256, 256, 0, stream>>>(
        We1, We2, Wn1, Wn2, pA1, pA2, pWn1, pWn2);

    // ---- node projection + BN (two-stage stats, no contended atomics) ----
    k_node_proj<<<512, 256, 0, stream>>>(x, Wnp, bnp, t, partN);
    k_stats_reduce<<<1, 256, 0, stream>>>(partN, 512, g_np, be_np, ss);
    k_bn_apply<<<2048, 256, 0, stream>>>(t, ss, h, h_bf);

    for (int l = 0; l < 3; ++l) {
        hipMemsetAsync(aggr, 0, (size_t)N_NODES * HD * sizeof(float), stream);
        if (epre)
            k_edge_mfma_s<true><<<N_EDGES / 128, 256, 0, stream>>>(
                h_bf, e_bf, ea, sE, Wep, bep, sD, sS, rowptr, hist,
                pA1 + (size_t)l * 40 * 64 * 8, be1 + l * HD,
                pA2 + (size_t)l * 32 * 64 * 8, be2 + l * HD, aggr);
        else
            k_edge_mfma_s<false><<<N_EDGES / 128, 256, 0, stream>>>(
                h_bf, e_bf, ea, sE, Wep, bep, sD, sS, rowptr, hist,
                pA1 + (size_t)l * 40 * 64 * 8, be1 + l * HD,
                pA2 + (size_t)l * 32 * 64 * 8, be2 + l * HD, aggr);

        k_node_mfma<<<NBU, 64, 0, stream>>>(
            h_bf, aggr, h,
            pWn1 + (size_t)l * 48 * 64 * 8, bn1 + l * HD,
            pWn2 + (size_t)l * 16 * 64 * 8, bn2 + l * ND, t, partU);
        k_stats_reduce<<<1, 256, 0, stream>>>(partU, NBU, g_bn + l * ND, b_bn + l * ND, ss);
        k_bn_apply<<<2048, 256, 0, stream>>>(t, ss, h, h_bf);
    }

    hipMemsetAsync(pooled, 0, (size_t)(N_GRAPH * ND + 512) * sizeof(float), stream);
    k_pool<<<512, 256, 0, stream>>>(h, batch, pooled, cnt);
    k_readout<<<(N_GRAPH + WPB - 1) / WPB, 256, 0, stream>>>(
        pooled, cnt, Wo1, bo1, Wo2, bo2, outp);
}